// Round 6
// baseline (303.350 us; speedup 1.0000x reference)
//
#include <hip/hip_runtime.h>
#include <math.h>

#define LDEC 512
#define LENC 2048
#define DMODEL 1024
#define NH 16
#define HD 64
#define SCALE 0.125f
#define NTOP 31
#define NSAMP 38

typedef __attribute__((ext_vector_type(8))) short bf16x8;
typedef __attribute__((ext_vector_type(4))) float f32x4;

__device__ inline float wave_sum(float v) {
#pragma unroll
  for (int m = 32; m > 0; m >>= 1) v += __shfl_xor(v, m);
  return v;
}

__device__ inline unsigned short f2bf(float x) {
  unsigned u = __float_as_uint(x);
  u += 0x7fff + ((u >> 16) & 1);  // RNE
  return (unsigned short)(u >> 16);
}
__device__ inline float bf2f(unsigned short h) {
  return __uint_as_float(((unsigned)h) << 16);
}

// async HBM -> LDS, 16 B per lane; lds base must be wave-uniform
__device__ __forceinline__ void gld16(const unsigned short* g, unsigned short* l) {
  __builtin_amdgcn_global_load_lds(
      (const __attribute__((address_space(1))) unsigned int*)g,
      (__attribute__((address_space(3))) unsigned int*)l, 16, 0, 0);
}

// XOR-swizzled LDS index (row stride 64 shorts = 128 B): kills the
// stride-128B bank-conflict pattern; col must stay within [0,64).
__device__ __forceinline__ int sws(int row, int col) {
  return row * 64 + (col ^ ((row & 7) << 3));
}

// 16B-chunk XOR swizzle for 32-short-stride tiles (row = 64 B):
// chunk in [0,4) of 8 shorts; spreads row-walks over 4 bank-quads.
__device__ __forceinline__ int sws2(int row, int chunk) {
  return row * 32 + ((chunk ^ (row & 3)) << 3);
}

// ================== FUSED PROLOGUE: cvt_in + cvt_w3 + k_samp =================
// grid: [0,5120) cvt_in | [5120,5888) cvt_w3 | [5888,7104) k_samp split-K.
// dyn LDS 17408.
__global__ __launch_bounds__(256) void prologue(
    const float* __restrict__ dec, const float* __restrict__ enc,
    const float* __restrict__ Wq, const float* __restrict__ Wk,
    const float* __restrict__ Wv, const int* __restrict__ sidx,
    unsigned short* __restrict__ dh, unsigned short* __restrict__ dl,
    unsigned short* __restrict__ eh,
    unsigned short* __restrict__ Wqh, unsigned short* __restrict__ Wql,
    unsigned short* __restrict__ Wkh, unsigned short* __restrict__ Wvh,
    float* __restrict__ KsPart) {
  extern __shared__ char smraw[];
  int bx = blockIdx.x;
  int tid = threadIdx.x;
  if (bx < 5120) {
    // ---- cvt_in ----
    int i = bx * 256 + tid;
    if (i < 262144) {
      float4 v = ((const float4*)dec)[i];
      ushort4 h = make_ushort4(f2bf(v.x), f2bf(v.y), f2bf(v.z), f2bf(v.w));
      ushort4 l = make_ushort4(f2bf(v.x - bf2f(h.x)), f2bf(v.y - bf2f(h.y)),
                               f2bf(v.z - bf2f(h.z)), f2bf(v.w - bf2f(h.w)));
      *(ushort4*)(dh + i * 4) = h;
      *(ushort4*)(dl + i * 4) = l;
    } else {
      int j = i - 262144;
      float4 v = ((const float4*)enc)[j];
      *(ushort4*)(eh + j * 4) =
          make_ushort4(f2bf(v.x), f2bf(v.y), f2bf(v.z), f2bf(v.w));
    }
  } else if (bx < 5888) {
    // ---- cvt_w3 ----
    float (*t)[68] = (float(*)[68])smraw;
    int wb = bx - 5120;
    int which = wb >> 8, rem = wb & 255;
    const float* W = which == 0 ? Wq : (which == 1 ? Wk : Wv);
    unsigned short* Th = which == 0 ? Wqh : (which == 1 ? Wkh : Wvh);
    unsigned short* Tl = which == 0 ? Wql : nullptr;
    int k0 = (rem >> 4) * 64, n0 = (rem & 15) * 64;
#pragma unroll
    for (int i = 0; i < 4; ++i) {
      int c = tid + 256 * i;
      int r = c >> 4, c4 = (c & 15) * 4;
      float4 v = *(const float4*)(W + (size_t)(k0 + r) * DMODEL + n0 + c4);
      t[c4 + 0][r] = v.x; t[c4 + 1][r] = v.y; t[c4 + 2][r] = v.z; t[c4 + 3][r] = v.w;
    }
    __syncthreads();
#pragma unroll
    for (int i = 0; i < 4; ++i) {
      int c = tid + 256 * i;
      int n = c >> 4, k4 = (c & 15) * 4;
      float4 v = *(const float4*)&t[n][k4];
      ushort4 h = make_ushort4(f2bf(v.x), f2bf(v.y), f2bf(v.z), f2bf(v.w));
      *(ushort4*)(Th + (size_t)(n0 + n) * DMODEL + k0 + k4) = h;
      if (Tl) {
        ushort4 l = make_ushort4(f2bf(v.x - bf2f(h.x)), f2bf(v.y - bf2f(h.y)),
                                 f2bf(v.z - bf2f(h.z)), f2bf(v.w - bf2f(h.w)));
        *(ushort4*)(Tl + (size_t)(n0 + n) * DMODEL + k0 + k4) = l;
      }
    }
  } else {
    // ---- k_samp split-K (fp32; 38s x 4 col-chunks x 8 k-chunks) ----
    // Each block: 128-long fp32 MAC per thread, 16-deep load batching.
    float* er = (float*)smraw;  // 128 floats
    int sb = bx - 5888;         // 0..1215
    int s = sb >> 5;            // 0..37
    int rem = sb & 31;
    int cchunk = rem >> 3, kc = rem & 7;
    int c = cchunk * 256 + tid;
    int srow = sidx[s];
    if (tid < 32) {
      int idx = tid * 4;
      *(float4*)&er[idx] =
          *(const float4*)(enc + (size_t)srow * DMODEL + kc * 128 + idx);
    }
    __syncthreads();
    float acc = 0.f;
    const float* wp = Wk + (size_t)(kc * 128) * DMODEL + c;
    for (int k0 = 0; k0 < 128; k0 += 16) {
      float w[16];
#pragma unroll
      for (int j = 0; j < 16; ++j) w[j] = wp[(size_t)(k0 + j) * DMODEL];
#pragma unroll
      for (int j = 0; j < 16; ++j) acc = fmaf(er[k0 + j], w[j], acc);
    }
    KsPart[(size_t)kc * (NSAMP * 1024) + s * 1024 + c] = acc;
  }
}

// ======= shared epilogue (256-thr, 2x2 wave grid): 64x32 wave tile =========
template <int BF16OUT>
__device__ __forceinline__ void gemm_epilogue256(
    unsigned short* sm, f32x4 (&acc)[4][2], float* __restrict__ C,
    unsigned short* __restrict__ Cb, int row0, int col0, int wave, int lane) {
  const int l16 = lane & 15, quad = lane >> 4;
  float* eL = (float*)sm + wave * 576;
  const int rr = lane >> 2, cc = (lane & 3) * 8;
  const int wr = wave >> 1, wc = wave & 1;
#pragma unroll
  for (int x = 0; x < 4; ++x) {
#pragma unroll
    for (int y = 0; y < 2; ++y)
#pragma unroll
      for (int q = 0; q < 4; ++q)
        eL[(quad * 4 + q) * 36 + y * 16 + l16] = acc[x][y][q];
    float4 v0 = *(const float4*)&eL[rr * 36 + cc];
    float4 v1 = *(const float4*)&eL[rr * 36 + cc + 4];
    size_t ro = (size_t)(row0 + wr * 64 + x * 16 + rr) * DMODEL + col0 + wc * 32 + cc;
    if (BF16OUT) {
      uint2 o;
      o.x = (unsigned)f2bf(v0.x) | ((unsigned)f2bf(v0.y) << 16);
      o.y = (unsigned)f2bf(v0.z) | ((unsigned)f2bf(v0.w) << 16);
      *(uint2*)(Cb + ro) = o;
      o.x = (unsigned)f2bf(v1.x) | ((unsigned)f2bf(v1.y) << 16);
      o.y = (unsigned)f2bf(v1.z) | ((unsigned)f2bf(v1.w) << 16);
      *(uint2*)(Cb + ro + 4) = o;
    } else {
      *(float4*)(C + ro) = v0;
      *(float4*)(C + ro + 4) = v1;
    }
  }
}

// ======= 1-pass bf16 GEMM, 256 thr, block tile 128x64, ASYNC global->LDS ===
// 24576 B dyn LDS (dbuf) -> up to 6 blocks/CU. sws2-swizzled via pre-swizzled
// global source (gld16 needs linear LDS dest).
template <int BF16OUT>
__device__ __forceinline__ void gemm256_1p_async(
    const unsigned short* __restrict__ Ah, const unsigned short* __restrict__ Bh,
    float* __restrict__ C, unsigned short* __restrict__ Cb, int row0, int col0) {
  extern __shared__ unsigned short sm[];
  const int BUFS = 6144;
  const int tid = threadIdx.x, lane = tid & 63, wave = tid >> 6;
  const int l16 = lane & 15, quad = lane >> 4;
  const int wr = wave >> 1, wc = wave & 1;

  const int srow = wave * 16 + (lane >> 2);
  const int scol = (((lane & 3) ^ ((lane >> 2) & 3))) * 8;  // pre-swizzled source
  const unsigned short* gA0 = Ah + (size_t)(row0 + srow) * DMODEL + scol;
  const unsigned short* gA1 = Ah + (size_t)(row0 + 64 + srow) * DMODEL + scol;
  const unsigned short* gB = Bh + (size_t)(col0 + srow) * DMODEL + scol;
  const int wofs = wave * 512;

  f32x4 acc[4][2];
#pragma unroll
  for (int x = 0; x < 4; ++x)
#pragma unroll
    for (int y = 0; y < 2; ++y) acc[x][y] = (f32x4){0.f, 0.f, 0.f, 0.f};

  gld16(gA0, sm + wofs);
  gld16(gA1, sm + 2048 + wofs);
  gld16(gB, sm + 4096 + wofs);
  __syncthreads();

  for (int it = 0; it < 32; ++it) {
    const unsigned short* cur = sm + (it & 1) * BUFS;
    if (it < 31) {
      int ko = (it + 1) * 32;
      unsigned short* nxt = sm + ((it + 1) & 1) * BUFS;
      gld16(gA0 + ko, nxt + wofs);
      gld16(gA1 + ko, nxt + 2048 + wofs);
      gld16(gB + ko, nxt + 4096 + wofs);
    }
    bf16x8 a[4], b[2];
#pragma unroll
    for (int x = 0; x < 4; ++x)
      a[x] = *(const bf16x8*)&cur[sws2(wr * 64 + x * 16 + l16, quad)];
#pragma unroll
    for (int y = 0; y < 2; ++y)
      b[y] = *(const bf16x8*)&cur[4096 + sws2(wc * 32 + y * 16 + l16, quad)];
#pragma unroll
    for (int x = 0; x < 4; ++x)
#pragma unroll
      for (int y = 0; y < 2; ++y)
        acc[x][y] = __builtin_amdgcn_mfma_f32_16x16x32_bf16(a[x], b[y], acc[x][y], 0, 0, 0);
    __syncthreads();
  }
  gemm_epilogue256<BF16OUT>(sm, acc, C, Cb, row0, col0, wave, lane);
}

// ======= 3-pass hi/lo GEMM, 256 thr, 128x64 tile, single-buffer 24576 B ====
__device__ __forceinline__ void gemm256_3p(
    const unsigned short* __restrict__ Ah, const unsigned short* __restrict__ Al,
    const unsigned short* __restrict__ Bh, const unsigned short* __restrict__ Bl,
    float* __restrict__ C, int row0, int col0) {
  extern __shared__ unsigned short sm[];
  const int tid = threadIdx.x, lane = tid & 63, wave = tid >> 6;
  const int l16 = lane & 15, quad = lane >> 4;
  const int wr = wave >> 1, wc = wave & 1;

  const int r = tid >> 2, kc = tid & 3;  // r in [0,64)
  const unsigned short* gAh = Ah + (size_t)(row0 + r) * DMODEL + kc * 8;
  const unsigned short* gBh = Bh + (size_t)(col0 + r) * DMODEL + kc * 8;
  const unsigned short* gAl = Al + (size_t)(row0 + r) * DMODEL + kc * 8;
  const unsigned short* gBl = Bl + (size_t)(col0 + r) * DMODEL + kc * 8;
  const int lofs0 = sws2(r, kc), lofs1 = sws2(r + 64, kc);

  f32x4 acc[4][2];
#pragma unroll
  for (int x = 0; x < 4; ++x)
#pragma unroll
    for (int y = 0; y < 2; ++y) acc[x][y] = (f32x4){0.f, 0.f, 0.f, 0.f};

  uint4 pah0 = *(const uint4*)gAh;
  uint4 pah1 = *(const uint4*)(gAh + (size_t)64 * DMODEL);
  uint4 pal0 = *(const uint4*)gAl;
  uint4 pal1 = *(const uint4*)(gAl + (size_t)64 * DMODEL);
  uint4 pbh = *(const uint4*)gBh;
  uint4 pbl = *(const uint4*)gBl;

  for (int it = 0; it < 32; ++it) {
    *(uint4*)&sm[lofs0] = pah0;
    *(uint4*)&sm[lofs1] = pah1;
    *(uint4*)&sm[4096 + lofs0] = pbh;
    *(uint4*)&sm[6144 + lofs0] = pal0;
    *(uint4*)&sm[6144 + lofs1] = pal1;
    *(uint4*)&sm[10240 + lofs0] = pbl;
    __syncthreads();
    if (it < 31) {
      int ko = (it + 1) * 32;
      pah0 = *(const uint4*)(gAh + ko);
      pah1 = *(const uint4*)(gAh + (size_t)64 * DMODEL + ko);
      pal0 = *(const uint4*)(gAl + ko);
      pal1 = *(const uint4*)(gAl + (size_t)64 * DMODEL + ko);
      pbh = *(const uint4*)(gBh + ko);
      pbl = *(const uint4*)(gBl + ko);
    }
    bf16x8 ah[4], bh[2], al[4], bl[2];
#pragma unroll
    for (int x = 0; x < 4; ++x) {
      int rr = wr * 64 + x * 16 + l16;
      ah[x] = *(const bf16x8*)&sm[sws2(rr, quad)];
      al[x] = *(const bf16x8*)&sm[6144 + sws2(rr, quad)];
    }
#pragma unroll
    for (int y = 0; y < 2; ++y) {
      int rr = wc * 32 + y * 16 + l16;
      bh[y] = *(const bf16x8*)&sm[4096 + sws2(rr, quad)];
      bl[y] = *(const bf16x8*)&sm[10240 + sws2(rr, quad)];
    }
#pragma unroll
    for (int x = 0; x < 4; ++x)
#pragma unroll
      for (int y = 0; y < 2; ++y) {
        acc[x][y] = __builtin_amdgcn_mfma_f32_16x16x32_bf16(ah[x], bh[y], acc[x][y], 0, 0, 0);
        acc[x][y] = __builtin_amdgcn_mfma_f32_16x16x32_bf16(ah[x], bl[y], acc[x][y], 0, 0, 0);
        acc[x][y] = __builtin_amdgcn_mfma_f32_16x16x32_bf16(al[x], bh[y], acc[x][y], 0, 0, 0);
      }
    __syncthreads();
  }
  gemm_epilogue256<0>(sm, acc, C, nullptr, row0, col0, wave, lane);
}

// merged Q(3-pass) + K(1-pass async, bf16-out) + V(1-pass async)
// grid (72,16) x 256 thr, dyn LDS 24576 -> 4-6 blocks/CU.
__global__ __launch_bounds__(256, 8) void gemm_qkv(
    const unsigned short* __restrict__ dh, const unsigned short* __restrict__ dl,
    const unsigned short* __restrict__ Wqh, const unsigned short* __restrict__ Wql,
    float* __restrict__ Q,
    const unsigned short* __restrict__ eh, const unsigned short* __restrict__ Wkh,
    unsigned short* __restrict__ Kb16,
    const unsigned short* __restrict__ Wvh, float* __restrict__ V) {
  int bx = blockIdx.x;
  if (bx < 8)
    gemm256_3p(dh, dl, Wqh, Wql, Q, bx * 128, blockIdx.y * 64);
  else if (bx < 40)
    gemm256_1p_async<1>(eh, Wkh, nullptr, Kb16, (bx - 8) * 128, blockIdx.y * 64);
  else
    gemm256_1p_async<0>(eh, Wvh, V, nullptr, (bx - 40) * 128, blockIdx.y * 64);
}

__global__ __launch_bounds__(256, 8) void gemm_one(
    const unsigned short* __restrict__ Ah, const unsigned short* __restrict__ Bh,
    float* __restrict__ C) {
  gemm256_1p_async<0>(Ah, Bh, C, nullptr, blockIdx.x * 128, blockIdx.y * 64);
}

// ============ FUSED TRIO: cvt_vt + lin_cos_stats(MFMA) + pp_scores ==========
// grid: [0,1024) cvt_vt | [1024,1536) lin_cos_stats | [1536,1664) pp_scores.
// dyn LDS 34816 B (max branch: lin_cos 34560).
__global__ __launch_bounds__(256, 4) void trio(
    const float* __restrict__ V, unsigned short* __restrict__ Vt,
    const unsigned short* __restrict__ Kb,
    float* __restrict__ kvpL, float* __restrict__ kvpC,
    float* __restrict__ kspL, float* __restrict__ kspC, float* __restrict__ vsp,
    const float* __restrict__ Q, const float* __restrict__ KsPart,
    float* __restrict__ Mout) {
  extern __shared__ char smraw[];
  int bx0 = blockIdx.x;
  int tid = threadIdx.x;
  if (bx0 < 1024) {
    // ---- cvt_vt ----
    unsigned short (*tile)[72] = (unsigned short(*)[72])smraw;
    int bh = bx0 >> 5;
    int s0 = (bx0 & 31) * 64;
    int b = bh >> 4, h = bh & 15;
#pragma unroll
    for (int i = 0; i < 4; ++i) {
      int c = tid + 256 * i;
      int s = c >> 4, d4 = (c & 15) * 4;
      float4 v = *(const float4*)(V + (size_t)(b * LENC + s0 + s) * DMODEL + h * HD + d4);
      tile[d4 + 0][s] = f2bf(v.x);
      tile[d4 + 1][s] = f2bf(v.y);
      tile[d4 + 2][s] = f2bf(v.z);
      tile[d4 + 3][s] = f2bf(v.w);
    }
    __syncthreads();
#pragma unroll
    for (int i = 0; i < 2; ++i) {
      int c = tid + 256 * i;
      int d = c >> 3, soff = (c & 7) * 8;
      uint4 o = *(const uint4*)&tile[d][soff];
      *(uint4*)(Vt + (size_t)(bh * 64 + d) * LENC + s0 + soff) = o;
    }
  } else if (bx0 < 1536) {
    // ---- lin_cos_stats via hi/lo bf16 MFMA 3-pass ----
    float (*Kt)[65] = (float(*)[65])smraw;                          // 16640 B
    unsigned int (*Vu)[65] = (unsigned int(*)[65])(smraw + 16640);  // 16640 B
    float* nrm = (float*)(smraw + 33280);                           //   256 B
    float4* vred = (float4*)(smraw + 33536);                        //  1024 B
    int bx = bx0 - 1024;
    int bh = bx >> 4, part = bx & 15;
    int b = bh >> 4, h = bh & 15;
    const int lane = tid & 63, wv = tid >> 6;
    const int l16 = lane & 15, quad = lane >> 4;
    const int dblk = wv * 16;
    const unsigned short* Kg = Kb + (size_t)(b * LENC + part * 128) * DMODEL + h * HD;
    const float* Vg = V + (size_t)(b * LENC + part * 128) * DMODEL + h * HD;
    const int sK = tid >> 2, d16 = (tid & 3) * 16;
    const int sVb = tid >> 4, v4 = (tid & 15) * 4;

    f32x4 accL[4], accC[4];
#pragma unroll
    for (int n = 0; n < 4; ++n) {
      accL[n] = (f32x4){0.f, 0.f, 0.f, 0.f};
      accC[n] = (f32x4){0.f, 0.f, 0.f, 0.f};
    }
    float kslp = 0.f, kscp = 0.f;
    float4 vpart = make_float4(0.f, 0.f, 0.f, 0.f);

    for (int ch = 0; ch < 2; ++ch) {
      const int s0 = ch * 64;
      // stage K (bf16 -> f32) + row sumsq -> nrm
      {
        const unsigned short* kr = Kg + (size_t)(s0 + sK) * DMODEL + d16;
        uint4 p0 = *(const uint4*)kr;
        uint4 p1 = *(const uint4*)(kr + 8);
        float kvv[16];
        kvv[0] = __uint_as_float(p0.x << 16);
        kvv[1] = __uint_as_float(p0.x & 0xffff0000u);
        kvv[2] = __uint_as_float(p0.y << 16);
        kvv[3] = __uint_as_float(p0.y & 0xffff0000u);
        kvv[4] = __uint_as_float(p0.z << 16);
        kvv[5] = __uint_as_float(p0.z & 0xffff0000u);
        kvv[6] = __uint_as_float(p0.w << 16);
        kvv[7] = __uint_as_float(p0.w & 0xffff0000u);
        kvv[8] = __uint_as_float(p1.x << 16);
        kvv[9] = __uint_as_float(p1.x & 0xffff0000u);
        kvv[10] = __uint_as_float(p1.y << 16);
        kvv[11] = __uint_as_float(p1.y & 0xffff0000u);
        kvv[12] = __uint_as_float(p1.z << 16);
        kvv[13] = __uint_as_float(p1.z & 0xffff0000u);
        kvv[14] = __uint_as_float(p1.w << 16);
        kvv[15] = __uint_as_float(p1.w & 0xffff0000u);
        float ss = 0.f;
#pragma unroll
        for (int j = 0; j < 16; ++j) ss = fmaf(kvv[j], kvv[j], ss);
        ss += __shfl_xor(ss, 1);
        ss += __shfl_xor(ss, 2);
        if ((tid & 3) == 0) nrm[sK] = sqrtf(ss);
#pragma unroll
        for (int j = 0; j < 16; ++j) Kt[sK][d16 + j] = kvv[j];
      }
      // stage V (f32 -> packed hi|lo bf16) + column-sum partial
#pragma unroll
      for (int i = 0; i < 4; ++i) {
        int sv = sVb + 16 * i;
        float4 vv = *(const float4*)(Vg + (size_t)(s0 + sv) * DMODEL + v4);
        vpart.x += vv.x; vpart.y += vv.y; vpart.z += vv.z; vpart.w += vv.w;
        unsigned short h0 = f2bf(vv.x), h1 = f2bf(vv.y);
        unsigned short h2 = f2bf(vv.z), h3 = f2bf(vv.w);
        Vu[sv][v4 + 0] = ((unsigned)h0 << 16) | (unsigned)f2bf(vv.x - bf2f(h0));
        Vu[sv][v4 + 1] = ((unsigned)h1 << 16) | (unsigned)f2bf(vv.y - bf2f(h1));
        Vu[sv][v4 + 2] = ((unsigned)h2 << 16) | (unsigned)f2bf(vv.z - bf2f(h2));
        Vu[sv][v4 + 3] = ((unsigned)h3 << 16) | (unsigned)f2bf(vv.w - bf2f(h3));
      }
      __syncthreads();
      // fragment build + MFMA
#pragma unroll
      for (int kk = 0; kk < 2; ++kk) {
        const int sb = kk * 32 + quad * 8;
        bf16x8 aLh, aLl, aCh, aCl;
#pragma unroll
        for (int j = 0; j < 8; ++j) {
          float kval = Kt[sb + j][dblk + l16];
          float nn = nrm[sb + j];
          float kfl = kval > 0.f ? kval + 1.f : __expf(kval);
          float kn = kval / fmaxf(nn, 1e-12f);
          float kfc = fmaxf(kn, 0.f) + 1e-6f;
          kslp += kfl;
          kscp += kfc;
          unsigned short hL = f2bf(kfl);
          aLh[j] = hL;
          aLl[j] = f2bf(kfl - bf2f(hL));
          unsigned short hC = f2bf(kfc);
          aCh[j] = hC;
          aCl[j] = f2bf(kfc - bf2f(hC));
        }
#pragma unroll
        for (int n = 0; n < 4; ++n) {
          bf16x8 bhv, blv;
#pragma unroll
          for (int j = 0; j < 8; ++j) {
            unsigned uv = Vu[sb + j][n * 16 + l16];
            bhv[j] = (short)(unsigned short)(uv >> 16);
            blv[j] = (short)(unsigned short)(uv & 0xffffu);
          }
          accL[n] = __builtin_amdgcn_mfma_f32_16x16x32_bf16(aLh, bhv, accL[n], 0, 0, 0);
          accL[n] = __builtin_amdgcn_mfma_f32_16x16x32_bf16(aLh, blv, accL[n], 0, 0, 0);
          accL[n] = __builtin_amdgcn_mfma_f32_16x16x32_bf16(aLl, bhv, accL[n], 0, 0, 0);
          accC[n] = __builtin_amdgcn_mfma_f32_16x16x32_bf16(aCh, bhv, accC[n], 0, 0, 0);
          accC[n] = __builtin_amdgcn_mfma_f32_16x16x32_bf16(aCh, blv, accC[n], 0, 0, 0);
          accC[n] = __builtin_amdgcn_mfma_f32_16x16x32_bf16(aCl, bhv, accC[n], 0, 0, 0);
        }
      }
      __syncthreads();
    }
    // outputs: kv partials (D layout: row = quad*4+q, col = l16)
    const int obase = part * 131072 + bh * 4096;
#pragma unroll
    for (int n = 0; n < 4; ++n)
#pragma unroll
      for (int q = 0; q < 4; ++q) {
        int o = obase + (dblk + quad * 4 + q) * 64 + n * 16 + l16;
        kvpL[o] = accL[n][q];
        kvpC[o] = accC[n][q];
      }
    kslp += __shfl_xor(kslp, 16);
    kslp += __shfl_xor(kslp, 32);
    kscp += __shfl_xor(kscp, 16);
    kscp += __shfl_xor(kscp, 32);
    if (quad == 0) {
      kspL[part * 2048 + bh * 64 + dblk + l16] = kslp;
      kspC[part * 2048 + bh * 64 + dblk + l16] = kscp;
    }
    vpart.x += __shfl_xor(vpart.x, 16); vpart.x += __shfl_xor(vpart.x, 32);
    vpart.y += __shfl_xor(vpart.y, 16); vpart.y += __shfl_xor(vpart.y, 32);
    vpart.z += __shfl_xor(vpart.z, 16); vpart.z += __shfl_xor(vpart.z, 32);
    vpart.w += __shfl_xor(vpart.w, 16); vpart.w += __shfl_xor(vpart.w, 32);
    if (quad == 0) vred[wv * 16 + l16] = vpart;
    __syncthreads();
    if (tid < 16) {
      float4 a0 = vred[tid], a1 = vred[16 + tid];
      float4 a2 = vred[32 + tid], a3 = vred[48 + tid];
      float4 s = make_float4(a0.x + a1.x + a2.x + a3.x, a0.y + a1.y + a2.y + a3.y,
                             a0.z + a1.z + a2.z + a3.z, a0.w + a1.w + a2.w + a3.w);
      *(float4*)&vsp[part * 2048 + bh * 64 + tid * 4] = s;
    }
  } else {
    // ---- pp_scores (fp32; sums the 8 split-K partials in fixed order) ----
    float (*ksL)[65] = (float(*)[65])smraw;  // 38*65*4 = 9880 B
    int bx = bx0 - 1536;
    int bh = bx >> 2, chunk = bx & 3;
    int b = bh >> 4, h = bh & 15;
    int t0 = chunk * 128;
    const float* Qb = Q + (b * LDEC) * DMODEL + h * HD;
    for (int slot = tid; slot < NSAMP * 16; slot += 256) {
      int r = slot >> 4, c4 = slot & 15;
      const float* kp = KsPart + r * 1024 + h * HD + c4 * 4;
      float4 kx = *(const float4*)kp;
#pragma unroll
      for (int p = 1; p < 8; ++p) {
        float4 k2 = *(const float4*)(kp + (size_t)p * (NSAMP * 1024));
        kx.x += k2.x; kx.y += k2.y; kx.z += k2.z; kx.w += k2.w;
      }
      ksL[r][c4 * 4 + 0] = kx.x; ksL[r][c4 * 4 + 1] = kx.y;
      ksL[r][c4 * 4 + 2] = kx.z; ksL[r][c4 * 4 + 3] = kx.w;
    }
    __syncthreads();
    if (tid < 128) {
      float qr[64];
      const float* qrow = Qb + (size_t)(t0 + tid) * DMODEL;
#pragma unroll
      for (int d4 = 0; d4 < 16; ++d4)
        *(float4*)&qr[d4 * 4] = *(const float4*)(qrow + d4 * 4);
      float mx = -INFINITY, sm = 0.f;
      for (int j = 0; j < NSAMP; ++j) {
        float s = 0.f;
#pragma unroll
        for (int d = 0; d < 64; ++d) s = fmaf(qr[d], ksL[j][d], s);
        s *= SCALE;
        mx = fmaxf(mx, s);
        sm += s;
      }
      Mout[bh * LDEC + t0 + tid] = mx - sm / (float)NSAMP;
    }
  }
}

// ============ FUSED TAIL: reduce_all + pp_topk ==============================
// grid: [0,1048) reduce_all | [1048,1080) pp_topk. dyn LDS 4224 B.
__global__ __launch_bounds__(256) void tail2(
    const float* __restrict__ kvpL, const float* __restrict__ kvpC,
    const float* __restrict__ kspL, const float* __restrict__ kspC,
    const float* __restrict__ vsp, float* __restrict__ kvL,
    float* __restrict__ kvC, float* __restrict__ ksL,
    float* __restrict__ ksC, float* __restrict__ vmean,
    const float* __restrict__ Mbuf, int* __restrict__ sel) {
  extern __shared__ char smraw[];
  int bx = blockIdx.x;
  int tid = threadIdx.x;
  if (bx < 1048) {
    int i = bx * 256 + tid;
    if (i < 131072) {
      float s = 0.f;
#pragma unroll
      for (int p = 0; p < 16; ++p) s += kvpL[p * 131072 + i];
      kvL[i] = s;
    } else if (i < 262144) {
      int j = i - 131072;
      float s = 0.f;
#pragma unroll
      for (int p = 0; p < 16; ++p) s += kvpC[p * 131072 + j];
      kvC[j] = s;
    } else if (i < 268288) {
      int j = i - 262144;
      int which = j >> 11, jj = j & 2047;
      const float* src = which == 0 ? kspL : (which == 1 ? kspC : vsp);
      float s = 0.f;
#pragma unroll
      for (int p = 0; p < 16; ++p) s += src[p * 2048 + jj];
      if (which == 0) ksL[jj] = s;
      else if (which == 1) ksC[jj] = s;
      else vmean[jj] = s * (1.f / 2048.f);
    }
  } else {
    // ---- pp_topk (tie -> lower index) ----
    float* vals = (float*)smraw;
    int* flag = (int*)(smraw + 2048);
    float* wvs = (float*)(smraw + 4096);
    int* wis = (int*)(smraw + 4112);
    int bh = bx - 1048;
    int lane = tid & 63, g = tid >> 6;
    vals[tid] = Mbuf[bh * 512 + tid];
    vals[tid + 256] = Mbuf[bh * 512 + tid + 256];
    flag[tid] = 0; flag[tid + 256] = 0;
    __syncthreads();
    for (int it = 0; it < NTOP; ++it) {
      float v0 = vals[tid]; int i0 = tid;
      float v1 = vals[tid + 256];
      if (v1 > v0) { v0 = v1; i0 = tid + 256; }
#pragma unroll
      for (int mm = 32; mm > 0; mm >>= 1) {
        float ov = __shfl_xor(v0, mm);
        int oi = __shfl_xor(i0, mm);
        if (ov > v0 || (ov == v0 && oi < i0)) { v0 = ov; i0 = oi; }
      }
      if (lane == 0) { wvs[g] = v0; wis[g] = i0; }
      __syncthreads();
      if (tid == 0) {
        float bv = wvs[0]; int bi = wis[0];
#pragma unroll
        for (int w = 1; w < 4; ++w)
          if (wvs[w] > bv || (wvs[w] == bv && wis[w] < bi)) { bv = wvs[w]; bi = wis[w]; }
        vals[bi] = -INFINITY;
        flag[bi] = 1;
      }
      __syncthreads();
    }
    sel[bh * 512 + tid] = flag[tid];
    sel[bh * 512 + tid + 256] = flag[tid + 256];
  }
}

// ---------------- MFMA flash attention, split-K 4-way + XCD swizzle ---------
// LDS 40960 B (swizzled, conflict-free); row sums via MFMA ones-column trick.
__global__ __launch_bounds__(256) void attn_mfma(
    const float* __restrict__ Qf, const unsigned short* __restrict__ Kb,
    const unsigned short* __restrict__ Vt,
    float* __restrict__ OsP0, float* __restrict__ OsP1,
    float* __restrict__ OsP2, float* __restrict__ OsP3,
    float* __restrict__ OlS0, float* __restrict__ OlS1,
    float* __restrict__ st) {
  __shared__ unsigned short Ks[2][4096];
  __shared__ unsigned short Vs[2][4096];
  __shared__ unsigned short Ps[4][1024];
  const int tid = threadIdx.x;
  const int wave = tid >> 6, lane = tid & 63;
  const int l16 = lane & 15, quad = lane >> 4;
  const int bx = blockIdx.x;
  const int xcd = bx & 7, sub = bx >> 3;
  const int qt = sub & 7, qr = (sub >> 3) & 3, grp = sub >> 5;
  const int bh = xcd + 8 * grp;
  const int b = bh >> 4, h = bh & 15;
  const int tbase = qt * 64 + wave * 16;
  const int sbase = qr * 512;

  const float* qrow = Qf + (size_t)(b * LDEC + tbase + l16) * DMODEL + h * HD + quad * 8;
  bf16x8 qa0, qa1;
  {
    float4 a0 = *(const float4*)qrow, a1 = *(const float4*)(qrow + 4);
    float4 a2 = *(const float4*)(qrow + 32), a3 = *(const float4*)(qrow + 36);
    qa0[0] = f2bf(a0.x * SCALE); qa0[1] = f2bf(a0.y * SCALE);
    qa0[2] = f2bf(a0.z * SCALE); qa0[3] = f2bf(a0.w * SCALE);
    qa0[4] = f2bf(a1.x * SCALE); qa0[5] = f2bf(a1.y * SCALE);
    qa0[6] = f2bf(a1.z * SCALE); qa0[7] = f2bf(a1.w * SCALE);
    qa1[0] = f2bf(a2.x * SCALE); qa1[1] = f2bf(a2.y * SCALE);
    qa1[2] = f2bf(a2.z * SCALE); qa1[3] = f2bf(a2.w * SCALE);
    qa1[4] = f2bf(a3.x * SCALE); qa1[5] = f2bf(a3.y * SCALE);
    qa1[6] = f2bf(a3.z * SCALE); qa1[7] = f2bf(a3.w * SCALE);
  }

  // ones B-fragment: row-sum of P via MFMA (D col all equal)
  bf16x8 bone;
#pragma unroll
  for (int j = 0; j < 8; ++j) bone[j] = (short)0x3f80;

  int tA = tbase + l16;
  int cA = min(4 * tA, LENC - 1);
  int loA = max(cA - 256, 0), hiA = min(cA + 256, LENC - 1);
  const int loW = max(4 * tbase - 256, 0);
  const int hiW = min(4 * (tbase + 15) + 256, LENC - 1);
  const bool blockAny = (sbase <= hiW) && (sbase + 511 >= loW);

  f32x4 Os[4], Ol[4], Ssum, Slsum;
#pragma unroll
  for (int n = 0; n < 4; ++n) {
    Os[n] = (f32x4){0.f, 0.f, 0.f, 0.f};
    Ol[n] = (f32x4){0.f, 0.f, 0.f, 0.f};
  }
  Ssum = (f32x4){0.f, 0.f, 0.f, 0.f};
  Slsum = (f32x4){0.f, 0.f, 0.f, 0.f};

  const int c0 = tid, c1 = tid + 256;
  const unsigned short* kg0 = Kb + (size_t)(b * LENC + sbase + (c0 >> 3)) * DMODEL + h * HD + (c0 & 7) * 8;
  const unsigned short* kg1 = Kb + (size_t)(b * LENC + sbase + (c1 >> 3)) * DMODEL + h * HD + (c1 & 7) * 8;
  const unsigned short* vg0 = Vt + (size_t)(bh * 64 + (c0 >> 3)) * LENC + sbase + (c0 & 7) * 8;
  const unsigned short* vg1 = Vt + (size_t)(bh * 64 + (c1 >> 3)) * LENC + sbase + (c1 & 7) * 8;
  const int of0 = sws(c0 >> 3, (c0 & 7) * 8);
  const int of1 = sws(c1 >> 3, (c1 & 7) * 8);

  uint4 pk0, pk1, pv0, pv1;
  pk0 = *(const uint4*)kg0; pk1 = *(const uint4*)kg1;
  pv0 = *(const uint4*)vg0; pv1 = *(const uint4*)vg1;
  *(uint4*)&Ks[0][of0] = pk0; *(uint4*)&Ks[0][of1] = pk1;
  *(uint4*)&Vs[0][of0] = pv0; *(uint4*)&Vs[0][of1] = pv1;
  __syncthreads();

  for (int it = 0; it < 8; ++it) {
    const int cur = it & 1;
    const int s0 = sbase + it * 64;
    const bool anyL = (s0 <= hiW) && (s0 + 63 >= loW);
    if (it < 7) {
      pk0 = *(const uint4*)(kg0 + (size_t)(it + 1) * 64 * DMODEL);
      pk1 = *(const uint4*)(kg1 + (size_t)(it + 1) * 64 * DMODEL);
      pv0 = *(const uint4*)(vg0 + (it + 1) * 64);
      pv1 = *(const uint4*)(vg1 + (it + 1) * 64);
    }
    const unsigned short* K_ = Ks[cur];
    const unsigned short* V_ = Vs[cur];

    f32x4 S[4];
#pragma unroll
    for (int n = 0; n < 4; ++n) {
      bf16x8 bk0 = *(const bf16x8*)&K_[sws(n * 16 + l16, quad * 8)];
      bf16x8 bk1 = *(const bf16x8*)&K_[sws(n * 16 + l16, 32 + quad * 8)];
      f32x4 z = (f32x4){0.f, 0.f, 0.f, 0.f};
      z = __builtin_amdgcn_mfma_f32_16x16x32_bf16(qa0, bk0, z, 0, 0, 0);
      S[n] = __builtin_amdgcn_mfma_f32_16x16x32_bf16(qa1, bk1, z, 0, 0, 0);
    }

    unsigned short* Pw = Ps[wave];
#pragma unroll
    for (int n = 0; n < 4; ++n)
#pragma unroll
      for (int r = 0; r < 4; ++r)
        Pw[sws(quad * 4 + r, n * 16 + l16)] = f2bf(__expf(S[n][r]));
    bf16x8 aP0 = *(const bf16x8*)&Pw[sws(l16, quad * 8)];
    bf16x8 aP1 = *(const bf16x8*)&Pw[sws(l16, 32 + quad * 8)];
    // row sums (softmax denominators) via ones-column MFMA
    Ssum = __builtin_amdgcn_mfma_f32_16x16x32_bf16(aP0, bone, Ssum, 0, 0, 0);
    Ssum = __builtin_amdgcn_mfma_f32_16x16x32_bf16(aP1, bone, Ssum, 0, 0, 0);
#pragma unroll
    for (int n = 0; n < 4; ++n) {
      bf16x8 bv0 = *(const bf16x8*)&V_[sws(n * 16 + l16, quad * 8)];
      bf16x8 bv1 = *(const bf16x8*)&V_[sws(n * 16 + l16, 32 + quad * 8)];
      Os[n] = __builtin_amdgcn_mfma_f32_16x16x32_bf16(aP0, bv0, Os[n], 0, 0, 0);
      Os[n] = __builtin_amdgcn_mfma_f32_16x16x32_bf16(aP1, bv1, Os[n], 0, 0, 0);
    }
    if (anyL) {
      bf16x8 aL0 = aP0, aL1 = aP1;
#pragma unroll
      for (int j = 0; j < 8; ++j) {
        int sc = s0 + quad * 8 + j;
        if (sc < loA || sc > hiA) aL0[j] = 0;
        if (sc + 32 < loA || sc + 32 > hiA) aL1[j] = 0;
      }
      Slsum = __builtin_amdgcn_mfma_f32_16x16x32_bf16(aL0, bone, Slsum, 0, 0, 0);
      Slsum = __builtin_amdgcn_mfma_f32_16x16x32_bf16(aL1, bone, Slsum, 0, 0, 0);
#pragma unroll
      for (int n = 0; n < 4; ++n) {
        bf16x8 bv0 = *(const bf16x8*)&V_[sws(n * 16 + l16, quad * 8)];
        bf16x8 bv1 = *(const bf16x8*)&V_[sws(n * 16 + l16, 32 + quad * 8)];
        Ol[n] = __builtin_amdgcn_mfma_f32_16x16x32_bf16(aL0, bv0, Ol[n], 0, 0, 0);
        Ol[n] = __builtin_amdgcn_mfma_f32_16x16x32_bf16(aL1, bv1, Ol[n], 0, 0, 0);
      }
    }
    // single barrier per iteration: all reads of buffer (1-cur) completed
    // before the previous iteration's barrier, so writing it now is safe.
    if (it < 7) {
      unsigned short* KL = Ks[1 - cur];
      unsigned short* VL = Vs[1 - cur];
      *(uint4*)&KL[of0] = pk0; *(uint4*)&KL[of1] = pk1;
      *(uint4*)&VL[of0] = pv0; *(uint4*)&VL[of1] = pv1;
    }
    __syncthreads();
  }

  float* osp = qr == 0 ? OsP0 : (qr == 1 ? OsP1 : (qr == 2 ? OsP2 : OsP3));
  float* olp = (qr & 1) ? OlS1 : OlS0;
  float* sp = st + qr * 32768;
#pragma unroll
  for (int r = 0; r < 4; ++r) {
    int t = tbase + quad * 4 + r;
#pragma unroll
    for (int n = 0; n < 4; ++n) {
      size_t o = (size_t)(b * LDEC + t) * DMODEL + h * HD + n * 16 + l16;
      osp[o] = Os[n][r];
      if (blockAny) olp[o] = Ol[n][r];
    }
    if (l16 == 0) {
      int sr = bh * 512 + t;
      sp[sr] = Ssum[r];
      sp[16384 + sr] = Slsum[r];
    }
  }
}

// fused: split-K-4 combine + probsparse fill + linear/cosine apply
// grid: [0,1024) combine_fill | [1024,5120) lin_cos_apply.
__global__ __launch_bounds__(256) void combine_fill(
    float* __restrict__ braw, const float* __restrict__ P1,
    const float* __restrict__ P2, const float* __restrict__ P3,
    const float* __restrict__ L1, const float* __restrict__ st,
    const float* __restrict__ vmean, const int* __restrict__ sel,
    const float* __restrict__ Q, const float* __restrict__ kvL,
    const float* __restrict__ kvC, const float* __restrict__ ksL,
    const float* __restrict__ ksC) {
  __shared__ float sh[2][4][64];
  int bx0 = blockIdx.x;
  int tid = threadIdx.x;
  if (bx0 < 1024) {
    int i4 = bx0 * 256 + tid;
    int i = i4 * 4;
    int col = i & 1023, bt = i >> 10;
    int t = bt & 511, b = bt >> 9, h = col >> 6, d = col & 63;
    int bh = b * 16 + h;
    int sr = bh * 512 + t;
    float iS = 1.f / (st[sr] + st[32768 + sr] + st[65536 + sr] + st[98304 + sr]);
    float iL = 1.f / (st[16384 + sr] + st[49152 + sr] + st[81920 + sr] + st[114688 + sr]);
    float4 s0 = *(const float4*)(braw + i);
    float4 s1 = *(const float4*)(P1 + i);
    float4 s2 = *(const float4*)(P2 + i);
    float4 s3 = *(const float4*)(P3 + i);
    // local-branch: row t's window touches quarters q0..q1 (q1-q0 <= 1);
    // quarter q wrote parity slot q&1 (slot0 = braw+4M, slot1 = L1).
    int c = min(4 * t, LENC - 1);
    int lo = max(c - 256, 0), hi = min(c + 256, LENC - 1);
    int q0 = lo >> 9, q1 = hi >> 9;
    const float* Lp0 = (q0 & 1) ? L1 : (braw + 4194304);
    float4 l = *(const float4*)(Lp0 + i);
    if (q1 != q0) {
      const float* Lp1 = (q1 & 1) ? L1 : (braw + 4194304);
      float4 l2 = *(const float4*)(Lp1 + i);
      l.x += l2.x; l.y += l2.y; l.z += l2.z; l.w += l2.w;
    }
    float4 os = make_float4((s0.x + s1.x + s2.x + s3.x) * iS,
                            (s0.y + s1.y + s2.y + s3.y) * iS,
                            (s0.z + s1.z + s2.z + s3.z) * iS,
                            (s0.w + s1.w + s2.w + s3.w) * iS);
    float4 ol = make_float4(l.x * iL, l.y * iL, l.z * iL, l.w * iL);
    *(float4*)(braw + i) = os;
    *(float4*)(braw + 4194304 + i) = ol;
    float4 pp = sel[sr] ? os : *(const float4*)(vmean + bh * 64 + d);
    *(float4*)(braw + 2097152 + i) = pp;
  } else {
    // ---- lin_cos_apply ----
    int lane = tid & 63, g = tid >> 6;
    int row = (bx0 - 1024) * 4 + g;
    int bh = row >> 9, t = row & 511;
    int b = bh >> 4, h = bh & 15;
    float qv = Q[(b * LDEC + t) * DMODEL + h * HD + lane];
    float x = qv * SCALE;
    float qfl = x > 0.f ? x + 1.f : __expf(x);
    float qnorm = sqrtf(wave_sum(qv * qv));
    float qn = qv / fmaxf(qnorm, 1e-12f);
    float qfc = fmaxf(qn, 0.f) + 1e-6f;
    sh[0][g][lane] = qfl;
    sh[1][g][lane] = qfc;
    float denL = fmaxf(wave_sum(qfl * ksL[bh * 64 + lane]), 1e-6f);
    float denC = fmaxf(wave_sum(qfc * ksC[bh * 64 + lane]), 1e-6f);
    const float* kvLb = kvL + bh * 4096;
    const float* kvCb = kvC + bh * 4096;
    float aL = 0.f, aC = 0.f;
#pragma unroll
    for (int d = 0; d < 64; ++d) {
      aL = fmaf(sh[0][g][d], kvLb[d * 64 + lane], aL);
      aC = fmaf(sh[1][g][d], kvCb[d * 64 + lane], aC);
    }
    int o = (b * LDEC + t) * DMODEL + h * HD + lane;
    braw[1048576 + o] = aL / denL;
    braw[3145728 + o] = aC / denC;
  }
}

// ============ FUSED EPILOGUE CVT: cvt_w(Wo) + cvt_braw ======================
// grid: [0,256) cvt_w | [256,5376) cvt_braw. dyn LDS 17408.
__global__ __launch_bounds__(256) void epi_cvt(
    const float* __restrict__ Wo, unsigned short* __restrict__ Woh,
    const float* __restrict__ braw, unsigned short* __restrict__ braw16) {
  extern __shared__ char smraw[];
  int bx = blockIdx.x;
  int tid = threadIdx.x;
  if (bx < 256) {
    float (*t)[68] = (float(*)[68])smraw;
    int k0 = (bx >> 4) * 64, n0 = (bx & 15) * 64;
#pragma unroll
    for (int i = 0; i < 4; ++i) {
      int c = tid + 256 * i;
      int r = c >> 4, c4 = (c & 15) * 4;
      float4 v = *(const float4*)(Wo + (size_t)(k0 + r) * DMODEL + n0 + c4);
      t[c4 + 0][r] = v.x; t[c4 + 1][r] = v.y; t[c4 + 2][r] = v.z; t[c4 + 3][r] = v.w;
    }
    __syncthreads();
#pragma unroll
    for (int i = 0; i < 4; ++i) {
      int c = tid + 256 * i;
      int n = c >> 4, k4 = (c & 15) * 4;
      float4 v = *(const float4*)&t[n][k4];
      *(ushort4*)(Woh + (size_t)(n0 + n) * DMODEL + k0 + k4) =
          make_ushort4(f2bf(v.x), f2bf(v.y), f2bf(v.z), f2bf(v.w));
    }
  } else {
    int i = (bx - 256) * 256 + tid;
    float4 v = ((const float4*)braw)[i];
    *(ushort4*)(braw16 + i * 4) = make_ushort4(f2bf(v.x), f2bf(v.y), f2bf(v.z), f2bf(v.w));
  }
}

// ---------------- final combine
__global__ __launch_bounds__(256) void combine(
    const float* __restrict__ dec, const float* __restrict__ proj,
    const float* __restrict__ rmsw, const float* __restrict__ alphas,
    float* __restrict__ out) {
  __shared__ float red[4];
  int row = blockIdx.x;
  int tid = threadIdx.x, lane = tid & 63, g = tid >> 6;
  int base = row * DMODEL + tid * 4;
  float4 dv = *(const float4*)(dec + base);
  float4 wv = *(const float4*)(rmsw + tid * 4);
  float a[6];
  float amax = -INFINITY;
#pragma unroll
  for (int i = 0; i < 6; ++i) { a[i] = alphas[i]; amax = fmaxf(amax, a[i]); }
  float asum = 0.f;
#pragma unroll
  for (int i = 0; i < 6; ++i) { a[i] = __expf(a[i] - amax); asum += a[i]; }
#pragma unroll
  for (int i = 0; i < 6; ++i) a[i] /= asum;
  float4 acc = make_float4(a[0] * dv.x, a[0] * dv.y, a[0] * dv.z, a[0] * dv.w);
  for (int br = 0; br < 5; ++br) {
    float4 pv = *(const float4*)(proj + br * 1048576 + base);
    float4 xx = make_float4(dv.x + pv.x, dv.y + pv.y, dv.z + pv.z, dv.w + pv.w);
    float ssq = xx.x * xx.x + xx.y * xx.y + xx.z * xx.z + xx.w * xx.w;
    float wsum = wave_sum(ssq);
    if (lane == 0) red[g] = wsum;
    __syncthreads();
    float tot = red[0] + red[1] + red[2] + red[3];
    float rr = rsqrtf(tot / 1024.f + 1e-6f);
    float wb = a[br + 1];
    acc.x += wb * xx.x * rr * wv.x;
    acc.y += wb * xx.y * rr * wv.y;
    acc.z += wb * xx.z * rr * wv.z;
    acc.w += wb * xx.w * rr * wv.w;
    __syncthreads();
  }
  *(float4*)(out + base) = acc;
}

extern "C" void kernel_launch(void* const* d_in, const int* in_sizes, int n_in,
                              void* d_out, int out_size, void* d_ws, size_t ws_size,
                              hipStream_t stream) {
  const float* dec = (const float*)d_in[0];
  const float* enc = (const float*)d_in[1];
  const float* Wq = (const float*)d_in[2];
  const float* Wk = (const float*)d_in[3];
  const float* Wv = (const float*)d_in[4];
  const float* Wo = (const float*)d_in[5];
  const float* rmsw = (const float*)d_in[6];
  const float* alphas = (const float*)d_in[7];
  const int* sidx = (const int*)d_in[8];

  const size_t M = 1048576;
  float* ws = (float*)d_ws;
  float* Q    = ws;                                  // [0,1M)
  unsigned short* Kb16 = (unsigned short*)(ws + M);  // [1M,3M)
  float* KsPart = ws + 3 * M;                        // [3M,+311296)
  float* V    = ws + 5 * M;                          // [5M,9M)
  float* Vtb_f= ws + 9 * M;                          // [9M,11M)
  float* braw = ws + 11 * M;                         // [11M,16M)
  unsigned short* Wqh = (unsigned short*)(ws + 9 * M);
  unsigned short* Wql = (unsigned short*)(ws + 9 * M + M / 2);
  unsigned short* Wkh = (unsigned short*)(ws + 10 * M);
  unsigned short* Wvh = (unsigned short*)(ws + 10 * M + M / 2);
  unsigned short* eh  = (unsigned short*)(ws + 11 * M);
  unsigned short* dh  = (unsigned short*)(ws + 15 * M);
  unsigned short* dl  = (unsigned short*)(ws + 15 * M + M / 2);
  unsigned short* Vtb = (unsigned short*)Vtb_f;
  float* kvpL = ws + 11 * M;
  float* kvpC = ws + 13 * M;
  float* kspL = ws + 15 * M;
  float* kspC = ws + 15 * M + 32768;
  float* vsp  = ws + 15 * M + 65536;
  // attn split-K-4 partials (all dead regions at attn time):
  float* OsP1 = ws + 5 * M;   // ex-V (consumed by trio)
  float* OsP2 = ws + 3 * M;   // ex-KsPart (consumed by trio)
  float* OsP3 = ws + 4 * M;
  float* OlS1 = ws + 6 * M;
  float* stats = ws + 7 * M;  // 4*32768 floats
  float* tail = ws + 16 * M;
  float* kvL  = tail;
  float* kvC  = tail + 131072;
  float* ksL  = tail + 262144;
  float* ksC  = tail + 264192;
  float* vmean= tail + 266240;
  float* Mbuf = tail + 317440;
  int*   sel  = (int*)(tail + 333824);
  unsigned short* Woh = (unsigned short*)ws;
  unsigned short* braw16 = (unsigned short*)(ws + M);
  float* proj = ws + 3 * M + M / 2;

  hipLaunchKernelGGL(prologue, dim3(7104), dim3(256), 17408, stream,
                     dec, enc, Wq, Wk, Wv, sidx, dh, dl, eh, Wqh, Wql, Wkh, Wvh, KsPart);
  hipLaunchKernelGGL(gemm_qkv, dim3(72, 16), dim3(256), 24576, stream,
                     dh, dl, Wqh, Wql, Q, eh, Wkh, Kb16, Wvh, V);
  hipLaunchKernelGGL(trio, dim3(1664), dim3(256), 34816, stream,
                     V, Vtb, Kb16, kvpL, kvpC, kspL, kspC, vsp, Q, KsPart, Mbuf);
  hipLaunchKernelGGL(tail2, dim3(1080), dim3(256), 4224, stream,
                     kvpL, kvpC, kspL, kspC, vsp, kvL, kvC, ksL, ksC, vmean, Mbuf, sel);
  hipLaunchKernelGGL(attn_mfma, dim3(1024), dim3(256), 0, stream, Q, Kb16, Vtb,
                     braw, OsP1, OsP2, OsP3, braw + 4 * M, OlS1, stats);
  hipLaunchKernelGGL(combine_fill, dim3(5120), dim3(256), 0, stream,
                     braw, OsP1, OsP2, OsP3, OlS1, stats, vmean, sel,
                     Q, kvL, kvC, ksL, ksC);
  hipLaunchKernelGGL(epi_cvt, dim3(5376), dim3(256), 17408, stream, Wo, Woh, braw, braw16);
  hipLaunchKernelGGL(gemm_one, dim3(40, 16), dim3(256), 24576, stream, braw16, Woh, proj);
  hipLaunchKernelGGL(combine, dim3(1024), dim3(256), 0, stream, dec, proj, rmsw, alphas,
                     (float*)d_out);
}

// Round 7
// 279.282 us; speedup vs baseline: 1.0862x; 1.0862x over previous
//
#include <hip/hip_runtime.h>
#include <math.h>

#define LDEC 512
#define LENC 2048
#define DMODEL 1024
#define NH 16
#define HD 64
#define SCALE 0.125f
#define NTOP 31
#define NSAMP 38

typedef __attribute__((ext_vector_type(8))) short bf16x8;
typedef __attribute__((ext_vector_type(4))) float f32x4;

__device__ inline float wave_sum(float v) {
#pragma unroll
  for (int m = 32; m > 0; m >>= 1) v += __shfl_xor(v, m);
  return v;
}

__device__ inline unsigned short f2bf(float x) {
  unsigned u = __float_as_uint(x);
  u += 0x7fff + ((u >> 16) & 1);  // RNE
  return (unsigned short)(u >> 16);
}
__device__ inline float bf2f(unsigned short h) {
  return __uint_as_float(((unsigned)h) << 16);
}

// async HBM -> LDS, 16 B per lane; lds base must be wave-uniform
__device__ __forceinline__ void gld16(const unsigned short* g, unsigned short* l) {
  __builtin_amdgcn_global_load_lds(
      (const __attribute__((address_space(1))) unsigned int*)g,
      (__attribute__((address_space(3))) unsigned int*)l, 16, 0, 0);
}

// XOR-swizzled LDS index (row stride 64 shorts = 128 B): kills the
// stride-128B bank-conflict pattern; col must stay within [0,64).
__device__ __forceinline__ int sws(int row, int col) {
  return row * 64 + (col ^ ((row & 7) << 3));
}

// ================== FUSED PROLOGUE: cvt_in + cvt_w3 + k_samp =================
// grid: [0,5120) cvt_in | [5120,5888) cvt_w3 | [5888,7104) k_samp split-K.
// dyn LDS 17408.
__global__ __launch_bounds__(256) void prologue(
    const float* __restrict__ dec, const float* __restrict__ enc,
    const float* __restrict__ Wq, const float* __restrict__ Wk,
    const float* __restrict__ Wv, const int* __restrict__ sidx,
    unsigned short* __restrict__ dh, unsigned short* __restrict__ dl,
    unsigned short* __restrict__ eh,
    unsigned short* __restrict__ Wqh, unsigned short* __restrict__ Wql,
    unsigned short* __restrict__ Wkh, unsigned short* __restrict__ Wvh,
    float* __restrict__ KsPart) {
  extern __shared__ char smraw[];
  int bx = blockIdx.x;
  int tid = threadIdx.x;
  if (bx < 5120) {
    // ---- cvt_in ----
    int i = bx * 256 + tid;
    if (i < 262144) {
      float4 v = ((const float4*)dec)[i];
      ushort4 h = make_ushort4(f2bf(v.x), f2bf(v.y), f2bf(v.z), f2bf(v.w));
      ushort4 l = make_ushort4(f2bf(v.x - bf2f(h.x)), f2bf(v.y - bf2f(h.y)),
                               f2bf(v.z - bf2f(h.z)), f2bf(v.w - bf2f(h.w)));
      *(ushort4*)(dh + i * 4) = h;
      *(ushort4*)(dl + i * 4) = l;
    } else {
      int j = i - 262144;
      float4 v = ((const float4*)enc)[j];
      *(ushort4*)(eh + j * 4) =
          make_ushort4(f2bf(v.x), f2bf(v.y), f2bf(v.z), f2bf(v.w));
    }
  } else if (bx < 5888) {
    // ---- cvt_w3 ----
    float (*t)[68] = (float(*)[68])smraw;
    int wb = bx - 5120;
    int which = wb >> 8, rem = wb & 255;
    const float* W = which == 0 ? Wq : (which == 1 ? Wk : Wv);
    unsigned short* Th = which == 0 ? Wqh : (which == 1 ? Wkh : Wvh);
    unsigned short* Tl = which == 0 ? Wql : nullptr;
    int k0 = (rem >> 4) * 64, n0 = (rem & 15) * 64;
#pragma unroll
    for (int i = 0; i < 4; ++i) {
      int c = tid + 256 * i;
      int r = c >> 4, c4 = (c & 15) * 4;
      float4 v = *(const float4*)(W + (size_t)(k0 + r) * DMODEL + n0 + c4);
      t[c4 + 0][r] = v.x; t[c4 + 1][r] = v.y; t[c4 + 2][r] = v.z; t[c4 + 3][r] = v.w;
    }
    __syncthreads();
#pragma unroll
    for (int i = 0; i < 4; ++i) {
      int c = tid + 256 * i;
      int n = c >> 4, k4 = (c & 15) * 4;
      float4 v = *(const float4*)&t[n][k4];
      ushort4 h = make_ushort4(f2bf(v.x), f2bf(v.y), f2bf(v.z), f2bf(v.w));
      *(ushort4*)(Th + (size_t)(n0 + n) * DMODEL + k0 + k4) = h;
      if (Tl) {
        ushort4 l = make_ushort4(f2bf(v.x - bf2f(h.x)), f2bf(v.y - bf2f(h.y)),
                                 f2bf(v.z - bf2f(h.z)), f2bf(v.w - bf2f(h.w)));
        *(ushort4*)(Tl + (size_t)(n0 + n) * DMODEL + k0 + k4) = l;
      }
    }
  } else {
    // ---- k_samp split-K (fp32; 38s x 4 col-chunks x 8 k-chunks) ----
    float* er = (float*)smraw;  // 128 floats
    int sb = bx - 5888;         // 0..1215
    int s = sb >> 5;            // 0..37
    int rem = sb & 31;
    int cchunk = rem >> 3, kc = rem & 7;
    int c = cchunk * 256 + tid;
    int srow = sidx[s];
    if (tid < 32) {
      int idx = tid * 4;
      *(float4*)&er[idx] =
          *(const float4*)(enc + (size_t)srow * DMODEL + kc * 128 + idx);
    }
    __syncthreads();
    float acc = 0.f;
    const float* wp = Wk + (size_t)(kc * 128) * DMODEL + c;
    for (int k0 = 0; k0 < 128; k0 += 16) {
      float w[16];
#pragma unroll
      for (int j = 0; j < 16; ++j) w[j] = wp[(size_t)(k0 + j) * DMODEL];
#pragma unroll
      for (int j = 0; j < 16; ++j) acc = fmaf(er[k0 + j], w[j], acc);
    }
    KsPart[(size_t)kc * (NSAMP * 1024) + s * 1024 + c] = acc;
  }
}

// ======= shared epilogue: 64x32 wave tile via LDS transpose (stride 36) ====
template <int BF16OUT>
__device__ __forceinline__ void gemm_epilogue(
    unsigned short* sm, f32x4 (&acc)[4][2], float* __restrict__ C,
    unsigned short* __restrict__ Cb, int row0, int col0, int wave, int lane) {
  const int l16 = lane & 15, quad = lane >> 4;
  float* eL = (float*)sm + wave * 576;
  const int rr = lane >> 2, cc = (lane & 3) * 8;
  const int wr = wave >> 2, wc = wave & 3;
#pragma unroll
  for (int x = 0; x < 4; ++x) {
#pragma unroll
    for (int y = 0; y < 2; ++y)
#pragma unroll
      for (int q = 0; q < 4; ++q)
        eL[(quad * 4 + q) * 36 + y * 16 + l16] = acc[x][y][q];
    float4 v0 = *(const float4*)&eL[rr * 36 + cc];
    float4 v1 = *(const float4*)&eL[rr * 36 + cc + 4];
    size_t ro = (size_t)(row0 + wr * 64 + x * 16 + rr) * DMODEL + col0 + wc * 32 + cc;
    if (BF16OUT) {
      uint2 o;
      o.x = (unsigned)f2bf(v0.x) | ((unsigned)f2bf(v0.y) << 16);
      o.y = (unsigned)f2bf(v0.z) | ((unsigned)f2bf(v0.w) << 16);
      *(uint2*)(Cb + ro) = o;
      o.x = (unsigned)f2bf(v1.x) | ((unsigned)f2bf(v1.y) << 16);
      o.y = (unsigned)f2bf(v1.z) | ((unsigned)f2bf(v1.w) << 16);
      *(uint2*)(Cb + ro + 4) = o;
    } else {
      *(float4*)(C + ro) = v0;
      *(float4*)(C + ro + 4) = v1;
    }
  }
}

// ======= 1-pass bf16 GEMM, 512 thr, wave-tile 64x32, ASYNC global->LDS ====
template <int BF16OUT>
__device__ __forceinline__ void gemm512_1p_async(
    const unsigned short* __restrict__ Ah, const unsigned short* __restrict__ Bh,
    float* __restrict__ C, unsigned short* __restrict__ Cb, int row0, int col0) {
  extern __shared__ unsigned short sm[];
  const int BUFS = 8192;
  const int tid = threadIdx.x, lane = tid & 63, wave = tid >> 6;
  const int l16 = lane & 15, quad = lane >> 4;
  const int wr = wave >> 2, wc = wave & 3;

  const int srow = wave * 16 + (lane >> 2);
  const int scol = (lane & 3) * 8;
  const unsigned short* gA = Ah + (size_t)(row0 + srow) * DMODEL + scol;
  const unsigned short* gB = Bh + (size_t)(col0 + srow) * DMODEL + scol;
  const int wofs = wave * 512;

  f32x4 acc[4][2];
#pragma unroll
  for (int x = 0; x < 4; ++x)
#pragma unroll
    for (int y = 0; y < 2; ++y) acc[x][y] = (f32x4){0.f, 0.f, 0.f, 0.f};

  gld16(gA, sm + wofs);
  gld16(gB, sm + 4096 + wofs);
  __syncthreads();

  for (int it = 0; it < 32; ++it) {
    const unsigned short* cur = sm + (it & 1) * BUFS;
    if (it < 31) {
      int ko = (it + 1) * 32;
      unsigned short* nxt = sm + ((it + 1) & 1) * BUFS;
      gld16(gA + ko, nxt + wofs);
      gld16(gB + ko, nxt + 4096 + wofs);
    }
    bf16x8 a[4], b[2];
#pragma unroll
    for (int x = 0; x < 4; ++x)
      a[x] = *(const bf16x8*)&cur[(wr * 64 + x * 16 + l16) * 32 + quad * 8];
#pragma unroll
    for (int y = 0; y < 2; ++y)
      b[y] = *(const bf16x8*)&cur[4096 + (wc * 32 + y * 16 + l16) * 32 + quad * 8];
#pragma unroll
    for (int x = 0; x < 4; ++x)
#pragma unroll
      for (int y = 0; y < 2; ++y)
        acc[x][y] = __builtin_amdgcn_mfma_f32_16x16x32_bf16(a[x], b[y], acc[x][y], 0, 0, 0);
    __syncthreads();
  }
  gemm_epilogue<BF16OUT>(sm, acc, C, Cb, row0, col0, wave, lane);
}

// ======= 3-pass hi/lo GEMM, 512 thr, padded dbuf =====
__device__ __forceinline__ void gemm512_3p(
    const unsigned short* __restrict__ Ah, const unsigned short* __restrict__ Al,
    const unsigned short* __restrict__ Bh, const unsigned short* __restrict__ Bl,
    float* __restrict__ C, int row0, int col0) {
  extern __shared__ unsigned short sm[];
  const int BUFS = 20480;
  const int tid = threadIdx.x, lane = tid & 63, wave = tid >> 6;
  const int l16 = lane & 15, quad = lane >> 4;
  const int wr = wave >> 2, wc = wave & 3;

  const int r = tid >> 2, kc = tid & 3;
  const unsigned short* gAh = Ah + (size_t)(row0 + r) * DMODEL + kc * 8;
  const unsigned short* gBh = Bh + (size_t)(col0 + r) * DMODEL + kc * 8;
  const unsigned short* gAl = Al + (size_t)(row0 + r) * DMODEL + kc * 8;
  const unsigned short* gBl = Bl + (size_t)(col0 + r) * DMODEL + kc * 8;
  const int lofs = r * 40 + kc * 8;

  f32x4 acc[4][2];
#pragma unroll
  for (int x = 0; x < 4; ++x)
#pragma unroll
    for (int y = 0; y < 2; ++y) acc[x][y] = (f32x4){0.f, 0.f, 0.f, 0.f};

  uint4 pah = *(const uint4*)gAh, pbh = *(const uint4*)gBh;
  uint4 pal = *(const uint4*)gAl, pbl = *(const uint4*)gBl;
  *(uint4*)&sm[lofs] = pah;
  *(uint4*)&sm[5120 + lofs] = pbh;
  *(uint4*)&sm[10240 + lofs] = pal;
  *(uint4*)&sm[15360 + lofs] = pbl;
  pah = *(const uint4*)(gAh + 32);
  pbh = *(const uint4*)(gBh + 32);
  pal = *(const uint4*)(gAl + 32);
  pbl = *(const uint4*)(gBl + 32);
  __syncthreads();

  for (int it = 0; it < 32; ++it) {
    const unsigned short* cur = sm + (it & 1) * BUFS;
    bf16x8 ah[4], bh[2], al[4], bl[2];
#pragma unroll
    for (int x = 0; x < 4; ++x) {
      ah[x] = *(const bf16x8*)&cur[(wr * 64 + x * 16 + l16) * 40 + quad * 8];
      al[x] = *(const bf16x8*)&cur[10240 + (wr * 64 + x * 16 + l16) * 40 + quad * 8];
    }
#pragma unroll
    for (int y = 0; y < 2; ++y) {
      bh[y] = *(const bf16x8*)&cur[5120 + (wc * 32 + y * 16 + l16) * 40 + quad * 8];
      bl[y] = *(const bf16x8*)&cur[15360 + (wc * 32 + y * 16 + l16) * 40 + quad * 8];
    }
#pragma unroll
    for (int x = 0; x < 4; ++x)
#pragma unroll
      for (int y = 0; y < 2; ++y) {
        acc[x][y] = __builtin_amdgcn_mfma_f32_16x16x32_bf16(ah[x], bh[y], acc[x][y], 0, 0, 0);
        acc[x][y] = __builtin_amdgcn_mfma_f32_16x16x32_bf16(ah[x], bl[y], acc[x][y], 0, 0, 0);
        acc[x][y] = __builtin_amdgcn_mfma_f32_16x16x32_bf16(al[x], bh[y], acc[x][y], 0, 0, 0);
      }
    if (it < 31) {
      unsigned short* nxt = sm + ((it + 1) & 1) * BUFS;
      *(uint4*)&nxt[lofs] = pah;
      *(uint4*)&nxt[5120 + lofs] = pbh;
      *(uint4*)&nxt[10240 + lofs] = pal;
      *(uint4*)&nxt[15360 + lofs] = pbl;
      if (it < 30) {
        int ko = (it + 2) * 32;
        pah = *(const uint4*)(gAh + ko);
        pbh = *(const uint4*)(gBh + ko);
        pal = *(const uint4*)(gAl + ko);
        pbl = *(const uint4*)(gBl + ko);
      }
    }
    __syncthreads();
  }
  gemm_epilogue<0>(sm, acc, C, nullptr, row0, col0, wave, lane);
}

// merged Q(3-pass) + K(1-pass async, bf16-out) + V(1-pass async)
__global__ __launch_bounds__(512, 4) void gemm_qkv(
    const unsigned short* __restrict__ dh, const unsigned short* __restrict__ dl,
    const unsigned short* __restrict__ Wqh, const unsigned short* __restrict__ Wql,
    float* __restrict__ Q,
    const unsigned short* __restrict__ eh, const unsigned short* __restrict__ Wkh,
    unsigned short* __restrict__ Kb16,
    const unsigned short* __restrict__ Wvh, float* __restrict__ V) {
  int bx = blockIdx.x;
  if (bx < 8)
    gemm512_3p(dh, dl, Wqh, Wql, Q, bx * 128, blockIdx.y * 128);
  else if (bx < 40)
    gemm512_1p_async<1>(eh, Wkh, nullptr, Kb16, (bx - 8) * 128, blockIdx.y * 128);
  else
    gemm512_1p_async<0>(eh, Wvh, V, nullptr, (bx - 40) * 128, blockIdx.y * 128);
}

__global__ __launch_bounds__(512, 4) void gemm_one(
    const unsigned short* __restrict__ Ah, const unsigned short* __restrict__ Bh,
    float* __restrict__ C) {
  gemm512_1p_async<0>(Ah, Bh, C, nullptr, blockIdx.x * 128, blockIdx.y * 128);
}

// ============ FUSED TRIO: cvt_vt + lin_cos_stats(MFMA) + pp_scores ==========
// grid: [0,1024) cvt_vt | [1024,1536) lin_cos_stats | [1536,1664) pp_scores.
// dyn LDS 34816 B (max branch: lin_cos 34560).
__global__ __launch_bounds__(256, 4) void trio(
    const float* __restrict__ V, unsigned short* __restrict__ Vt,
    const unsigned short* __restrict__ Kb,
    float* __restrict__ kvpL, float* __restrict__ kvpC,
    float* __restrict__ kspL, float* __restrict__ kspC, float* __restrict__ vsp,
    const float* __restrict__ Q, const float* __restrict__ KsPart,
    float* __restrict__ Mout) {
  extern __shared__ char smraw[];
  int bx0 = blockIdx.x;
  int tid = threadIdx.x;
  if (bx0 < 1024) {
    // ---- cvt_vt ----
    unsigned short (*tile)[72] = (unsigned short(*)[72])smraw;
    int bh = bx0 >> 5;
    int s0 = (bx0 & 31) * 64;
    int b = bh >> 4, h = bh & 15;
#pragma unroll
    for (int i = 0; i < 4; ++i) {
      int c = tid + 256 * i;
      int s = c >> 4, d4 = (c & 15) * 4;
      float4 v = *(const float4*)(V + (size_t)(b * LENC + s0 + s) * DMODEL + h * HD + d4);
      tile[d4 + 0][s] = f2bf(v.x);
      tile[d4 + 1][s] = f2bf(v.y);
      tile[d4 + 2][s] = f2bf(v.z);
      tile[d4 + 3][s] = f2bf(v.w);
    }
    __syncthreads();
#pragma unroll
    for (int i = 0; i < 2; ++i) {
      int c = tid + 256 * i;
      int d = c >> 3, soff = (c & 7) * 8;
      uint4 o = *(const uint4*)&tile[d][soff];
      *(uint4*)(Vt + (size_t)(bh * 64 + d) * LENC + s0 + soff) = o;
    }
  } else if (bx0 < 1536) {
    // ---- lin_cos_stats via hi/lo bf16 MFMA 3-pass ----
    float (*Kt)[65] = (float(*)[65])smraw;                          // 16640 B
    unsigned int (*Vu)[65] = (unsigned int(*)[65])(smraw + 16640);  // 16640 B
    float* nrm = (float*)(smraw + 33280);                           //   256 B
    float4* vred = (float4*)(smraw + 33536);                        //  1024 B
    int bx = bx0 - 1024;
    int bh = bx >> 4, part = bx & 15;
    int b = bh >> 4, h = bh & 15;
    const int lane = tid & 63, wv = tid >> 6;
    const int l16 = lane & 15, quad = lane >> 4;
    const int dblk = wv * 16;
    const unsigned short* Kg = Kb + (size_t)(b * LENC + part * 128) * DMODEL + h * HD;
    const float* Vg = V + (size_t)(b * LENC + part * 128) * DMODEL + h * HD;
    const int sK = tid >> 2, d16 = (tid & 3) * 16;
    const int sVb = tid >> 4, v4 = (tid & 15) * 4;

    f32x4 accL[4], accC[4];
#pragma unroll
    for (int n = 0; n < 4; ++n) {
      accL[n] = (f32x4){0.f, 0.f, 0.f, 0.f};
      accC[n] = (f32x4){0.f, 0.f, 0.f, 0.f};
    }
    float kslp = 0.f, kscp = 0.f;
    float4 vpart = make_float4(0.f, 0.f, 0.f, 0.f);

    for (int ch = 0; ch < 2; ++ch) {
      const int s0 = ch * 64;
      // stage K (bf16 -> f32) + row sumsq -> nrm
      {
        const unsigned short* kr = Kg + (size_t)(s0 + sK) * DMODEL + d16;
        uint4 p0 = *(const uint4*)kr;
        uint4 p1 = *(const uint4*)(kr + 8);
        float kvv[16];
        kvv[0] = __uint_as_float(p0.x << 16);
        kvv[1] = __uint_as_float(p0.x & 0xffff0000u);
        kvv[2] = __uint_as_float(p0.y << 16);
        kvv[3] = __uint_as_float(p0.y & 0xffff0000u);
        kvv[4] = __uint_as_float(p0.z << 16);
        kvv[5] = __uint_as_float(p0.z & 0xffff0000u);
        kvv[6] = __uint_as_float(p0.w << 16);
        kvv[7] = __uint_as_float(p0.w & 0xffff0000u);
        kvv[8] = __uint_as_float(p1.x << 16);
        kvv[9] = __uint_as_float(p1.x & 0xffff0000u);
        kvv[10] = __uint_as_float(p1.y << 16);
        kvv[11] = __uint_as_float(p1.y & 0xffff0000u);
        kvv[12] = __uint_as_float(p1.z << 16);
        kvv[13] = __uint_as_float(p1.z & 0xffff0000u);
        kvv[14] = __uint_as_float(p1.w << 16);
        kvv[15] = __uint_as_float(p1.w & 0xffff0000u);
        float ss = 0.f;
#pragma unroll
        for (int j = 0; j < 16; ++j) ss = fmaf(kvv[j], kvv[j], ss);
        ss += __shfl_xor(ss, 1);
        ss += __shfl_xor(ss, 2);
        if ((tid & 3) == 0) nrm[sK] = sqrtf(ss);
#pragma unroll
        for (int j = 0; j < 16; ++j) Kt[sK][d16 + j] = kvv[j];
      }
      // stage V (f32 -> packed hi|lo bf16) + column-sum partial
#pragma unroll
      for (int i = 0; i < 4; ++i) {
        int sv = sVb + 16 * i;
        float4 vv = *(const float4*)(Vg + (size_t)(s0 + sv) * DMODEL + v4);
        vpart.x += vv.x; vpart.y += vv.y; vpart.z += vv.z; vpart.w += vv.w;
        unsigned short h0 = f2bf(vv.x), h1 = f2bf(vv.y);
        unsigned short h2 = f2bf(vv.z), h3 = f2bf(vv.w);
        Vu[sv][v4 + 0] = ((unsigned)h0 << 16) | (unsigned)f2bf(vv.x - bf2f(h0));
        Vu[sv][v4 + 1] = ((unsigned)h1 << 16) | (unsigned)f2bf(vv.y - bf2f(h1));
        Vu[sv][v4 + 2] = ((unsigned)h2 << 16) | (unsigned)f2bf(vv.z - bf2f(h2));
        Vu[sv][v4 + 3] = ((unsigned)h3 << 16) | (unsigned)f2bf(vv.w - bf2f(h3));
      }
      __syncthreads();
      // fragment build + MFMA
#pragma unroll
      for (int kk = 0; kk < 2; ++kk) {
        const int sb = kk * 32 + quad * 8;
        bf16x8 aLh, aLl, aCh, aCl;
#pragma unroll
        for (int j = 0; j < 8; ++j) {
          float kval = Kt[sb + j][dblk + l16];
          float nn = nrm[sb + j];
          float kfl = kval > 0.f ? kval + 1.f : __expf(kval);
          float kn = kval / fmaxf(nn, 1e-12f);
          float kfc = fmaxf(kn, 0.f) + 1e-6f;
          kslp += kfl;
          kscp += kfc;
          unsigned short hL = f2bf(kfl);
          aLh[j] = hL;
          aLl[j] = f2bf(kfl - bf2f(hL));
          unsigned short hC = f2bf(kfc);
          aCh[j] = hC;
          aCl[j] = f2bf(kfc - bf2f(hC));
        }
#pragma unroll
        for (int n = 0; n < 4; ++n) {
          bf16x8 bhv, blv;
#pragma unroll
          for (int j = 0; j < 8; ++j) {
            unsigned uv = Vu[sb + j][n * 16 + l16];
            bhv[j] = (short)(unsigned short)(uv >> 16);
            blv[j] = (short)(unsigned short)(uv & 0xffffu);
          }
          accL[n] = __builtin_amdgcn_mfma_f32_16x16x32_bf16(aLh, bhv, accL[n], 0, 0, 0);
          accL[n] = __builtin_amdgcn_mfma_f32_16x16x32_bf16(aLh, blv, accL[n], 0, 0, 0);
          accL[n] = __builtin_amdgcn_mfma_f32_16x16x32_bf16(aLl, bhv, accL[n], 0, 0, 0);
          accC[n] = __builtin_amdgcn_mfma_f32_16x16x32_bf16(aCh, bhv, accC[n], 0, 0, 0);
          accC[n] = __builtin_amdgcn_mfma_f32_16x16x32_bf16(aCh, blv, accC[n], 0, 0, 0);
          accC[n] = __builtin_amdgcn_mfma_f32_16x16x32_bf16(aCl, bhv, accC[n], 0, 0, 0);
        }
      }
      __syncthreads();
    }
    // outputs: kv partials (D layout: row = quad*4+q, col = l16)
    const int obase = part * 131072 + bh * 4096;
#pragma unroll
    for (int n = 0; n < 4; ++n)
#pragma unroll
      for (int q = 0; q < 4; ++q) {
        int o = obase + (dblk + quad * 4 + q) * 64 + n * 16 + l16;
        kvpL[o] = accL[n][q];
        kvpC[o] = accC[n][q];
      }
    kslp += __shfl_xor(kslp, 16);
    kslp += __shfl_xor(kslp, 32);
    kscp += __shfl_xor(kscp, 16);
    kscp += __shfl_xor(kscp, 32);
    if (quad == 0) {
      kspL[part * 2048 + bh * 64 + dblk + l16] = kslp;
      kspC[part * 2048 + bh * 64 + dblk + l16] = kscp;
    }
    vpart.x += __shfl_xor(vpart.x, 16); vpart.x += __shfl_xor(vpart.x, 32);
    vpart.y += __shfl_xor(vpart.y, 16); vpart.y += __shfl_xor(vpart.y, 32);
    vpart.z += __shfl_xor(vpart.z, 16); vpart.z += __shfl_xor(vpart.z, 32);
    vpart.w += __shfl_xor(vpart.w, 16); vpart.w += __shfl_xor(vpart.w, 32);
    if (quad == 0) vred[wv * 16 + l16] = vpart;
    __syncthreads();
    if (tid < 16) {
      float4 a0 = vred[tid], a1 = vred[16 + tid];
      float4 a2 = vred[32 + tid], a3 = vred[48 + tid];
      float4 s = make_float4(a0.x + a1.x + a2.x + a3.x, a0.y + a1.y + a2.y + a3.y,
                             a0.z + a1.z + a2.z + a3.z, a0.w + a1.w + a2.w + a3.w);
      *(float4*)&vsp[part * 2048 + bh * 64 + tid * 4] = s;
    }
  } else {
    // ---- pp_scores (fp32; sums the 8 split-K partials in fixed order) ----
    float (*ksL)[65] = (float(*)[65])smraw;  // 38*65*4 = 9880 B
    int bx = bx0 - 1536;
    int bh = bx >> 2, chunk = bx & 3;
    int b = bh >> 4, h = bh & 15;
    int t0 = chunk * 128;
    const float* Qb = Q + (b * LDEC) * DMODEL + h * HD;
    for (int slot = tid; slot < NSAMP * 16; slot += 256) {
      int r = slot >> 4, c4 = slot & 15;
      const float* kp = KsPart + r * 1024 + h * HD + c4 * 4;
      float4 kx = *(const float4*)kp;
#pragma unroll
      for (int p = 1; p < 8; ++p) {
        float4 k2 = *(const float4*)(kp + (size_t)p * (NSAMP * 1024));
        kx.x += k2.x; kx.y += k2.y; kx.z += k2.z; kx.w += k2.w;
      }
      ksL[r][c4 * 4 + 0] = kx.x; ksL[r][c4 * 4 + 1] = kx.y;
      ksL[r][c4 * 4 + 2] = kx.z; ksL[r][c4 * 4 + 3] = kx.w;
    }
    __syncthreads();
    if (tid < 128) {
      float qr[64];
      const float* qrow = Qb + (size_t)(t0 + tid) * DMODEL;
#pragma unroll
      for (int d4 = 0; d4 < 16; ++d4)
        *(float4*)&qr[d4 * 4] = *(const float4*)(qrow + d4 * 4);
      float mx = -INFINITY, sm = 0.f;
      for (int j = 0; j < NSAMP; ++j) {
        float s = 0.f;
#pragma unroll
        for (int d = 0; d < 64; ++d) s = fmaf(qr[d], ksL[j][d], s);
        s *= SCALE;
        mx = fmaxf(mx, s);
        sm += s;
      }
      Mout[bh * LDEC + t0 + tid] = mx - sm / (float)NSAMP;
    }
  }
}

// ============ FUSED TAIL: reduce_all + pp_topk ==============================
// grid: [0,1048) reduce_all | [1048,1080) pp_topk. dyn LDS 4224 B.
__global__ __launch_bounds__(256) void tail2(
    const float* __restrict__ kvpL, const float* __restrict__ kvpC,
    const float* __restrict__ kspL, const float* __restrict__ kspC,
    const float* __restrict__ vsp, float* __restrict__ kvL,
    float* __restrict__ kvC, float* __restrict__ ksL,
    float* __restrict__ ksC, float* __restrict__ vmean,
    const float* __restrict__ Mbuf, int* __restrict__ sel) {
  extern __shared__ char smraw[];
  int bx = blockIdx.x;
  int tid = threadIdx.x;
  if (bx < 1048) {
    int i = bx * 256 + tid;
    if (i < 131072) {
      float s = 0.f;
#pragma unroll
      for (int p = 0; p < 16; ++p) s += kvpL[p * 131072 + i];
      kvL[i] = s;
    } else if (i < 262144) {
      int j = i - 131072;
      float s = 0.f;
#pragma unroll
      for (int p = 0; p < 16; ++p) s += kvpC[p * 131072 + j];
      kvC[j] = s;
    } else if (i < 268288) {
      int j = i - 262144;
      int which = j >> 11, jj = j & 2047;
      const float* src = which == 0 ? kspL : (which == 1 ? kspC : vsp);
      float s = 0.f;
#pragma unroll
      for (int p = 0; p < 16; ++p) s += src[p * 2048 + jj];
      if (which == 0) ksL[jj] = s;
      else if (which == 1) ksC[jj] = s;
      else vmean[jj] = s * (1.f / 2048.f);
    }
  } else {
    // ---- pp_topk (tie -> lower index) ----
    float* vals = (float*)smraw;
    int* flag = (int*)(smraw + 2048);
    float* wvs = (float*)(smraw + 4096);
    int* wis = (int*)(smraw + 4112);
    int bh = bx - 1048;
    int lane = tid & 63, g = tid >> 6;
    vals[tid] = Mbuf[bh * 512 + tid];
    vals[tid + 256] = Mbuf[bh * 512 + tid + 256];
    flag[tid] = 0; flag[tid + 256] = 0;
    __syncthreads();
    for (int it = 0; it < NTOP; ++it) {
      float v0 = vals[tid]; int i0 = tid;
      float v1 = vals[tid + 256];
      if (v1 > v0) { v0 = v1; i0 = tid + 256; }
#pragma unroll
      for (int mm = 32; mm > 0; mm >>= 1) {
        float ov = __shfl_xor(v0, mm);
        int oi = __shfl_xor(i0, mm);
        if (ov > v0 || (ov == v0 && oi < i0)) { v0 = ov; i0 = oi; }
      }
      if (lane == 0) { wvs[g] = v0; wis[g] = i0; }
      __syncthreads();
      if (tid == 0) {
        float bv = wvs[0]; int bi = wis[0];
#pragma unroll
        for (int w = 1; w < 4; ++w)
          if (wvs[w] > bv || (wvs[w] == bv && wis[w] < bi)) { bv = wvs[w]; bi = wis[w]; }
        vals[bi] = -INFINITY;
        flag[bi] = 1;
      }
      __syncthreads();
    }
    sel[bh * 512 + tid] = flag[tid];
    sel[bh * 512 + tid + 256] = flag[tid + 256];
  }
}

// ---------------- MFMA flash attention, split-K 4-way + XCD swizzle ---------
// LDS 40960 B (swizzled, conflict-free); row sums via MFMA ones-column trick.
__global__ __launch_bounds__(256) void attn_mfma(
    const float* __restrict__ Qf, const unsigned short* __restrict__ Kb,
    const unsigned short* __restrict__ Vt,
    float* __restrict__ OsP0, float* __restrict__ OsP1,
    float* __restrict__ OsP2, float* __restrict__ OsP3,
    float* __restrict__ OlS0, float* __restrict__ OlS1,
    float* __restrict__ st) {
  __shared__ unsigned short Ks[2][4096];
  __shared__ unsigned short Vs[2][4096];
  __shared__ unsigned short Ps[4][1024];
  const int tid = threadIdx.x;
  const int wave = tid >> 6, lane = tid & 63;
  const int l16 = lane & 15, quad = lane >> 4;
  const int bx = blockIdx.x;
  const int xcd = bx & 7, sub = bx >> 3;
  const int qt = sub & 7, qr = (sub >> 3) & 3, grp = sub >> 5;
  const int bh = xcd + 8 * grp;
  const int b = bh >> 4, h = bh & 15;
  const int tbase = qt * 64 + wave * 16;
  const int sbase = qr * 512;

  const float* qrow = Qf + (size_t)(b * LDEC + tbase + l16) * DMODEL + h * HD + quad * 8;
  bf16x8 qa0, qa1;
  {
    float4 a0 = *(const float4*)qrow, a1 = *(const float4*)(qrow + 4);
    float4 a2 = *(const float4*)(qrow + 32), a3 = *(const float4*)(qrow + 36);
    qa0[0] = f2bf(a0.x * SCALE); qa0[1] = f2bf(a0.y * SCALE);
    qa0[2] = f2bf(a0.z * SCALE); qa0[3] = f2bf(a0.w * SCALE);
    qa0[4] = f2bf(a1.x * SCALE); qa0[5] = f2bf(a1.y * SCALE);
    qa0[6] = f2bf(a1.z * SCALE); qa0[7] = f2bf(a1.w * SCALE);
    qa1[0] = f2bf(a2.x * SCALE); qa1[1] = f2bf(a2.y * SCALE);
    qa1[2] = f2bf(a2.z * SCALE); qa1[3] = f2bf(a2.w * SCALE);
    qa1[4] = f2bf(a3.x * SCALE); qa1[5] = f2bf(a3.y * SCALE);
    qa1[6] = f2bf(a3.z * SCALE); qa1[7] = f2bf(a3.w * SCALE);
  }

  // ones B-fragment: row-sum of P via MFMA (D col all equal)
  bf16x8 bone;
#pragma unroll
  for (int j = 0; j < 8; ++j) bone[j] = (short)0x3f80;

  int tA = tbase + l16;
  int cA = min(4 * tA, LENC - 1);
  int loA = max(cA - 256, 0), hiA = min(cA + 256, LENC - 1);
  const int loW = max(4 * tbase - 256, 0);
  const int hiW = min(4 * (tbase + 15) + 256, LENC - 1);
  const bool blockAny = (sbase <= hiW) && (sbase + 511 >= loW);

  f32x4 Os[4], Ol[4], Ssum, Slsum;
#pragma unroll
  for (int n = 0; n < 4; ++n) {
    Os[n] = (f32x4){0.f, 0.f, 0.f, 0.f};
    Ol[n] = (f32x4){0.f, 0.f, 0.f, 0.f};
  }
  Ssum = (f32x4){0.f, 0.f, 0.f, 0.f};
  Slsum = (f32x4){0.f, 0.f, 0.f, 0.f};

  const int c0 = tid, c1 = tid + 256;
  const unsigned short* kg0 = Kb + (size_t)(b * LENC + sbase + (c0 >> 3)) * DMODEL + h * HD + (c0 & 7) * 8;
  const unsigned short* kg1 = Kb + (size_t)(b * LENC + sbase + (c1 >> 3)) * DMODEL + h * HD + (c1 & 7) * 8;
  const unsigned short* vg0 = Vt + (size_t)(bh * 64 + (c0 >> 3)) * LENC + sbase + (c0 & 7) * 8;
  const unsigned short* vg1 = Vt + (size_t)(bh * 64 + (c1 >> 3)) * LENC + sbase + (c1 & 7) * 8;
  const int of0 = sws(c0 >> 3, (c0 & 7) * 8);
  const int of1 = sws(c1 >> 3, (c1 & 7) * 8);

  uint4 pk0, pk1, pv0, pv1;
  pk0 = *(const uint4*)kg0; pk1 = *(const uint4*)kg1;
  pv0 = *(const uint4*)vg0; pv1 = *(const uint4*)vg1;
  *(uint4*)&Ks[0][of0] = pk0; *(uint4*)&Ks[0][of1] = pk1;
  *(uint4*)&Vs[0][of0] = pv0; *(uint4*)&Vs[0][of1] = pv1;
  __syncthreads();

  for (int it = 0; it < 8; ++it) {
    const int cur = it & 1;
    const int s0 = sbase + it * 64;
    const bool anyL = (s0 <= hiW) && (s0 + 63 >= loW);
    if (it < 7) {
      pk0 = *(const uint4*)(kg0 + (size_t)(it + 1) * 64 * DMODEL);
      pk1 = *(const uint4*)(kg1 + (size_t)(it + 1) * 64 * DMODEL);
      pv0 = *(const uint4*)(vg0 + (it + 1) * 64);
      pv1 = *(const uint4*)(vg1 + (it + 1) * 64);
    }
    const unsigned short* K_ = Ks[cur];
    const unsigned short* V_ = Vs[cur];

    f32x4 S[4];
#pragma unroll
    for (int n = 0; n < 4; ++n) {
      bf16x8 bk0 = *(const bf16x8*)&K_[sws(n * 16 + l16, quad * 8)];
      bf16x8 bk1 = *(const bf16x8*)&K_[sws(n * 16 + l16, 32 + quad * 8)];
      f32x4 z = (f32x4){0.f, 0.f, 0.f, 0.f};
      z = __builtin_amdgcn_mfma_f32_16x16x32_bf16(qa0, bk0, z, 0, 0, 0);
      S[n] = __builtin_amdgcn_mfma_f32_16x16x32_bf16(qa1, bk1, z, 0, 0, 0);
    }

    unsigned short* Pw = Ps[wave];
#pragma unroll
    for (int n = 0; n < 4; ++n)
#pragma unroll
      for (int r = 0; r < 4; ++r)
        Pw[sws(quad * 4 + r, n * 16 + l16)] = f2bf(__expf(S[n][r]));
    bf16x8 aP0 = *(const bf16x8*)&Pw[sws(l16, quad * 8)];
    bf16x8 aP1 = *(const bf16x8*)&Pw[sws(l16, 32 + quad * 8)];
    // row sums (softmax denominators) via ones-column MFMA
    Ssum = __builtin_amdgcn_mfma_f32_16x16x32_bf16(aP0, bone, Ssum, 0, 0, 0);
    Ssum = __builtin_amdgcn_mfma_f32_16x16x32_bf16(aP1, bone, Ssum, 0, 0, 0);
#pragma unroll
    for (int n = 0; n < 4; ++n) {
      bf16x8 bv0 = *(const bf16x8*)&V_[sws(n * 16 + l16, quad * 8)];
      bf16x8 bv1 = *(const bf16x8*)&V_[sws(n * 16 + l16, 32 + quad * 8)];
      Os[n] = __builtin_amdgcn_mfma_f32_16x16x32_bf16(aP0, bv0, Os[n], 0, 0, 0);
      Os[n] = __builtin_amdgcn_mfma_f32_16x16x32_bf16(aP1, bv1, Os[n], 0, 0, 0);
    }
    if (anyL) {
      bf16x8 aL0 = aP0, aL1 = aP1;
#pragma unroll
      for (int j = 0; j < 8; ++j) {
        int sc = s0 + quad * 8 + j;
        if (sc < loA || sc > hiA) aL0[j] = 0;
        if (sc + 32 < loA || sc + 32 > hiA) aL1[j] = 0;
      }
      Slsum = __builtin_amdgcn_mfma_f32_16x16x32_bf16(aL0, bone, Slsum, 0, 0, 0);
      Slsum = __builtin_amdgcn_mfma_f32_16x16x32_bf16(aL1, bone, Slsum, 0, 0, 0);
#pragma unroll
      for (int n = 0; n < 4; ++n) {
        bf16x8 bv0 = *(const bf16x8*)&V_[sws(n * 16 + l16, quad * 8)];
        bf16x8 bv1 = *(const bf16x8*)&V_[sws(n * 16 + l16, 32 + quad * 8)];
        Ol[n] = __builtin_amdgcn_mfma_f32_16x16x32_bf16(aL0, bv0, Ol[n], 0, 0, 0);
        Ol[n] = __builtin_amdgcn_mfma_f32_16x16x32_bf16(aL1, bv1, Ol[n], 0, 0, 0);
      }
    }
    // single barrier per iteration: all reads of buffer (1-cur) completed
    // before the previous iteration's barrier, so writing it now is safe.
    if (it < 7) {
      unsigned short* KL = Ks[1 - cur];
      unsigned short* VL = Vs[1 - cur];
      *(uint4*)&KL[of0] = pk0; *(uint4*)&KL[of1] = pk1;
      *(uint4*)&VL[of0] = pv0; *(uint4*)&VL[of1] = pv1;
    }
    __syncthreads();
  }

  float* osp = qr == 0 ? OsP0 : (qr == 1 ? OsP1 : (qr == 2 ? OsP2 : OsP3));
  float* olp = (qr & 1) ? OlS1 : OlS0;
  float* sp = st + qr * 32768;
#pragma unroll
  for (int r = 0; r < 4; ++r) {
    int t = tbase + quad * 4 + r;
#pragma unroll
    for (int n = 0; n < 4; ++n) {
      size_t o = (size_t)(b * LDEC + t) * DMODEL + h * HD + n * 16 + l16;
      osp[o] = Os[n][r];
      if (blockAny) olp[o] = Ol[n][r];
    }
    if (l16 == 0) {
      int sr = bh * 512 + t;
      sp[sr] = Ssum[r];
      sp[16384 + sr] = Slsum[r];
    }
  }
}

// fused: split-K-4 combine + probsparse fill + lin/cos apply + Wo cvt.
// Emits bf16 DIRECTLY into b16 (the gemm_one input) -> epi_cvt eliminated.
// grid: [0,1024) combine | [1024,5120) lin_cos | [5120,5376) cvt_w(Wo).
// dyn LDS 17408 (Wo branch).
__global__ __launch_bounds__(256) void combine_fill(
    const float* __restrict__ braw, const float* __restrict__ P1,
    const float* __restrict__ P2, const float* __restrict__ P3,
    const float* __restrict__ L1, const float* __restrict__ st,
    const float* __restrict__ vmean, const int* __restrict__ sel,
    const float* __restrict__ Q, const float* __restrict__ kvL,
    const float* __restrict__ kvC, const float* __restrict__ ksL,
    const float* __restrict__ ksC,
    unsigned short* __restrict__ b16, const float* __restrict__ Wo,
    unsigned short* __restrict__ Woh) {
  extern __shared__ char smraw[];
  __shared__ float sh[2][4][64];
  int bx0 = blockIdx.x;
  int tid = threadIdx.x;
  if (bx0 < 1024) {
    int i4 = bx0 * 256 + tid;
    int i = i4 * 4;
    int col = i & 1023, bt = i >> 10;
    int t = bt & 511, b = bt >> 9, h = col >> 6, d = col & 63;
    int bh = b * 16 + h;
    int sr = bh * 512 + t;
    float iS = 1.f / (st[sr] + st[32768 + sr] + st[65536 + sr] + st[98304 + sr]);
    float iL = 1.f / (st[16384 + sr] + st[49152 + sr] + st[81920 + sr] + st[114688 + sr]);
    float4 s0 = *(const float4*)(braw + i);
    float4 s1 = *(const float4*)(P1 + i);
    float4 s2 = *(const float4*)(P2 + i);
    float4 s3 = *(const float4*)(P3 + i);
    // local-branch: row t's window touches quarters q0..q1 (q1-q0 <= 1);
    // quarter q wrote parity slot q&1 (slot0 = braw+4M, slot1 = L1).
    int c = min(4 * t, LENC - 1);
    int lo = max(c - 256, 0), hi = min(c + 256, LENC - 1);
    int q0 = lo >> 9, q1 = hi >> 9;
    const float* Lp0 = (q0 & 1) ? L1 : (braw + 4194304);
    float4 l = *(const float4*)(Lp0 + i);
    if (q1 != q0) {
      const float* Lp1 = (q1 & 1) ? L1 : (braw + 4194304);
      float4 l2 = *(const float4*)(Lp1 + i);
      l.x += l2.x; l.y += l2.y; l.z += l2.z; l.w += l2.w;
    }
    float4 os = make_float4((s0.x + s1.x + s2.x + s3.x) * iS,
                            (s0.y + s1.y + s2.y + s3.y) * iS,
                            (s0.z + s1.z + s2.z + s3.z) * iS,
                            (s0.w + s1.w + s2.w + s3.w) * iS);
    float4 ol = make_float4(l.x * iL, l.y * iL, l.z * iL, l.w * iL);
    float4 pp = sel[sr] ? os : *(const float4*)(vmean + bh * 64 + d);
    uint2 o2;
    o2.x = (unsigned)f2bf(os.x) | ((unsigned)f2bf(os.y) << 16);
    o2.y = (unsigned)f2bf(os.z) | ((unsigned)f2bf(os.w) << 16);
    *(uint2*)(b16 + i) = o2;
    o2.x = (unsigned)f2bf(pp.x) | ((unsigned)f2bf(pp.y) << 16);
    o2.y = (unsigned)f2bf(pp.z) | ((unsigned)f2bf(pp.w) << 16);
    *(uint2*)(b16 + 2097152 + i) = o2;
    o2.x = (unsigned)f2bf(ol.x) | ((unsigned)f2bf(ol.y) << 16);
    o2.y = (unsigned)f2bf(ol.z) | ((unsigned)f2bf(ol.w) << 16);
    *(uint2*)(b16 + 4194304 + i) = o2;
  } else if (bx0 < 5120) {
    // ---- lin_cos_apply (bf16 direct out) ----
    int lane = tid & 63, g = tid >> 6;
    int row = (bx0 - 1024) * 4 + g;
    int bh = row >> 9, t = row & 511;
    int b = bh >> 4, h = bh & 15;
    float qv = Q[(b * LDEC + t) * DMODEL + h * HD + lane];
    float x = qv * SCALE;
    float qfl = x > 0.f ? x + 1.f : __expf(x);
    float qnorm = sqrtf(wave_sum(qv * qv));
    float qn = qv / fmaxf(qnorm, 1e-12f);
    float qfc = fmaxf(qn, 0.f) + 1e-6f;
    sh[0][g][lane] = qfl;
    sh[1][g][lane] = qfc;
    float denL = fmaxf(wave_sum(qfl * ksL[bh * 64 + lane]), 1e-6f);
    float denC = fmaxf(wave_sum(qfc * ksC[bh * 64 + lane]), 1e-6f);
    const float* kvLb = kvL + bh * 4096;
    const float* kvCb = kvC + bh * 4096;
    float aL = 0.f, aC = 0.f;
#pragma unroll
    for (int d = 0; d < 64; ++d) {
      aL = fmaf(sh[0][g][d], kvLb[d * 64 + lane], aL);
      aC = fmaf(sh[1][g][d], kvCb[d * 64 + lane], aC);
    }
    int o = (b * LDEC + t) * DMODEL + h * HD + lane;
    b16[1048576 + o] = f2bf(aL / denL);
    b16[3145728 + o] = f2bf(aC / denC);
  } else {
    // ---- cvt_w (Wo transpose -> bf16) ----
    float (*tl)[68] = (float(*)[68])smraw;
    int wb = bx0 - 5120;
    int k0 = (wb >> 4) * 64, n0 = (wb & 15) * 64;
#pragma unroll
    for (int i = 0; i < 4; ++i) {
      int c = tid + 256 * i;
      int r = c >> 4, c4 = (c & 15) * 4;
      float4 v = *(const float4*)(Wo + (size_t)(k0 + r) * DMODEL + n0 + c4);
      tl[c4 + 0][r] = v.x; tl[c4 + 1][r] = v.y; tl[c4 + 2][r] = v.z; tl[c4 + 3][r] = v.w;
    }
    __syncthreads();
#pragma unroll
    for (int i = 0; i < 4; ++i) {
      int c = tid + 256 * i;
      int n = c >> 4, k4 = (c & 15) * 4;
      float4 v = *(const float4*)&tl[n][k4];
      *(ushort4*)(Woh + (size_t)(n0 + n) * DMODEL + k0 + k4) =
          make_ushort4(f2bf(v.x), f2bf(v.y), f2bf(v.z), f2bf(v.w));
    }
  }
}

// ---------------- final combine
__global__ __launch_bounds__(256) void combine(
    const float* __restrict__ dec, const float* __restrict__ proj,
    const float* __restrict__ rmsw, const float* __restrict__ alphas,
    float* __restrict__ out) {
  __shared__ float red[4];
  int row = blockIdx.x;
  int tid = threadIdx.x, lane = tid & 63, g = tid >> 6;
  int base = row * DMODEL + tid * 4;
  float4 dv = *(const float4*)(dec + base);
  float4 wv = *(const float4*)(rmsw + tid * 4);
  float a[6];
  float amax = -INFINITY;
#pragma unroll
  for (int i = 0; i < 6; ++i) { a[i] = alphas[i]; amax = fmaxf(amax, a[i]); }
  float asum = 0.f;
#pragma unroll
  for (int i = 0; i < 6; ++i) { a[i] = __expf(a[i] - amax); asum += a[i]; }
#pragma unroll
  for (int i = 0; i < 6; ++i) a[i] /= asum;
  float4 acc = make_float4(a[0] * dv.x, a[0] * dv.y, a[0] * dv.z, a[0] * dv.w);
  for (int br = 0; br < 5; ++br) {
    float4 pv = *(const float4*)(proj + br * 1048576 + base);
    float4 xx = make_float4(dv.x + pv.x, dv.y + pv.y, dv.z + pv.z, dv.w + pv.w);
    float ssq = xx.x * xx.x + xx.y * xx.y + xx.z * xx.z + xx.w * xx.w;
    float wsum = wave_sum(ssq);
    if (lane == 0) red[g] = wsum;
    __syncthreads();
    float tot = red[0] + red[1] + red[2] + red[3];
    float rr = rsqrtf(tot / 1024.f + 1e-6f);
    float wb = a[br + 1];
    acc.x += wb * xx.x * rr * wv.x;
    acc.y += wb * xx.y * rr * wv.y;
    acc.z += wb * xx.z * rr * wv.z;
    acc.w += wb * xx.w * rr * wv.w;
    __syncthreads();
  }
  *(float4*)(out + base) = acc;
}

extern "C" void kernel_launch(void* const* d_in, const int* in_sizes, int n_in,
                              void* d_out, int out_size, void* d_ws, size_t ws_size,
                              hipStream_t stream) {
  const float* dec = (const float*)d_in[0];
  const float* enc = (const float*)d_in[1];
  const float* Wq = (const float*)d_in[2];
  const float* Wk = (const float*)d_in[3];
  const float* Wv = (const float*)d_in[4];
  const float* Wo = (const float*)d_in[5];
  const float* rmsw = (const float*)d_in[6];
  const float* alphas = (const float*)d_in[7];
  const int* sidx = (const int*)d_in[8];

  const size_t M = 1048576;
  float* ws = (float*)d_ws;
  float* Q    = ws;                                  // [0,1M)
  unsigned short* Kb16 = (unsigned short*)(ws + M);  // [1M,3M)
  float* KsPart = ws + 3 * M;                        // [3M,+311296)
  float* V    = ws + 5 * M;                          // [5M,9M)
  float* Vtb_f= ws + 9 * M;                          // [9M,11M)
  float* braw = ws + 11 * M;                         // [11M,16M) f32 partial slots
  unsigned short* Wqh = (unsigned short*)(ws + 9 * M);
  unsigned short* Wql = (unsigned short*)(ws + 9 * M + M / 2);
  unsigned short* Wkh = (unsigned short*)(ws + 10 * M);
  unsigned short* Wvh = (unsigned short*)(ws + 10 * M + M / 2);
  unsigned short* eh  = (unsigned short*)(ws + 11 * M);
  unsigned short* dh  = (unsigned short*)(ws + 15 * M);
  unsigned short* dl  = (unsigned short*)(ws + 15 * M + M / 2);
  unsigned short* Vtb = (unsigned short*)Vtb_f;
  float* kvpL = ws + 11 * M;
  float* kvpC = ws + 13 * M;
  float* kspL = ws + 15 * M;
  float* kspC = ws + 15 * M + 32768;
  float* vsp  = ws + 15 * M + 65536;
  // attn split-K-4 partials (all dead regions at attn time):
  float* OsP1 = ws + 5 * M;   // ex-V (consumed by trio)
  float* OsP2 = ws + 3 * M;   // ex-KsPart (consumed by trio)
  float* OsP3 = ws + 4 * M;
  float* OlS1 = ws + 6 * M;
  float* stats = ws + 7 * M;  // 4*32768 floats
  float* tail = ws + 16 * M;
  float* kvL  = tail;
  float* kvC  = tail + 131072;
  float* ksL  = tail + 262144;
  float* ksC  = tail + 264192;
  float* vmean= tail + 266240;
  float* Mbuf = tail + 317440;
  int*   sel  = (int*)(tail + 333824);
  // bf16 GEMM inputs written by combine_fill, read by gemm_one.
  // braw16 occupies the braw f32 slots 1..3.5 which are never written as f32
  // anymore ([12M,14.5M)); Woh sits at [14.5M,15M). No overlap with any
  // region read concurrently by combine_fill (P0 [11M,12M), L0 [15M,16M)).
  unsigned short* braw16 = (unsigned short*)(ws + 12 * M);
  unsigned short* Woh = (unsigned short*)(ws + 14 * M + M / 2);
  float* proj = ws + 3 * M + M / 2;

  hipLaunchKernelGGL(prologue, dim3(7104), dim3(256), 17408, stream,
                     dec, enc, Wq, Wk, Wv, sidx, dh, dl, eh, Wqh, Wql, Wkh, Wvh, KsPart);
  hipLaunchKernelGGL(gemm_qkv, dim3(72, 8), dim3(512), 81920, stream,
                     dh, dl, Wqh, Wql, Q, eh, Wkh, Kb16, Wvh, V);
  hipLaunchKernelGGL(trio, dim3(1664), dim3(256), 34816, stream,
                     V, Vtb, Kb16, kvpL, kvpC, kspL, kspC, vsp, Q, KsPart, Mbuf);
  hipLaunchKernelGGL(tail2, dim3(1080), dim3(256), 4224, stream,
                     kvpL, kvpC, kspL, kspC, vsp, kvL, kvC, ksL, ksC, vmean, Mbuf, sel);
  hipLaunchKernelGGL(attn_mfma, dim3(1024), dim3(256), 0, stream, Q, Kb16, Vtb,
                     braw, OsP1, OsP2, OsP3, braw + 4 * M, OlS1, stats);
  hipLaunchKernelGGL(combine_fill, dim3(5376), dim3(256), 17408, stream,
                     braw, OsP1, OsP2, OsP3, OlS1, stats, vmean, sel,
                     Q, kvL, kvC, ksL, ksC, braw16, Wo, Woh);
  hipLaunchKernelGGL(gemm_one, dim3(40, 8), dim3(512), 32768, stream, braw16, Woh, proj);
  hipLaunchKernelGGL(combine, dim3(1024), dim3(256), 0, stream, dec, proj, rmsw, alphas,
                     (float*)d_out);
}

// Round 8
// 278.022 us; speedup vs baseline: 1.0911x; 1.0045x over previous
//
#include <hip/hip_runtime.h>
#include <math.h>

#define LDEC 512
#define LENC 2048
#define DMODEL 1024
#define NH 16
#define HD 64
#define SCALE 0.125f
#define NTOP 31
#define NSAMP 38

typedef __attribute__((ext_vector_type(8))) short bf16x8;
typedef __attribute__((ext_vector_type(4))) float f32x4;

__device__ inline float wave_sum(float v) {
#pragma unroll
  for (int m = 32; m > 0; m >>= 1) v += __shfl_xor(v, m);
  return v;
}

__device__ inline unsigned short f2bf(float x) {
  unsigned u = __float_as_uint(x);
  u += 0x7fff + ((u >> 16) & 1);  // RNE
  return (unsigned short)(u >> 16);
}
__device__ inline float bf2f(unsigned short h) {
  return __uint_as_float(((unsigned)h) << 16);
}

// async HBM -> LDS, 16 B per lane; lds base must be wave-uniform
__device__ __forceinline__ void gld16(const unsigned short* g, unsigned short* l) {
  __builtin_amdgcn_global_load_lds(
      (const __attribute__((address_space(1))) unsigned int*)g,
      (__attribute__((address_space(3))) unsigned int*)l, 16, 0, 0);
}

// XOR-swizzled LDS index (row stride 64 shorts = 128 B): kills the
// stride-128B bank-conflict pattern; col must stay within [0,64).
__device__ __forceinline__ int sws(int row, int col) {
  return row * 64 + (col ^ ((row & 7) << 3));
}

// ================== FUSED PROLOGUE: cvt_in + cvt_w3 + k_samp =================
// grid: [0,5120) cvt_in | [5120,5888) cvt_w3 | [5888,7104) k_samp split-K.
// dyn LDS 17408.
__global__ __launch_bounds__(256) void prologue(
    const float* __restrict__ dec, const float* __restrict__ enc,
    const float* __restrict__ Wq, const float* __restrict__ Wk,
    const float* __restrict__ Wv, const int* __restrict__ sidx,
    unsigned short* __restrict__ dh, unsigned short* __restrict__ dl,
    unsigned short* __restrict__ eh,
    unsigned short* __restrict__ Wqh, unsigned short* __restrict__ Wql,
    unsigned short* __restrict__ Wkh, unsigned short* __restrict__ Wvh,
    float* __restrict__ KsPart) {
  extern __shared__ char smraw[];
  int bx = blockIdx.x;
  int tid = threadIdx.x;
  if (bx < 5120) {
    // ---- cvt_in ----
    int i = bx * 256 + tid;
    if (i < 262144) {
      float4 v = ((const float4*)dec)[i];
      ushort4 h = make_ushort4(f2bf(v.x), f2bf(v.y), f2bf(v.z), f2bf(v.w));
      ushort4 l = make_ushort4(f2bf(v.x - bf2f(h.x)), f2bf(v.y - bf2f(h.y)),
                               f2bf(v.z - bf2f(h.z)), f2bf(v.w - bf2f(h.w)));
      *(ushort4*)(dh + i * 4) = h;
      *(ushort4*)(dl + i * 4) = l;
    } else {
      int j = i - 262144;
      float4 v = ((const float4*)enc)[j];
      *(ushort4*)(eh + j * 4) =
          make_ushort4(f2bf(v.x), f2bf(v.y), f2bf(v.z), f2bf(v.w));
    }
  } else if (bx < 5888) {
    // ---- cvt_w3 ----
    float (*t)[68] = (float(*)[68])smraw;
    int wb = bx - 5120;
    int which = wb >> 8, rem = wb & 255;
    const float* W = which == 0 ? Wq : (which == 1 ? Wk : Wv);
    unsigned short* Th = which == 0 ? Wqh : (which == 1 ? Wkh : Wvh);
    unsigned short* Tl = which == 0 ? Wql : nullptr;
    int k0 = (rem >> 4) * 64, n0 = (rem & 15) * 64;
#pragma unroll
    for (int i = 0; i < 4; ++i) {
      int c = tid + 256 * i;
      int r = c >> 4, c4 = (c & 15) * 4;
      float4 v = *(const float4*)(W + (size_t)(k0 + r) * DMODEL + n0 + c4);
      t[c4 + 0][r] = v.x; t[c4 + 1][r] = v.y; t[c4 + 2][r] = v.z; t[c4 + 3][r] = v.w;
    }
    __syncthreads();
#pragma unroll
    for (int i = 0; i < 4; ++i) {
      int c = tid + 256 * i;
      int n = c >> 4, k4 = (c & 15) * 4;
      float4 v = *(const float4*)&t[n][k4];
      ushort4 h = make_ushort4(f2bf(v.x), f2bf(v.y), f2bf(v.z), f2bf(v.w));
      *(ushort4*)(Th + (size_t)(n0 + n) * DMODEL + k0 + k4) = h;
      if (Tl) {
        ushort4 l = make_ushort4(f2bf(v.x - bf2f(h.x)), f2bf(v.y - bf2f(h.y)),
                                 f2bf(v.z - bf2f(h.z)), f2bf(v.w - bf2f(h.w)));
        *(ushort4*)(Tl + (size_t)(n0 + n) * DMODEL + k0 + k4) = l;
      }
    }
  } else {
    // ---- k_samp split-K (fp32; 38s x 4 col-chunks x 8 k-chunks) ----
    float* er = (float*)smraw;  // 128 floats
    int sb = bx - 5888;         // 0..1215
    int s = sb >> 5;            // 0..37
    int rem = sb & 31;
    int cchunk = rem >> 3, kc = rem & 7;
    int c = cchunk * 256 + tid;
    int srow = sidx[s];
    if (tid < 32) {
      int idx = tid * 4;
      *(float4*)&er[idx] =
          *(const float4*)(enc + (size_t)srow * DMODEL + kc * 128 + idx);
    }
    __syncthreads();
    float acc = 0.f;
    const float* wp = Wk + (size_t)(kc * 128) * DMODEL + c;
    for (int k0 = 0; k0 < 128; k0 += 16) {
      float w[16];
#pragma unroll
      for (int j = 0; j < 16; ++j) w[j] = wp[(size_t)(k0 + j) * DMODEL];
#pragma unroll
      for (int j = 0; j < 16; ++j) acc = fmaf(er[k0 + j], w[j], acc);
    }
    KsPart[(size_t)kc * (NSAMP * 1024) + s * 1024 + c] = acc;
  }
}

// ======= shared epilogue: 64x32 wave tile via LDS transpose (stride 36) ====
template <int BF16OUT>
__device__ __forceinline__ void gemm_epilogue(
    unsigned short* sm, f32x4 (&acc)[4][2], float* __restrict__ C,
    unsigned short* __restrict__ Cb, int row0, int col0, int wave, int lane) {
  const int l16 = lane & 15, quad = lane >> 4;
  float* eL = (float*)sm + wave * 576;
  const int rr = lane >> 2, cc = (lane & 3) * 8;
  const int wr = wave >> 2, wc = wave & 3;
#pragma unroll
  for (int x = 0; x < 4; ++x) {
#pragma unroll
    for (int y = 0; y < 2; ++y)
#pragma unroll
      for (int q = 0; q < 4; ++q)
        eL[(quad * 4 + q) * 36 + y * 16 + l16] = acc[x][y][q];
    float4 v0 = *(const float4*)&eL[rr * 36 + cc];
    float4 v1 = *(const float4*)&eL[rr * 36 + cc + 4];
    size_t ro = (size_t)(row0 + wr * 64 + x * 16 + rr) * DMODEL + col0 + wc * 32 + cc;
    if (BF16OUT) {
      uint2 o;
      o.x = (unsigned)f2bf(v0.x) | ((unsigned)f2bf(v0.y) << 16);
      o.y = (unsigned)f2bf(v0.z) | ((unsigned)f2bf(v0.w) << 16);
      *(uint2*)(Cb + ro) = o;
      o.x = (unsigned)f2bf(v1.x) | ((unsigned)f2bf(v1.y) << 16);
      o.y = (unsigned)f2bf(v1.z) | ((unsigned)f2bf(v1.w) << 16);
      *(uint2*)(Cb + ro + 4) = o;
    } else {
      *(float4*)(C + ro) = v0;
      *(float4*)(C + ro + 4) = v1;
    }
  }
}

// ======= 1-pass bf16 GEMM, 512 thr, wave-tile 64x32, ASYNC global->LDS ====
// BK=64, full sws XOR swizzle (attn-proven, 0 conflicts). Linear LDS dest
// (gld16 requirement) + pre-swizzled per-lane GLOBAL source; ds_read uses
// the matching sws index. 16 K-iters, 16 MFMA/wave/iter. 2x16KB x2 = 64 KB.
template <int BF16OUT>
__device__ __forceinline__ void gemm512_1p_async(
    const unsigned short* __restrict__ Ah, const unsigned short* __restrict__ Bh,
    float* __restrict__ C, unsigned short* __restrict__ Cb, int row0, int col0) {
  extern __shared__ unsigned short sm[];
  const int BUFS = 16384;  // shorts per buffer (A 8192 | B 8192)
  const int tid = threadIdx.x, lane = tid & 63, wave = tid >> 6;
  const int l16 = lane & 15, quad = lane >> 4;
  const int wr = wave >> 2, wc = wave & 3;

  // staging: wave w covers rows w*16+{0..7} (call 0) and +8 (call 1);
  // lane l -> row += l>>3, linear col8 = l&7; global col pre-swizzled so
  // that LDS linear slot (row, c8) holds global col (c8 ^ (row&7)).
  const int srow = wave * 16 + (lane >> 3);
  const int scol = ((lane & 7) ^ (lane >> 3)) * 8;
  const unsigned short* gA = Ah + (size_t)(row0 + srow) * DMODEL + scol;
  const unsigned short* gB = Bh + (size_t)(col0 + srow) * DMODEL + scol;
  const int wofs = wave * 1024;

  f32x4 acc[4][2];
#pragma unroll
  for (int x = 0; x < 4; ++x)
#pragma unroll
    for (int y = 0; y < 2; ++y) acc[x][y] = (f32x4){0.f, 0.f, 0.f, 0.f};

  gld16(gA, sm + wofs);
  gld16(gA + (size_t)8 * DMODEL, sm + wofs + 512);
  gld16(gB, sm + 8192 + wofs);
  gld16(gB + (size_t)8 * DMODEL, sm + 8192 + wofs + 512);
  __syncthreads();

  for (int it = 0; it < 16; ++it) {
    const unsigned short* cur = sm + (it & 1) * BUFS;
    if (it < 15) {
      int ko = (it + 1) * 64;
      unsigned short* nxt = sm + ((it + 1) & 1) * BUFS;
      gld16(gA + ko, nxt + wofs);
      gld16(gA + (size_t)8 * DMODEL + ko, nxt + wofs + 512);
      gld16(gB + ko, nxt + 8192 + wofs);
      gld16(gB + (size_t)8 * DMODEL + ko, nxt + 8192 + wofs + 512);
    }
    bf16x8 a[2][4], b[2][2];
#pragma unroll
    for (int ks = 0; ks < 2; ++ks) {
#pragma unroll
      for (int x = 0; x < 4; ++x)
        a[ks][x] = *(const bf16x8*)&cur[sws(wr * 64 + x * 16 + l16, ks * 32 + quad * 8)];
#pragma unroll
      for (int y = 0; y < 2; ++y)
        b[ks][y] = *(const bf16x8*)&cur[8192 + sws(wc * 32 + y * 16 + l16, ks * 32 + quad * 8)];
    }
#pragma unroll
    for (int ks = 0; ks < 2; ++ks)
#pragma unroll
      for (int x = 0; x < 4; ++x)
#pragma unroll
        for (int y = 0; y < 2; ++y)
          acc[x][y] = __builtin_amdgcn_mfma_f32_16x16x32_bf16(a[ks][x], b[ks][y], acc[x][y], 0, 0, 0);
    __syncthreads();
  }
  gemm_epilogue<BF16OUT>(sm, acc, C, Cb, row0, col0, wave, lane);
}

// ======= 3-pass hi/lo GEMM, 512 thr, padded dbuf (unchanged from best) =====
__device__ __forceinline__ void gemm512_3p(
    const unsigned short* __restrict__ Ah, const unsigned short* __restrict__ Al,
    const unsigned short* __restrict__ Bh, const unsigned short* __restrict__ Bl,
    float* __restrict__ C, int row0, int col0) {
  extern __shared__ unsigned short sm[];
  const int BUFS = 20480;
  const int tid = threadIdx.x, lane = tid & 63, wave = tid >> 6;
  const int l16 = lane & 15, quad = lane >> 4;
  const int wr = wave >> 2, wc = wave & 3;

  const int r = tid >> 2, kc = tid & 3;
  const unsigned short* gAh = Ah + (size_t)(row0 + r) * DMODEL + kc * 8;
  const unsigned short* gBh = Bh + (size_t)(col0 + r) * DMODEL + kc * 8;
  const unsigned short* gAl = Al + (size_t)(row0 + r) * DMODEL + kc * 8;
  const unsigned short* gBl = Bl + (size_t)(col0 + r) * DMODEL + kc * 8;
  const int lofs = r * 40 + kc * 8;

  f32x4 acc[4][2];
#pragma unroll
  for (int x = 0; x < 4; ++x)
#pragma unroll
    for (int y = 0; y < 2; ++y) acc[x][y] = (f32x4){0.f, 0.f, 0.f, 0.f};

  uint4 pah = *(const uint4*)gAh, pbh = *(const uint4*)gBh;
  uint4 pal = *(const uint4*)gAl, pbl = *(const uint4*)gBl;
  *(uint4*)&sm[lofs] = pah;
  *(uint4*)&sm[5120 + lofs] = pbh;
  *(uint4*)&sm[10240 + lofs] = pal;
  *(uint4*)&sm[15360 + lofs] = pbl;
  pah = *(const uint4*)(gAh + 32);
  pbh = *(const uint4*)(gBh + 32);
  pal = *(const uint4*)(gAl + 32);
  pbl = *(const uint4*)(gBl + 32);
  __syncthreads();

  for (int it = 0; it < 32; ++it) {
    const unsigned short* cur = sm + (it & 1) * BUFS;
    bf16x8 ah[4], bh[2], al[4], bl[2];
#pragma unroll
    for (int x = 0; x < 4; ++x) {
      ah[x] = *(const bf16x8*)&cur[(wr * 64 + x * 16 + l16) * 40 + quad * 8];
      al[x] = *(const bf16x8*)&cur[10240 + (wr * 64 + x * 16 + l16) * 40 + quad * 8];
    }
#pragma unroll
    for (int y = 0; y < 2; ++y) {
      bh[y] = *(const bf16x8*)&cur[5120 + (wc * 32 + y * 16 + l16) * 40 + quad * 8];
      bl[y] = *(const bf16x8*)&cur[15360 + (wc * 32 + y * 16 + l16) * 40 + quad * 8];
    }
#pragma unroll
    for (int x = 0; x < 4; ++x)
#pragma unroll
      for (int y = 0; y < 2; ++y) {
        acc[x][y] = __builtin_amdgcn_mfma_f32_16x16x32_bf16(ah[x], bh[y], acc[x][y], 0, 0, 0);
        acc[x][y] = __builtin_amdgcn_mfma_f32_16x16x32_bf16(ah[x], bl[y], acc[x][y], 0, 0, 0);
        acc[x][y] = __builtin_amdgcn_mfma_f32_16x16x32_bf16(al[x], bh[y], acc[x][y], 0, 0, 0);
      }
    if (it < 31) {
      unsigned short* nxt = sm + ((it + 1) & 1) * BUFS;
      *(uint4*)&nxt[lofs] = pah;
      *(uint4*)&nxt[5120 + lofs] = pbh;
      *(uint4*)&nxt[10240 + lofs] = pal;
      *(uint4*)&nxt[15360 + lofs] = pbl;
      if (it < 30) {
        int ko = (it + 2) * 32;
        pah = *(const uint4*)(gAh + ko);
        pbh = *(const uint4*)(gBh + ko);
        pal = *(const uint4*)(gAl + ko);
        pbl = *(const uint4*)(gBl + ko);
      }
    }
    __syncthreads();
  }
  gemm_epilogue<0>(sm, acc, C, nullptr, row0, col0, wave, lane);
}

// merged Q(3-pass) + K(1-pass async, bf16-out) + V(1-pass async)
__global__ __launch_bounds__(512, 4) void gemm_qkv(
    const unsigned short* __restrict__ dh, const unsigned short* __restrict__ dl,
    const unsigned short* __restrict__ Wqh, const unsigned short* __restrict__ Wql,
    float* __restrict__ Q,
    const unsigned short* __restrict__ eh, const unsigned short* __restrict__ Wkh,
    unsigned short* __restrict__ Kb16,
    const unsigned short* __restrict__ Wvh, float* __restrict__ V) {
  int bx = blockIdx.x;
  if (bx < 8)
    gemm512_3p(dh, dl, Wqh, Wql, Q, bx * 128, blockIdx.y * 128);
  else if (bx < 40)
    gemm512_1p_async<1>(eh, Wkh, nullptr, Kb16, (bx - 8) * 128, blockIdx.y * 128);
  else
    gemm512_1p_async<0>(eh, Wvh, V, nullptr, (bx - 40) * 128, blockIdx.y * 128);
}

__global__ __launch_bounds__(512, 4) void gemm_one(
    const unsigned short* __restrict__ Ah, const unsigned short* __restrict__ Bh,
    float* __restrict__ C) {
  gemm512_1p_async<0>(Ah, Bh, C, nullptr, blockIdx.x * 128, blockIdx.y * 128);
}

// ============ FUSED TRIO: cvt_vt + lin_cos_stats(MFMA) + pp_scores ==========
// grid: [0,1024) cvt_vt | [1024,1536) lin_cos_stats | [1536,1664) pp_scores.
// dyn LDS 34816 B (max branch: lin_cos 34560).
__global__ __launch_bounds__(256, 4) void trio(
    const float* __restrict__ V, unsigned short* __restrict__ Vt,
    const unsigned short* __restrict__ Kb,
    float* __restrict__ kvpL, float* __restrict__ kvpC,
    float* __restrict__ kspL, float* __restrict__ kspC, float* __restrict__ vsp,
    const float* __restrict__ Q, const float* __restrict__ KsPart,
    float* __restrict__ Mout) {
  extern __shared__ char smraw[];
  int bx0 = blockIdx.x;
  int tid = threadIdx.x;
  if (bx0 < 1024) {
    // ---- cvt_vt ----
    unsigned short (*tile)[72] = (unsigned short(*)[72])smraw;
    int bh = bx0 >> 5;
    int s0 = (bx0 & 31) * 64;
    int b = bh >> 4, h = bh & 15;
#pragma unroll
    for (int i = 0; i < 4; ++i) {
      int c = tid + 256 * i;
      int s = c >> 4, d4 = (c & 15) * 4;
      float4 v = *(const float4*)(V + (size_t)(b * LENC + s0 + s) * DMODEL + h * HD + d4);
      tile[d4 + 0][s] = f2bf(v.x);
      tile[d4 + 1][s] = f2bf(v.y);
      tile[d4 + 2][s] = f2bf(v.z);
      tile[d4 + 3][s] = f2bf(v.w);
    }
    __syncthreads();
#pragma unroll
    for (int i = 0; i < 2; ++i) {
      int c = tid + 256 * i;
      int d = c >> 3, soff = (c & 7) * 8;
      uint4 o = *(const uint4*)&tile[d][soff];
      *(uint4*)(Vt + (size_t)(bh * 64 + d) * LENC + s0 + soff) = o;
    }
  } else if (bx0 < 1536) {
    // ---- lin_cos_stats via hi/lo bf16 MFMA 3-pass ----
    float (*Kt)[65] = (float(*)[65])smraw;                          // 16640 B
    unsigned int (*Vu)[65] = (unsigned int(*)[65])(smraw + 16640);  // 16640 B
    float* nrm = (float*)(smraw + 33280);                           //   256 B
    float4* vred = (float4*)(smraw + 33536);                        //  1024 B
    int bx = bx0 - 1024;
    int bh = bx >> 4, part = bx & 15;
    int b = bh >> 4, h = bh & 15;
    const int lane = tid & 63, wv = tid >> 6;
    const int l16 = lane & 15, quad = lane >> 4;
    const int dblk = wv * 16;
    const unsigned short* Kg = Kb + (size_t)(b * LENC + part * 128) * DMODEL + h * HD;
    const float* Vg = V + (size_t)(b * LENC + part * 128) * DMODEL + h * HD;
    const int sK = tid >> 2, d16 = (tid & 3) * 16;
    const int sVb = tid >> 4, v4 = (tid & 15) * 4;

    f32x4 accL[4], accC[4];
#pragma unroll
    for (int n = 0; n < 4; ++n) {
      accL[n] = (f32x4){0.f, 0.f, 0.f, 0.f};
      accC[n] = (f32x4){0.f, 0.f, 0.f, 0.f};
    }
    float kslp = 0.f, kscp = 0.f;
    float4 vpart = make_float4(0.f, 0.f, 0.f, 0.f);

    for (int ch = 0; ch < 2; ++ch) {
      const int s0 = ch * 64;
      // stage K (bf16 -> f32) + row sumsq -> nrm
      {
        const unsigned short* kr = Kg + (size_t)(s0 + sK) * DMODEL + d16;
        uint4 p0 = *(const uint4*)kr;
        uint4 p1 = *(const uint4*)(kr + 8);
        float kvv[16];
        kvv[0] = __uint_as_float(p0.x << 16);
        kvv[1] = __uint_as_float(p0.x & 0xffff0000u);
        kvv[2] = __uint_as_float(p0.y << 16);
        kvv[3] = __uint_as_float(p0.y & 0xffff0000u);
        kvv[4] = __uint_as_float(p0.z << 16);
        kvv[5] = __uint_as_float(p0.z & 0xffff0000u);
        kvv[6] = __uint_as_float(p0.w << 16);
        kvv[7] = __uint_as_float(p0.w & 0xffff0000u);
        kvv[8] = __uint_as_float(p1.x << 16);
        kvv[9] = __uint_as_float(p1.x & 0xffff0000u);
        kvv[10] = __uint_as_float(p1.y << 16);
        kvv[11] = __uint_as_float(p1.y & 0xffff0000u);
        kvv[12] = __uint_as_float(p1.z << 16);
        kvv[13] = __uint_as_float(p1.z & 0xffff0000u);
        kvv[14] = __uint_as_float(p1.w << 16);
        kvv[15] = __uint_as_float(p1.w & 0xffff0000u);
        float ss = 0.f;
#pragma unroll
        for (int j = 0; j < 16; ++j) ss = fmaf(kvv[j], kvv[j], ss);
        ss += __shfl_xor(ss, 1);
        ss += __shfl_xor(ss, 2);
        if ((tid & 3) == 0) nrm[sK] = sqrtf(ss);
#pragma unroll
        for (int j = 0; j < 16; ++j) Kt[sK][d16 + j] = kvv[j];
      }
      // stage V (f32 -> packed hi|lo bf16) + column-sum partial
#pragma unroll
      for (int i = 0; i < 4; ++i) {
        int sv = sVb + 16 * i;
        float4 vv = *(const float4*)(Vg + (size_t)(s0 + sv) * DMODEL + v4);
        vpart.x += vv.x; vpart.y += vv.y; vpart.z += vv.z; vpart.w += vv.w;
        unsigned short h0 = f2bf(vv.x), h1 = f2bf(vv.y);
        unsigned short h2 = f2bf(vv.z), h3 = f2bf(vv.w);
        Vu[sv][v4 + 0] = ((unsigned)h0 << 16) | (unsigned)f2bf(vv.x - bf2f(h0));
        Vu[sv][v4 + 1] = ((unsigned)h1 << 16) | (unsigned)f2bf(vv.y - bf2f(h1));
        Vu[sv][v4 + 2] = ((unsigned)h2 << 16) | (unsigned)f2bf(vv.z - bf2f(h2));
        Vu[sv][v4 + 3] = ((unsigned)h3 << 16) | (unsigned)f2bf(vv.w - bf2f(h3));
      }
      __syncthreads();
      // fragment build + MFMA
#pragma unroll
      for (int kk = 0; kk < 2; ++kk) {
        const int sb = kk * 32 + quad * 8;
        bf16x8 aLh, aLl, aCh, aCl;
#pragma unroll
        for (int j = 0; j < 8; ++j) {
          float kval = Kt[sb + j][dblk + l16];
          float nn = nrm[sb + j];
          float kfl = kval > 0.f ? kval + 1.f : __expf(kval);
          float kn = kval / fmaxf(nn, 1e-12f);
          float kfc = fmaxf(kn, 0.f) + 1e-6f;
          kslp += kfl;
          kscp += kfc;
          unsigned short hL = f2bf(kfl);
          aLh[j] = hL;
          aLl[j] = f2bf(kfl - bf2f(hL));
          unsigned short hC = f2bf(kfc);
          aCh[j] = hC;
          aCl[j] = f2bf(kfc - bf2f(hC));
        }
#pragma unroll
        for (int n = 0; n < 4; ++n) {
          bf16x8 bhv, blv;
#pragma unroll
          for (int j = 0; j < 8; ++j) {
            unsigned uv = Vu[sb + j][n * 16 + l16];
            bhv[j] = (short)(unsigned short)(uv >> 16);
            blv[j] = (short)(unsigned short)(uv & 0xffffu);
          }
          accL[n] = __builtin_amdgcn_mfma_f32_16x16x32_bf16(aLh, bhv, accL[n], 0, 0, 0);
          accL[n] = __builtin_amdgcn_mfma_f32_16x16x32_bf16(aLh, blv, accL[n], 0, 0, 0);
          accL[n] = __builtin_amdgcn_mfma_f32_16x16x32_bf16(aLl, bhv, accL[n], 0, 0, 0);
          accC[n] = __builtin_amdgcn_mfma_f32_16x16x32_bf16(aCh, bhv, accC[n], 0, 0, 0);
          accC[n] = __builtin_amdgcn_mfma_f32_16x16x32_bf16(aCh, blv, accC[n], 0, 0, 0);
          accC[n] = __builtin_amdgcn_mfma_f32_16x16x32_bf16(aCl, bhv, accC[n], 0, 0, 0);
        }
      }
      __syncthreads();
    }
    // outputs: kv partials (D layout: row = quad*4+q, col = l16)
    const int obase = part * 131072 + bh * 4096;
#pragma unroll
    for (int n = 0; n < 4; ++n)
#pragma unroll
      for (int q = 0; q < 4; ++q) {
        int o = obase + (dblk + quad * 4 + q) * 64 + n * 16 + l16;
        kvpL[o] = accL[n][q];
        kvpC[o] = accC[n][q];
      }
    kslp += __shfl_xor(kslp, 16);
    kslp += __shfl_xor(kslp, 32);
    kscp += __shfl_xor(kscp, 16);
    kscp += __shfl_xor(kscp, 32);
    if (quad == 0) {
      kspL[part * 2048 + bh * 64 + dblk + l16] = kslp;
      kspC[part * 2048 + bh * 64 + dblk + l16] = kscp;
    }
    vpart.x += __shfl_xor(vpart.x, 16); vpart.x += __shfl_xor(vpart.x, 32);
    vpart.y += __shfl_xor(vpart.y, 16); vpart.y += __shfl_xor(vpart.y, 32);
    vpart.z += __shfl_xor(vpart.z, 16); vpart.z += __shfl_xor(vpart.z, 32);
    vpart.w += __shfl_xor(vpart.w, 16); vpart.w += __shfl_xor(vpart.w, 32);
    if (quad == 0) vred[wv * 16 + l16] = vpart;
    __syncthreads();
    if (tid < 16) {
      float4 a0 = vred[tid], a1 = vred[16 + tid];
      float4 a2 = vred[32 + tid], a3 = vred[48 + tid];
      float4 s = make_float4(a0.x + a1.x + a2.x + a3.x, a0.y + a1.y + a2.y + a3.y,
                             a0.z + a1.z + a2.z + a3.z, a0.w + a1.w + a2.w + a3.w);
      *(float4*)&vsp[part * 2048 + bh * 64 + tid * 4] = s;
    }
  } else {
    // ---- pp_scores (fp32; sums the 8 split-K partials in fixed order) ----
    float (*ksL)[65] = (float(*)[65])smraw;  // 38*65*4 = 9880 B
    int bx = bx0 - 1536;
    int bh = bx >> 2, chunk = bx & 3;
    int b = bh >> 4, h = bh & 15;
    int t0 = chunk * 128;
    const float* Qb = Q + (b * LDEC) * DMODEL + h * HD;
    for (int slot = tid; slot < NSAMP * 16; slot += 256) {
      int r = slot >> 4, c4 = slot & 15;
      const float* kp = KsPart + r * 1024 + h * HD + c4 * 4;
      float4 kx = *(const float4*)kp;
#pragma unroll
      for (int p = 1; p < 8; ++p) {
        float4 k2 = *(const float4*)(kp + (size_t)p * (NSAMP * 1024));
        kx.x += k2.x; kx.y += k2.y; kx.z += k2.z; kx.w += k2.w;
      }
      ksL[r][c4 * 4 + 0] = kx.x; ksL[r][c4 * 4 + 1] = kx.y;
      ksL[r][c4 * 4 + 2] = kx.z; ksL[r][c4 * 4 + 3] = kx.w;
    }
    __syncthreads();
    if (tid < 128) {
      float qr[64];
      const float* qrow = Qb + (size_t)(t0 + tid) * DMODEL;
#pragma unroll
      for (int d4 = 0; d4 < 16; ++d4)
        *(float4*)&qr[d4 * 4] = *(const float4*)(qrow + d4 * 4);
      float mx = -INFINITY, sm = 0.f;
      for (int j = 0; j < NSAMP; ++j) {
        float s = 0.f;
#pragma unroll
        for (int d = 0; d < 64; ++d) s = fmaf(qr[d], ksL[j][d], s);
        s *= SCALE;
        mx = fmaxf(mx, s);
        sm += s;
      }
      Mout[bh * LDEC + t0 + tid] = mx - sm / (float)NSAMP;
    }
  }
}

// ============ FUSED TAIL: reduce_all + pp_topk ==============================
// grid: [0,1048) reduce_all | [1048,1080) pp_topk. dyn LDS 4224 B.
__global__ __launch_bounds__(256) void tail2(
    const float* __restrict__ kvpL, const float* __restrict__ kvpC,
    const float* __restrict__ kspL, const float* __restrict__ kspC,
    const float* __restrict__ vsp, float* __restrict__ kvL,
    float* __restrict__ kvC, float* __restrict__ ksL,
    float* __restrict__ ksC, float* __restrict__ vmean,
    const float* __restrict__ Mbuf, int* __restrict__ sel) {
  extern __shared__ char smraw[];
  int bx = blockIdx.x;
  int tid = threadIdx.x;
  if (bx < 1048) {
    int i = bx * 256 + tid;
    if (i < 131072) {
      float s = 0.f;
#pragma unroll
      for (int p = 0; p < 16; ++p) s += kvpL[p * 131072 + i];
      kvL[i] = s;
    } else if (i < 262144) {
      int j = i - 131072;
      float s = 0.f;
#pragma unroll
      for (int p = 0; p < 16; ++p) s += kvpC[p * 131072 + j];
      kvC[j] = s;
    } else if (i < 268288) {
      int j = i - 262144;
      int which = j >> 11, jj = j & 2047;
      const float* src = which == 0 ? kspL : (which == 1 ? kspC : vsp);
      float s = 0.f;
#pragma unroll
      for (int p = 0; p < 16; ++p) s += src[p * 2048 + jj];
      if (which == 0) ksL[jj] = s;
      else if (which == 1) ksC[jj] = s;
      else vmean[jj] = s * (1.f / 2048.f);
    }
  } else {
    // ---- pp_topk (tie -> lower index) ----
    float* vals = (float*)smraw;
    int* flag = (int*)(smraw + 2048);
    float* wvs = (float*)(smraw + 4096);
    int* wis = (int*)(smraw + 4112);
    int bh = bx - 1048;
    int lane = tid & 63, g = tid >> 6;
    vals[tid] = Mbuf[bh * 512 + tid];
    vals[tid + 256] = Mbuf[bh * 512 + tid + 256];
    flag[tid] = 0; flag[tid + 256] = 0;
    __syncthreads();
    for (int it = 0; it < NTOP; ++it) {
      float v0 = vals[tid]; int i0 = tid;
      float v1 = vals[tid + 256];
      if (v1 > v0) { v0 = v1; i0 = tid + 256; }
#pragma unroll
      for (int mm = 32; mm > 0; mm >>= 1) {
        float ov = __shfl_xor(v0, mm);
        int oi = __shfl_xor(i0, mm);
        if (ov > v0 || (ov == v0 && oi < i0)) { v0 = ov; i0 = oi; }
      }
      if (lane == 0) { wvs[g] = v0; wis[g] = i0; }
      __syncthreads();
      if (tid == 0) {
        float bv = wvs[0]; int bi = wis[0];
#pragma unroll
        for (int w = 1; w < 4; ++w)
          if (wvs[w] > bv || (wvs[w] == bv && wis[w] < bi)) { bv = wvs[w]; bi = wis[w]; }
        vals[bi] = -INFINITY;
        flag[bi] = 1;
      }
      __syncthreads();
    }
    sel[bh * 512 + tid] = flag[tid];
    sel[bh * 512 + tid + 256] = flag[tid + 256];
  }
}

// ---------------- MFMA flash attention, split-K 4-way + XCD swizzle ---------
// LDS 40960 B (swizzled, conflict-free); row sums via MFMA ones-column trick.
__global__ __launch_bounds__(256) void attn_mfma(
    const float* __restrict__ Qf, const unsigned short* __restrict__ Kb,
    const unsigned short* __restrict__ Vt,
    float* __restrict__ OsP0, float* __restrict__ OsP1,
    float* __restrict__ OsP2, float* __restrict__ OsP3,
    float* __restrict__ OlS0, float* __restrict__ OlS1,
    float* __restrict__ st) {
  __shared__ unsigned short Ks[2][4096];
  __shared__ unsigned short Vs[2][4096];
  __shared__ unsigned short Ps[4][1024];
  const int tid = threadIdx.x;
  const int wave = tid >> 6, lane = tid & 63;
  const int l16 = lane & 15, quad = lane >> 4;
  const int bx = blockIdx.x;
  const int xcd = bx & 7, sub = bx >> 3;
  const int qt = sub & 7, qr = (sub >> 3) & 3, grp = sub >> 5;
  const int bh = xcd + 8 * grp;
  const int b = bh >> 4, h = bh & 15;
  const int tbase = qt * 64 + wave * 16;
  const int sbase = qr * 512;

  const float* qrow = Qf + (size_t)(b * LDEC + tbase + l16) * DMODEL + h * HD + quad * 8;
  bf16x8 qa0, qa1;
  {
    float4 a0 = *(const float4*)qrow, a1 = *(const float4*)(qrow + 4);
    float4 a2 = *(const float4*)(qrow + 32), a3 = *(const float4*)(qrow + 36);
    qa0[0] = f2bf(a0.x * SCALE); qa0[1] = f2bf(a0.y * SCALE);
    qa0[2] = f2bf(a0.z * SCALE); qa0[3] = f2bf(a0.w * SCALE);
    qa0[4] = f2bf(a1.x * SCALE); qa0[5] = f2bf(a1.y * SCALE);
    qa0[6] = f2bf(a1.z * SCALE); qa0[7] = f2bf(a1.w * SCALE);
    qa1[0] = f2bf(a2.x * SCALE); qa1[1] = f2bf(a2.y * SCALE);
    qa1[2] = f2bf(a2.z * SCALE); qa1[3] = f2bf(a2.w * SCALE);
    qa1[4] = f2bf(a3.x * SCALE); qa1[5] = f2bf(a3.y * SCALE);
    qa1[6] = f2bf(a3.z * SCALE); qa1[7] = f2bf(a3.w * SCALE);
  }

  // ones B-fragment: row-sum of P via MFMA (D col all equal)
  bf16x8 bone;
#pragma unroll
  for (int j = 0; j < 8; ++j) bone[j] = (short)0x3f80;

  int tA = tbase + l16;
  int cA = min(4 * tA, LENC - 1);
  int loA = max(cA - 256, 0), hiA = min(cA + 256, LENC - 1);
  const int loW = max(4 * tbase - 256, 0);
  const int hiW = min(4 * (tbase + 15) + 256, LENC - 1);
  const bool blockAny = (sbase <= hiW) && (sbase + 511 >= loW);

  f32x4 Os[4], Ol[4], Ssum, Slsum;
#pragma unroll
  for (int n = 0; n < 4; ++n) {
    Os[n] = (f32x4){0.f, 0.f, 0.f, 0.f};
    Ol[n] = (f32x4){0.f, 0.f, 0.f, 0.f};
  }
  Ssum = (f32x4){0.f, 0.f, 0.f, 0.f};
  Slsum = (f32x4){0.f, 0.f, 0.f, 0.f};

  const int c0 = tid, c1 = tid + 256;
  const unsigned short* kg0 = Kb + (size_t)(b * LENC + sbase + (c0 >> 3)) * DMODEL + h * HD + (c0 & 7) * 8;
  const unsigned short* kg1 = Kb + (size_t)(b * LENC + sbase + (c1 >> 3)) * DMODEL + h * HD + (c1 & 7) * 8;
  const unsigned short* vg0 = Vt + (size_t)(bh * 64 + (c0 >> 3)) * LENC + sbase + (c0 & 7) * 8;
  const unsigned short* vg1 = Vt + (size_t)(bh * 64 + (c1 >> 3)) * LENC + sbase + (c1 & 7) * 8;
  const int of0 = sws(c0 >> 3, (c0 & 7) * 8);
  const int of1 = sws(c1 >> 3, (c1 & 7) * 8);

  uint4 pk0, pk1, pv0, pv1;
  pk0 = *(const uint4*)kg0; pk1 = *(const uint4*)kg1;
  pv0 = *(const uint4*)vg0; pv1 = *(const uint4*)vg1;
  *(uint4*)&Ks[0][of0] = pk0; *(uint4*)&Ks[0][of1] = pk1;
  *(uint4*)&Vs[0][of0] = pv0; *(uint4*)&Vs[0][of1] = pv1;
  __syncthreads();

  for (int it = 0; it < 8; ++it) {
    const int cur = it & 1;
    const int s0 = sbase + it * 64;
    const bool anyL = (s0 <= hiW) && (s0 + 63 >= loW);
    if (it < 7) {
      pk0 = *(const uint4*)(kg0 + (size_t)(it + 1) * 64 * DMODEL);
      pk1 = *(const uint4*)(kg1 + (size_t)(it + 1) * 64 * DMODEL);
      pv0 = *(const uint4*)(vg0 + (it + 1) * 64);
      pv1 = *(const uint4*)(vg1 + (it + 1) * 64);
    }
    const unsigned short* K_ = Ks[cur];
    const unsigned short* V_ = Vs[cur];

    f32x4 S[4];
#pragma unroll
    for (int n = 0; n < 4; ++n) {
      bf16x8 bk0 = *(const bf16x8*)&K_[sws(n * 16 + l16, quad * 8)];
      bf16x8 bk1 = *(const bf16x8*)&K_[sws(n * 16 + l16, 32 + quad * 8)];
      f32x4 z = (f32x4){0.f, 0.f, 0.f, 0.f};
      z = __builtin_amdgcn_mfma_f32_16x16x32_bf16(qa0, bk0, z, 0, 0, 0);
      S[n] = __builtin_amdgcn_mfma_f32_16x16x32_bf16(qa1, bk1, z, 0, 0, 0);
    }

    unsigned short* Pw = Ps[wave];
#pragma unroll
    for (int n = 0; n < 4; ++n)
#pragma unroll
      for (int r = 0; r < 4; ++r)
        Pw[sws(quad * 4 + r, n * 16 + l16)] = f2bf(__expf(S[n][r]));
    bf16x8 aP0 = *(const bf16x8*)&Pw[sws(l16, quad * 8)];
    bf16x8 aP1 = *(const bf16x8*)&Pw[sws(l16, 32 + quad * 8)];
    // row sums (softmax denominators) via ones-column MFMA
    Ssum = __builtin_amdgcn_mfma_f32_16x16x32_bf16(aP0, bone, Ssum, 0, 0, 0);
    Ssum = __builtin_amdgcn_mfma_f32_16x16x32_bf16(aP1, bone, Ssum, 0, 0, 0);
#pragma unroll
    for (int n = 0; n < 4; ++n) {
      bf16x8 bv0 = *(const bf16x8*)&V_[sws(n * 16 + l16, quad * 8)];
      bf16x8 bv1 = *(const bf16x8*)&V_[sws(n * 16 + l16, 32 + quad * 8)];
      Os[n] = __builtin_amdgcn_mfma_f32_16x16x32_bf16(aP0, bv0, Os[n], 0, 0, 0);
      Os[n] = __builtin_amdgcn_mfma_f32_16x16x32_bf16(aP1, bv1, Os[n], 0, 0, 0);
    }
    if (anyL) {
      bf16x8 aL0 = aP0, aL1 = aP1;
#pragma unroll
      for (int j = 0; j < 8; ++j) {
        int sc = s0 + quad * 8 + j;
        if (sc < loA || sc > hiA) aL0[j] = 0;
        if (sc + 32 < loA || sc + 32 > hiA) aL1[j] = 0;
      }
      Slsum = __builtin_amdgcn_mfma_f32_16x16x32_bf16(aL0, bone, Slsum, 0, 0, 0);
      Slsum = __builtin_amdgcn_mfma_f32_16x16x32_bf16(aL1, bone, Slsum, 0, 0, 0);
#pragma unroll
      for (int n = 0; n < 4; ++n) {
        bf16x8 bv0 = *(const bf16x8*)&V_[sws(n * 16 + l16, quad * 8)];
        bf16x8 bv1 = *(const bf16x8*)&V_[sws(n * 16 + l16, 32 + quad * 8)];
        Ol[n] = __builtin_amdgcn_mfma_f32_16x16x32_bf16(aL0, bv0, Ol[n], 0, 0, 0);
        Ol[n] = __builtin_amdgcn_mfma_f32_16x16x32_bf16(aL1, bv1, Ol[n], 0, 0, 0);
      }
    }
    // single barrier per iteration: all reads of buffer (1-cur) completed
    // before the previous iteration's barrier, so writing it now is safe.
    if (it < 7) {
      unsigned short* KL = Ks[1 - cur];
      unsigned short* VL = Vs[1 - cur];
      *(uint4*)&KL[of0] = pk0; *(uint4*)&KL[of1] = pk1;
      *(uint4*)&VL[of0] = pv0; *(uint4*)&VL[of1] = pv1;
    }
    __syncthreads();
  }

  float* osp = qr == 0 ? OsP0 : (qr == 1 ? OsP1 : (qr == 2 ? OsP2 : OsP3));
  float* olp = (qr & 1) ? OlS1 : OlS0;
  float* sp = st + qr * 32768;
#pragma unroll
  for (int r = 0; r < 4; ++r) {
    int t = tbase + quad * 4 + r;
#pragma unroll
    for (int n = 0; n < 4; ++n) {
      size_t o = (size_t)(b * LDEC + t) * DMODEL + h * HD + n * 16 + l16;
      osp[o] = Os[n][r];
      if (blockAny) olp[o] = Ol[n][r];
    }
    if (l16 == 0) {
      int sr = bh * 512 + t;
      sp[sr] = Ssum[r];
      sp[16384 + sr] = Slsum[r];
    }
  }
}

// fused: split-K-4 combine + probsparse fill + lin/cos apply + Wo cvt.
// Emits bf16 DIRECTLY into b16 (the gemm_one input) -> epi_cvt eliminated.
// grid: [0,1024) combine | [1024,5120) lin_cos | [5120,5376) cvt_w(Wo).
// dyn LDS 17408 (Wo branch).
__global__ __launch_bounds__(256) void combine_fill(
    const float* __restrict__ braw, const float* __restrict__ P1,
    const float* __restrict__ P2, const float* __restrict__ P3,
    const float* __restrict__ L1, const float* __restrict__ st,
    const float* __restrict__ vmean, const int* __restrict__ sel,
    const float* __restrict__ Q, const float* __restrict__ kvL,
    const float* __restrict__ kvC, const float* __restrict__ ksL,
    const float* __restrict__ ksC,
    unsigned short* __restrict__ b16, const float* __restrict__ Wo,
    unsigned short* __restrict__ Woh) {
  extern __shared__ char smraw[];
  __shared__ float sh[2][4][64];
  int bx0 = blockIdx.x;
  int tid = threadIdx.x;
  if (bx0 < 1024) {
    int i4 = bx0 * 256 + tid;
    int i = i4 * 4;
    int col = i & 1023, bt = i >> 10;
    int t = bt & 511, b = bt >> 9, h = col >> 6, d = col & 63;
    int bh = b * 16 + h;
    int sr = bh * 512 + t;
    float iS = 1.f / (st[sr] + st[32768 + sr] + st[65536 + sr] + st[98304 + sr]);
    float iL = 1.f / (st[16384 + sr] + st[49152 + sr] + st[81920 + sr] + st[114688 + sr]);
    float4 s0 = *(const float4*)(braw + i);
    float4 s1 = *(const float4*)(P1 + i);
    float4 s2 = *(const float4*)(P2 + i);
    float4 s3 = *(const float4*)(P3 + i);
    // local-branch: row t's window touches quarters q0..q1 (q1-q0 <= 1);
    // quarter q wrote parity slot q&1 (slot0 = braw+4M, slot1 = L1).
    int c = min(4 * t, LENC - 1);
    int lo = max(c - 256, 0), hi = min(c + 256, LENC - 1);
    int q0 = lo >> 9, q1 = hi >> 9;
    const float* Lp0 = (q0 & 1) ? L1 : (braw + 4194304);
    float4 l = *(const float4*)(Lp0 + i);
    if (q1 != q0) {
      const float* Lp1 = (q1 & 1) ? L1 : (braw + 4194304);
      float4 l2 = *(const float4*)(Lp1 + i);
      l.x += l2.x; l.y += l2.y; l.z += l2.z; l.w += l2.w;
    }
    float4 os = make_float4((s0.x + s1.x + s2.x + s3.x) * iS,
                            (s0.y + s1.y + s2.y + s3.y) * iS,
                            (s0.z + s1.z + s2.z + s3.z) * iS,
                            (s0.w + s1.w + s2.w + s3.w) * iS);
    float4 ol = make_float4(l.x * iL, l.y * iL, l.z * iL, l.w * iL);
    float4 pp = sel[sr] ? os : *(const float4*)(vmean + bh * 64 + d);
    uint2 o2;
    o2.x = (unsigned)f2bf(os.x) | ((unsigned)f2bf(os.y) << 16);
    o2.y = (unsigned)f2bf(os.z) | ((unsigned)f2bf(os.w) << 16);
    *(uint2*)(b16 + i) = o2;
    o2.x = (unsigned)f2bf(pp.x) | ((unsigned)f2bf(pp.y) << 16);
    o2.y = (unsigned)f2bf(pp.z) | ((unsigned)f2bf(pp.w) << 16);
    *(uint2*)(b16 + 2097152 + i) = o2;
    o2.x = (unsigned)f2bf(ol.x) | ((unsigned)f2bf(ol.y) << 16);
    o2.y = (unsigned)f2bf(ol.z) | ((unsigned)f2bf(ol.w) << 16);
    *(uint2*)(b16 + 4194304 + i) = o2;
  } else if (bx0 < 5120) {
    // ---- lin_cos_apply (bf16 direct out) ----
    int lane = tid & 63, g = tid >> 6;
    int row = (bx0 - 1024) * 4 + g;
    int bh = row >> 9, t = row & 511;
    int b = bh >> 4, h = bh & 15;
    float qv = Q[(b * LDEC + t) * DMODEL + h * HD + lane];
    float x = qv * SCALE;
    float qfl = x > 0.f ? x + 1.f : __expf(x);
    float qnorm = sqrtf(wave_sum(qv * qv));
    float qn = qv / fmaxf(qnorm, 1e-12f);
    float qfc = fmaxf(qn, 0.f) + 1e-6f;
    sh[0][g][lane] = qfl;
    sh[1][g][lane] = qfc;
    float denL = fmaxf(wave_sum(qfl * ksL[bh * 64 + lane]), 1e-6f);
    float denC = fmaxf(wave_sum(qfc * ksC[bh * 64 + lane]), 1e-6f);
    const float* kvLb = kvL + bh * 4096;
    const float* kvCb = kvC + bh * 4096;
    float aL = 0.f, aC = 0.f;
#pragma unroll
    for (int d = 0; d < 64; ++d) {
      aL = fmaf(sh[0][g][d], kvLb[d * 64 + lane], aL);
      aC = fmaf(sh[1][g][d], kvCb[d * 64 + lane], aC);
    }
    int o = (b * LDEC + t) * DMODEL + h * HD + lane;
    b16[1048576 + o] = f2bf(aL / denL);
    b16[3145728 + o] = f2bf(aC / denC);
  } else {
    // ---- cvt_w (Wo transpose -> bf16) ----
    float (*tl)[68] = (float(*)[68])smraw;
    int wb = bx0 - 5120;
    int k0 = (wb >> 4) * 64, n0 = (wb & 15) * 64;
#pragma unroll
    for (int i = 0; i < 4; ++i) {
      int c = tid + 256 * i;
      int r = c >> 4, c4 = (c & 15) * 4;
      float4 v = *(const float4*)(Wo + (size_t)(k0 + r) * DMODEL + n0 + c4);
      tl[c4 + 0][r] = v.x; tl[c4 + 1][r] = v.y; tl[c4 + 2][r] = v.z; tl[c4 + 3][r] = v.w;
    }
    __syncthreads();
#pragma unroll
    for (int i = 0; i < 4; ++i) {
      int c = tid + 256 * i;
      int n = c >> 4, k4 = (c & 15) * 4;
      float4 v = *(const float4*)&tl[n][k4];
      *(ushort4*)(Woh + (size_t)(n0 + n) * DMODEL + k0 + k4) =
          make_ushort4(f2bf(v.x), f2bf(v.y), f2bf(v.z), f2bf(v.w));
    }
  }
}

// ---------------- final combine
__global__ __launch_bounds__(256) void combine(
    const float* __restrict__ dec, const float* __restrict__ proj,
    const float* __restrict__ rmsw, const float* __restrict__ alphas,
    float* __restrict__ out) {
  __shared__ float red[4];
  int row = blockIdx.x;
  int tid = threadIdx.x, lane = tid & 63, g = tid >> 6;
  int base = row * DMODEL + tid * 4;
  float4 dv = *(const float4*)(dec + base);
  float4 wv = *(const float4*)(rmsw + tid * 4);
  float a[6];
  float amax = -INFINITY;
#pragma unroll
  for (int i = 0; i < 6; ++i) { a[i] = alphas[i]; amax = fmaxf(amax, a[i]); }
  float asum = 0.f;
#pragma unroll
  for (int i = 0; i < 6; ++i) { a[i] = __expf(a[i] - amax); asum += a[i]; }
#pragma unroll
  for (int i = 0; i < 6; ++i) a[i] /= asum;
  float4 acc = make_float4(a[0] * dv.x, a[0] * dv.y, a[0] * dv.z, a[0] * dv.w);
  for (int br = 0; br < 5; ++br) {
    float4 pv = *(const float4*)(proj + br * 1048576 + base);
    float4 xx = make_float4(dv.x + pv.x, dv.y + pv.y, dv.z + pv.z, dv.w + pv.w);
    float ssq = xx.x * xx.x + xx.y * xx.y + xx.z * xx.z + xx.w * xx.w;
    float wsum = wave_sum(ssq);
    if (lane == 0) red[g] = wsum;
    __syncthreads();
    float tot = red[0] + red[1] + red[2] + red[3];
    float rr = rsqrtf(tot / 1024.f + 1e-6f);
    float wb = a[br + 1];
    acc.x += wb * xx.x * rr * wv.x;
    acc.y += wb * xx.y * rr * wv.y;
    acc.z += wb * xx.z * rr * wv.z;
    acc.w += wb * xx.w * rr * wv.w;
    __syncthreads();
  }
  *(float4*)(out + base) = acc;
}

extern "C" void kernel_launch(void* const* d_in, const int* in_sizes, int n_in,
                              void* d_out, int out_size, void* d_ws, size_t ws_size,
                              hipStream_t stream) {
  const float* dec = (const float*)d_in[0];
  const float* enc = (const float*)d_in[1];
  const float* Wq = (const float*)d_in[2];
  const float* Wk = (const float*)d_in[3];
  const float* Wv = (const float*)d_in[4];
  const float* Wo = (const float*)d_in[5];
  const float* rmsw = (const float*)d_in[6];
  const float* alphas = (const float*)d_in[7];
  const int* sidx = (const int*)d_in[8];

  const size_t M = 1048576;
  float* ws = (float*)d_ws;
  float* Q    = ws;                                  // [0,1M)
  unsigned short* Kb16 = (unsigned short*)(ws + M);  // [1M,3M)
  float* KsPart = ws + 3 * M;                        // [3M,+311296)
  float* V    = ws + 5 * M;                          // [5M,9M)
  float* Vtb_f= ws + 9 * M;                          // [9M,11M)
  float* braw = ws + 11 * M;                         // [11M,16M) f32 partial slots
  unsigned short* Wqh = (unsigned short*)(ws + 9 * M);
  unsigned short* Wql = (unsigned short*)(ws + 9 * M + M / 2);
  unsigned short* Wkh = (unsigned short*)(ws + 10 * M);
  unsigned short* Wvh = (unsigned short*)(ws + 10 * M + M / 2);
  unsigned short* eh  = (unsigned short*)(ws + 11 * M);
  unsigned short* dh  = (unsigned short*)(ws + 15 * M);
  unsigned short* dl  = (unsigned short*)(ws + 15 * M + M / 2);
  unsigned short* Vtb = (unsigned short*)Vtb_f;
  float* kvpL = ws + 11 * M;
  float* kvpC = ws + 13 * M;
  float* kspL = ws + 15 * M;
  float* kspC = ws + 15 * M + 32768;
  float* vsp  = ws + 15 * M + 65536;
  // attn split-K-4 partials (all dead regions at attn time):
  float* OsP1 = ws + 5 * M;   // ex-V (consumed by trio)
  float* OsP2 = ws + 3 * M;   // ex-KsPart (consumed by trio)
  float* OsP3 = ws + 4 * M;
  float* OlS1 = ws + 6 * M;
  float* stats = ws + 7 * M;  // 4*32768 floats
  float* tail = ws + 16 * M;
  float* kvL  = tail;
  float* kvC  = tail + 131072;
  float* ksL  = tail + 262144;
  float* ksC  = tail + 264192;
  float* vmean= tail + 266240;
  float* Mbuf = tail + 317440;
  int*   sel  = (int*)(tail + 333824);
  // bf16 GEMM inputs written by combine_fill, read by gemm_one.
  unsigned short* braw16 = (unsigned short*)(ws + 12 * M);
  unsigned short* Woh = (unsigned short*)(ws + 14 * M + M / 2);
  float* proj = ws + 3 * M + M / 2;

  hipLaunchKernelGGL(prologue, dim3(7104), dim3(256), 17408, stream,
                     dec, enc, Wq, Wk, Wv, sidx, dh, dl, eh, Wqh, Wql, Wkh, Wvh, KsPart);
  hipLaunchKernelGGL(gemm_qkv, dim3(72, 8), dim3(512), 81920, stream,
                     dh, dl, Wqh, Wql, Q, eh, Wkh, Kb16, Wvh, V);
  hipLaunchKernelGGL(trio, dim3(1664), dim3(256), 34816, stream,
                     V, Vtb, Kb16, kvpL, kvpC, kspL, kspC, vsp, Q, KsPart, Mbuf);
  hipLaunchKernelGGL(tail2, dim3(1080), dim3(256), 4224, stream,
                     kvpL, kvpC, kspL, kspC, vsp, kvL, kvC, ksL, ksC, vmean, Mbuf, sel);
  hipLaunchKernelGGL(attn_mfma, dim3(1024), dim3(256), 0, stream, Q, Kb16, Vtb,
                     braw, OsP1, OsP2, OsP3, braw + 4 * M, OlS1, stats);
  hipLaunchKernelGGL(combine_fill, dim3(5376), dim3(256), 17408, stream,
                     braw, OsP1, OsP2, OsP3, OlS1, stats, vmean, sel,
                     Q, kvL, kvC, ksL, ksC, braw16, Wo, Woh);
  hipLaunchKernelGGL(gemm_one, dim3(40, 8), dim3(512), 65536, stream, braw16, Woh, proj);
  hipLaunchKernelGGL(combine, dim3(1024), dim3(256), 0, stream, dec, proj, rmsw, alphas,
                     (float*)d_out);
}

// Round 10
// 268.037 us; speedup vs baseline: 1.1317x; 1.0373x over previous
//
#include <hip/hip_runtime.h>
#include <math.h>

#define LDEC 512
#define LENC 2048
#define DMODEL 1024
#define NH 16
#define HD 64
#define SCALE 0.125f
#define NTOP 31
#define NSAMP 38

typedef __attribute__((ext_vector_type(8))) short bf16x8;
typedef __attribute__((ext_vector_type(4))) float f32x4;

__device__ inline float wave_sum(float v) {
#pragma unroll
  for (int m = 32; m > 0; m >>= 1) v += __shfl_xor(v, m);
  return v;
}

__device__ inline unsigned short f2bf(float x) {
  unsigned u = __float_as_uint(x);
  u += 0x7fff + ((u >> 16) & 1);  // RNE
  return (unsigned short)(u >> 16);
}
__device__ inline float bf2f(unsigned short h) {
  return __uint_as_float(((unsigned)h) << 16);
}

// async HBM -> LDS, 16 B per lane; lds base must be wave-uniform
__device__ __forceinline__ void gld16(const unsigned short* g, unsigned short* l) {
  __builtin_amdgcn_global_load_lds(
      (const __attribute__((address_space(1))) unsigned int*)g,
      (__attribute__((address_space(3))) unsigned int*)l, 16, 0, 0);
}

// XOR-swizzled LDS index (row stride 64 shorts = 128 B): kills the
// stride-128B bank-conflict pattern; col must stay within [0,64).
__device__ __forceinline__ int sws(int row, int col) {
  return row * 64 + (col ^ ((row & 7) << 3));
}

// ====== FUSED PROLOGUE: cvt_in + cvt_w3 + k_samp + cvt_w(Wo) ================
// grid: [0,5120) cvt_in | [5120,5888) cvt_w3 | [5888,7104) k_samp split-K |
// [7104,7360) Wo cvt (input-only dep; moved OFF the post-attn critical path).
// dyn LDS 17408.
__global__ __launch_bounds__(256) void prologue(
    const float* __restrict__ dec, const float* __restrict__ enc,
    const float* __restrict__ Wq, const float* __restrict__ Wk,
    const float* __restrict__ Wv, const int* __restrict__ sidx,
    unsigned short* __restrict__ dh, unsigned short* __restrict__ dl,
    unsigned short* __restrict__ eh,
    unsigned short* __restrict__ Wqh, unsigned short* __restrict__ Wql,
    unsigned short* __restrict__ Wkh, unsigned short* __restrict__ Wvh,
    float* __restrict__ KsPart,
    const float* __restrict__ Wo, unsigned short* __restrict__ Woh) {
  extern __shared__ char smraw[];
  int bx = blockIdx.x;
  int tid = threadIdx.x;
  if (bx < 5120) {
    // ---- cvt_in ----
    int i = bx * 256 + tid;
    if (i < 262144) {
      float4 v = ((const float4*)dec)[i];
      ushort4 h = make_ushort4(f2bf(v.x), f2bf(v.y), f2bf(v.z), f2bf(v.w));
      ushort4 l = make_ushort4(f2bf(v.x - bf2f(h.x)), f2bf(v.y - bf2f(h.y)),
                               f2bf(v.z - bf2f(h.z)), f2bf(v.w - bf2f(h.w)));
      *(ushort4*)(dh + i * 4) = h;
      *(ushort4*)(dl + i * 4) = l;
    } else {
      int j = i - 262144;
      float4 v = ((const float4*)enc)[j];
      *(ushort4*)(eh + j * 4) =
          make_ushort4(f2bf(v.x), f2bf(v.y), f2bf(v.z), f2bf(v.w));
    }
  } else if (bx < 5888) {
    // ---- cvt_w3 ----
    float (*t)[68] = (float(*)[68])smraw;
    int wb = bx - 5120;
    int which = wb >> 8, rem = wb & 255;
    const float* W = which == 0 ? Wq : (which == 1 ? Wk : Wv);
    unsigned short* Th = which == 0 ? Wqh : (which == 1 ? Wkh : Wvh);
    unsigned short* Tl = which == 0 ? Wql : nullptr;
    int k0 = (rem >> 4) * 64, n0 = (rem & 15) * 64;
#pragma unroll
    for (int i = 0; i < 4; ++i) {
      int c = tid + 256 * i;
      int r = c >> 4, c4 = (c & 15) * 4;
      float4 v = *(const float4*)(W + (size_t)(k0 + r) * DMODEL + n0 + c4);
      t[c4 + 0][r] = v.x; t[c4 + 1][r] = v.y; t[c4 + 2][r] = v.z; t[c4 + 3][r] = v.w;
    }
    __syncthreads();
#pragma unroll
    for (int i = 0; i < 4; ++i) {
      int c = tid + 256 * i;
      int n = c >> 4, k4 = (c & 15) * 4;
      float4 v = *(const float4*)&t[n][k4];
      ushort4 h = make_ushort4(f2bf(v.x), f2bf(v.y), f2bf(v.z), f2bf(v.w));
      *(ushort4*)(Th + (size_t)(n0 + n) * DMODEL + k0 + k4) = h;
      if (Tl) {
        ushort4 l = make_ushort4(f2bf(v.x - bf2f(h.x)), f2bf(v.y - bf2f(h.y)),
                                 f2bf(v.z - bf2f(h.z)), f2bf(v.w - bf2f(h.w)));
        *(ushort4*)(Tl + (size_t)(n0 + n) * DMODEL + k0 + k4) = l;
      }
    }
  } else if (bx < 7104) {
    // ---- k_samp split-K (fp32; 38s x 4 col-chunks x 8 k-chunks) ----
    float* er = (float*)smraw;  // 128 floats
    int sb = bx - 5888;         // 0..1215
    int s = sb >> 5;            // 0..37
    int rem = sb & 31;
    int cchunk = rem >> 3, kc = rem & 7;
    int c = cchunk * 256 + tid;
    int srow = sidx[s];
    if (tid < 32) {
      int idx = tid * 4;
      *(float4*)&er[idx] =
          *(const float4*)(enc + (size_t)srow * DMODEL + kc * 128 + idx);
    }
    __syncthreads();
    float acc = 0.f;
    const float* wp = Wk + (size_t)(kc * 128) * DMODEL + c;
    for (int k0 = 0; k0 < 128; k0 += 16) {
      float w[16];
#pragma unroll
      for (int j = 0; j < 16; ++j) w[j] = wp[(size_t)(k0 + j) * DMODEL];
#pragma unroll
      for (int j = 0; j < 16; ++j) acc = fmaf(er[k0 + j], w[j], acc);
    }
    KsPart[(size_t)kc * (NSAMP * 1024) + s * 1024 + c] = acc;
  } else {
    // ---- cvt_w (Wo transpose -> bf16) ----
    float (*tl)[68] = (float(*)[68])smraw;
    int wb = bx - 7104;
    int k0 = (wb >> 4) * 64, n0 = (wb & 15) * 64;
#pragma unroll
    for (int i = 0; i < 4; ++i) {
      int c = tid + 256 * i;
      int r = c >> 4, c4 = (c & 15) * 4;
      float4 v = *(const float4*)(Wo + (size_t)(k0 + r) * DMODEL + n0 + c4);
      tl[c4 + 0][r] = v.x; tl[c4 + 1][r] = v.y; tl[c4 + 2][r] = v.z; tl[c4 + 3][r] = v.w;
    }
    __syncthreads();
#pragma unroll
    for (int i = 0; i < 4; ++i) {
      int c = tid + 256 * i;
      int n = c >> 4, k4 = (c & 15) * 4;
      float4 v = *(const float4*)&tl[n][k4];
      *(ushort4*)(Woh + (size_t)(n0 + n) * DMODEL + k0 + k4) =
          make_ushort4(f2bf(v.x), f2bf(v.y), f2bf(v.z), f2bf(v.w));
    }
  }
}

// ======= shared epilogue: 64x32 wave tile via LDS transpose (stride 36) ====
template <int BF16OUT>
__device__ __forceinline__ void gemm_epilogue(
    unsigned short* sm, f32x4 (&acc)[4][2], float* __restrict__ C,
    unsigned short* __restrict__ Cb, int row0, int col0, int wave, int lane) {
  const int l16 = lane & 15, quad = lane >> 4;
  float* eL = (float*)sm + wave * 576;
  const int rr = lane >> 2, cc = (lane & 3) * 8;
  const int wr = wave >> 2, wc = wave & 3;
#pragma unroll
  for (int x = 0; x < 4; ++x) {
#pragma unroll
    for (int y = 0; y < 2; ++y)
#pragma unroll
      for (int q = 0; q < 4; ++q)
        eL[(quad * 4 + q) * 36 + y * 16 + l16] = acc[x][y][q];
    float4 v0 = *(const float4*)&eL[rr * 36 + cc];
    float4 v1 = *(const float4*)&eL[rr * 36 + cc + 4];
    size_t ro = (size_t)(row0 + wr * 64 + x * 16 + rr) * DMODEL + col0 + wc * 32 + cc;
    if (BF16OUT) {
      uint2 o;
      o.x = (unsigned)f2bf(v0.x) | ((unsigned)f2bf(v0.y) << 16);
      o.y = (unsigned)f2bf(v0.z) | ((unsigned)f2bf(v0.w) << 16);
      *(uint2*)(Cb + ro) = o;
      o.x = (unsigned)f2bf(v1.x) | ((unsigned)f2bf(v1.y) << 16);
      o.y = (unsigned)f2bf(v1.z) | ((unsigned)f2bf(v1.w) << 16);
      *(uint2*)(Cb + ro + 4) = o;
    } else {
      *(float4*)(C + ro) = v0;
      *(float4*)(C + ro + 4) = v1;
    }
  }
}

// ======= 1-pass bf16 GEMM, 512 thr, wave-tile 64x32, ASYNC global->LDS ====
// BK=64, full sws XOR swizzle (attn-proven, 0 conflicts).
template <int BF16OUT>
__device__ __forceinline__ void gemm512_1p_async(
    const unsigned short* __restrict__ Ah, const unsigned short* __restrict__ Bh,
    float* __restrict__ C, unsigned short* __restrict__ Cb, int row0, int col0) {
  extern __shared__ unsigned short sm[];
  const int BUFS = 16384;  // shorts per buffer (A 8192 | B 8192)
  const int tid = threadIdx.x, lane = tid & 63, wave = tid >> 6;
  const int l16 = lane & 15, quad = lane >> 4;
  const int wr = wave >> 2, wc = wave & 3;

  const int srow = wave * 16 + (lane >> 3);
  const int scol = ((lane & 7) ^ (lane >> 3)) * 8;
  const unsigned short* gA = Ah + (size_t)(row0 + srow) * DMODEL + scol;
  const unsigned short* gB = Bh + (size_t)(col0 + srow) * DMODEL + scol;
  const int wofs = wave * 1024;

  f32x4 acc[4][2];
#pragma unroll
  for (int x = 0; x < 4; ++x)
#pragma unroll
    for (int y = 0; y < 2; ++y) acc[x][y] = (f32x4){0.f, 0.f, 0.f, 0.f};

  gld16(gA, sm + wofs);
  gld16(gA + (size_t)8 * DMODEL, sm + wofs + 512);
  gld16(gB, sm + 8192 + wofs);
  gld16(gB + (size_t)8 * DMODEL, sm + 8192 + wofs + 512);
  __syncthreads();

  for (int it = 0; it < 16; ++it) {
    const unsigned short* cur = sm + (it & 1) * BUFS;
    if (it < 15) {
      int ko = (it + 1) * 64;
      unsigned short* nxt = sm + ((it + 1) & 1) * BUFS;
      gld16(gA + ko, nxt + wofs);
      gld16(gA + (size_t)8 * DMODEL + ko, nxt + wofs + 512);
      gld16(gB + ko, nxt + 8192 + wofs);
      gld16(gB + (size_t)8 * DMODEL + ko, nxt + 8192 + wofs + 512);
    }
    bf16x8 a[2][4], b[2][2];
#pragma unroll
    for (int ks = 0; ks < 2; ++ks) {
#pragma unroll
      for (int x = 0; x < 4; ++x)
        a[ks][x] = *(const bf16x8*)&cur[sws(wr * 64 + x * 16 + l16, ks * 32 + quad * 8)];
#pragma unroll
      for (int y = 0; y < 2; ++y)
        b[ks][y] = *(const bf16x8*)&cur[8192 + sws(wc * 32 + y * 16 + l16, ks * 32 + quad * 8)];
    }
#pragma unroll
    for (int ks = 0; ks < 2; ++ks)
#pragma unroll
      for (int x = 0; x < 4; ++x)
#pragma unroll
        for (int y = 0; y < 2; ++y)
          acc[x][y] = __builtin_amdgcn_mfma_f32_16x16x32_bf16(a[ks][x], b[ks][y], acc[x][y], 0, 0, 0);
    __syncthreads();
  }
  gemm_epilogue<BF16OUT>(sm, acc, C, Cb, row0, col0, wave, lane);
}

// ======= 3-pass hi/lo GEMM, 512 thr, padded dbuf (unchanged from best) =====
__device__ __forceinline__ void gemm512_3p(
    const unsigned short* __restrict__ Ah, const unsigned short* __restrict__ Al,
    const unsigned short* __restrict__ Bh, const unsigned short* __restrict__ Bl,
    float* __restrict__ C, int row0, int col0) {
  extern __shared__ unsigned short sm[];
  const int BUFS = 20480;
  const int tid = threadIdx.x, lane = tid & 63, wave = tid >> 6;
  const int l16 = lane & 15, quad = lane >> 4;
  const int wr = wave >> 2, wc = wave & 3;

  const int r = tid >> 2, kc = tid & 3;
  const unsigned short* gAh = Ah + (size_t)(row0 + r) * DMODEL + kc * 8;
  const unsigned short* gBh = Bh + (size_t)(col0 + r) * DMODEL + kc * 8;
  const unsigned short* gAl = Al + (size_t)(row0 + r) * DMODEL + kc * 8;
  const unsigned short* gBl = Bl + (size_t)(col0 + r) * DMODEL + kc * 8;
  const int lofs = r * 40 + kc * 8;

  f32x4 acc[4][2];
#pragma unroll
  for (int x = 0; x < 4; ++x)
#pragma unroll
    for (int y = 0; y < 2; ++y) acc[x][y] = (f32x4){0.f, 0.f, 0.f, 0.f};

  uint4 pah = *(const uint4*)gAh, pbh = *(const uint4*)gBh;
  uint4 pal = *(const uint4*)gAl, pbl = *(const uint4*)gBl;
  *(uint4*)&sm[lofs] = pah;
  *(uint4*)&sm[5120 + lofs] = pbh;
  *(uint4*)&sm[10240 + lofs] = pal;
  *(uint4*)&sm[15360 + lofs] = pbl;
  pah = *(const uint4*)(gAh + 32);
  pbh = *(const uint4*)(gBh + 32);
  pal = *(const uint4*)(gAl + 32);
  pbl = *(const uint4*)(gBl + 32);
  __syncthreads();

  for (int it = 0; it < 32; ++it) {
    const unsigned short* cur = sm + (it & 1) * BUFS;
    bf16x8 ah[4], bh[2], al[4], bl[2];
#pragma unroll
    for (int x = 0; x < 4; ++x) {
      ah[x] = *(const bf16x8*)&cur[(wr * 64 + x * 16 + l16) * 40 + quad * 8];
      al[x] = *(const bf16x8*)&cur[10240 + (wr * 64 + x * 16 + l16) * 40 + quad * 8];
    }
#pragma unroll
    for (int y = 0; y < 2; ++y) {
      bh[y] = *(const bf16x8*)&cur[5120 + (wc * 32 + y * 16 + l16) * 40 + quad * 8];
      bl[y] = *(const bf16x8*)&cur[15360 + (wc * 32 + y * 16 + l16) * 40 + quad * 8];
    }
#pragma unroll
    for (int x = 0; x < 4; ++x)
#pragma unroll
      for (int y = 0; y < 2; ++y) {
        acc[x][y] = __builtin_amdgcn_mfma_f32_16x16x32_bf16(ah[x], bh[y], acc[x][y], 0, 0, 0);
        acc[x][y] = __builtin_amdgcn_mfma_f32_16x16x32_bf16(ah[x], bl[y], acc[x][y], 0, 0, 0);
        acc[x][y] = __builtin_amdgcn_mfma_f32_16x16x32_bf16(al[x], bh[y], acc[x][y], 0, 0, 0);
      }
    if (it < 31) {
      unsigned short* nxt = sm + ((it + 1) & 1) * BUFS;
      *(uint4*)&nxt[lofs] = pah;
      *(uint4*)&nxt[5120 + lofs] = pbh;
      *(uint4*)&nxt[10240 + lofs] = pal;
      *(uint4*)&nxt[15360 + lofs] = pbl;
      if (it < 30) {
        int ko = (it + 2) * 32;
        pah = *(const uint4*)(gAh + ko);
        pbh = *(const uint4*)(gBh + ko);
        pal = *(const uint4*)(gAl + ko);
        pbl = *(const uint4*)(gBl + ko);
      }
    }
    __syncthreads();
  }
  gemm_epilogue<0>(sm, acc, C, nullptr, row0, col0, wave, lane);
}

// merged Q(3-pass) + K(1-pass async, bf16-out) + V(1-pass async)
__global__ __launch_bounds__(512, 4) void gemm_qkv(
    const unsigned short* __restrict__ dh, const unsigned short* __restrict__ dl,
    const unsigned short* __restrict__ Wqh, const unsigned short* __restrict__ Wql,
    float* __restrict__ Q,
    const unsigned short* __restrict__ eh, const unsigned short* __restrict__ Wkh,
    unsigned short* __restrict__ Kb16,
    const unsigned short* __restrict__ Wvh, float* __restrict__ V) {
  int bx = blockIdx.x;
  if (bx < 8)
    gemm512_3p(dh, dl, Wqh, Wql, Q, bx * 128, blockIdx.y * 128);
  else if (bx < 40)
    gemm512_1p_async<1>(eh, Wkh, nullptr, Kb16, (bx - 8) * 128, blockIdx.y * 128);
  else
    gemm512_1p_async<0>(eh, Wvh, V, nullptr, (bx - 40) * 128, blockIdx.y * 128);
}

__global__ __launch_bounds__(512, 4) void gemm_one(
    const unsigned short* __restrict__ Ah, const unsigned short* __restrict__ Bh,
    float* __restrict__ C) {
  gemm512_1p_async<0>(Ah, Bh, C, nullptr, blockIdx.x * 128, blockIdx.y * 128);
}

// ============ FUSED TRIO: cvt_vt + lin_cos_stats(MFMA) + pp_scores ==========
// grid: [0,1024) cvt_vt | [1024,1536) lin_cos_stats | [1536,1664) pp_scores.
// dyn LDS 34816 B (max branch: lin_cos 34560).
__global__ __launch_bounds__(256, 4) void trio(
    const float* __restrict__ V, unsigned short* __restrict__ Vt,
    const unsigned short* __restrict__ Kb,
    float* __restrict__ kvpL, float* __restrict__ kvpC,
    float* __restrict__ kspL, float* __restrict__ kspC, float* __restrict__ vsp,
    const float* __restrict__ Q, const float* __restrict__ KsPart,
    float* __restrict__ Mout) {
  extern __shared__ char smraw[];
  int bx0 = blockIdx.x;
  int tid = threadIdx.x;
  if (bx0 < 1024) {
    // ---- cvt_vt ----
    unsigned short (*tile)[72] = (unsigned short(*)[72])smraw;
    int bh = bx0 >> 5;
    int s0 = (bx0 & 31) * 64;
    int b = bh >> 4, h = bh & 15;
#pragma unroll
    for (int i = 0; i < 4; ++i) {
      int c = tid + 256 * i;
      int s = c >> 4, d4 = (c & 15) * 4;
      float4 v = *(const float4*)(V + (size_t)(b * LENC + s0 + s) * DMODEL + h * HD + d4);
      tile[d4 + 0][s] = f2bf(v.x);
      tile[d4 + 1][s] = f2bf(v.y);
      tile[d4 + 2][s] = f2bf(v.z);
      tile[d4 + 3][s] = f2bf(v.w);
    }
    __syncthreads();
#pragma unroll
    for (int i = 0; i < 2; ++i) {
      int c = tid + 256 * i;
      int d = c >> 3, soff = (c & 7) * 8;
      uint4 o = *(const uint4*)&tile[d][soff];
      *(uint4*)(Vt + (size_t)(bh * 64 + d) * LENC + s0 + soff) = o;
    }
  } else if (bx0 < 1536) {
    // ---- lin_cos_stats via hi/lo bf16 MFMA 3-pass ----
    float (*Kt)[65] = (float(*)[65])smraw;                          // 16640 B
    unsigned int (*Vu)[65] = (unsigned int(*)[65])(smraw + 16640);  // 16640 B
    float* nrm = (float*)(smraw + 33280);                           //   256 B
    float4* vred = (float4*)(smraw + 33536);                        //  1024 B
    int bx = bx0 - 1024;
    int bh = bx >> 4, part = bx & 15;
    int b = bh >> 4, h = bh & 15;
    const int lane = tid & 63, wv = tid >> 6;
    const int l16 = lane & 15, quad = lane >> 4;
    const int dblk = wv * 16;
    const unsigned short* Kg = Kb + (size_t)(b * LENC + part * 128) * DMODEL + h * HD;
    const float* Vg = V + (size_t)(b * LENC + part * 128) * DMODEL + h * HD;
    const int sK = tid >> 2, d16 = (tid & 3) * 16;
    const int sVb = tid >> 4, v4 = (tid & 15) * 4;

    f32x4 accL[4], accC[4];
#pragma unroll
    for (int n = 0; n < 4; ++n) {
      accL[n] = (f32x4){0.f, 0.f, 0.f, 0.f};
      accC[n] = (f32x4){0.f, 0.f, 0.f, 0.f};
    }
    float kslp = 0.f, kscp = 0.f;
    float4 vpart = make_float4(0.f, 0.f, 0.f, 0.f);

    for (int ch = 0; ch < 2; ++ch) {
      const int s0 = ch * 64;
      // stage K (bf16 -> f32) + row sumsq -> nrm
      {
        const unsigned short* kr = Kg + (size_t)(s0 + sK) * DMODEL + d16;
        uint4 p0 = *(const uint4*)kr;
        uint4 p1 = *(const uint4*)(kr + 8);
        float kvv[16];
        kvv[0] = __uint_as_float(p0.x << 16);
        kvv[1] = __uint_as_float(p0.x & 0xffff0000u);
        kvv[2] = __uint_as_float(p0.y << 16);
        kvv[3] = __uint_as_float(p0.y & 0xffff0000u);
        kvv[4] = __uint_as_float(p0.z << 16);
        kvv[5] = __uint_as_float(p0.z & 0xffff0000u);
        kvv[6] = __uint_as_float(p0.w << 16);
        kvv[7] = __uint_as_float(p0.w & 0xffff0000u);
        kvv[8] = __uint_as_float(p1.x << 16);
        kvv[9] = __uint_as_float(p1.x & 0xffff0000u);
        kvv[10] = __uint_as_float(p1.y << 16);
        kvv[11] = __uint_as_float(p1.y & 0xffff0000u);
        kvv[12] = __uint_as_float(p1.z << 16);
        kvv[13] = __uint_as_float(p1.z & 0xffff0000u);
        kvv[14] = __uint_as_float(p1.w << 16);
        kvv[15] = __uint_as_float(p1.w & 0xffff0000u);
        float ss = 0.f;
#pragma unroll
        for (int j = 0; j < 16; ++j) ss = fmaf(kvv[j], kvv[j], ss);
        ss += __shfl_xor(ss, 1);
        ss += __shfl_xor(ss, 2);
        if ((tid & 3) == 0) nrm[sK] = sqrtf(ss);
#pragma unroll
        for (int j = 0; j < 16; ++j) Kt[sK][d16 + j] = kvv[j];
      }
      // stage V (f32 -> packed hi|lo bf16) + column-sum partial
#pragma unroll
      for (int i = 0; i < 4; ++i) {
        int sv = sVb + 16 * i;
        float4 vv = *(const float4*)(Vg + (size_t)(s0 + sv) * DMODEL + v4);
        vpart.x += vv.x; vpart.y += vv.y; vpart.z += vv.z; vpart.w += vv.w;
        unsigned short h0 = f2bf(vv.x), h1 = f2bf(vv.y);
        unsigned short h2 = f2bf(vv.z), h3 = f2bf(vv.w);
        Vu[sv][v4 + 0] = ((unsigned)h0 << 16) | (unsigned)f2bf(vv.x - bf2f(h0));
        Vu[sv][v4 + 1] = ((unsigned)h1 << 16) | (unsigned)f2bf(vv.y - bf2f(h1));
        Vu[sv][v4 + 2] = ((unsigned)h2 << 16) | (unsigned)f2bf(vv.z - bf2f(h2));
        Vu[sv][v4 + 3] = ((unsigned)h3 << 16) | (unsigned)f2bf(vv.w - bf2f(h3));
      }
      __syncthreads();
      // fragment build + MFMA
#pragma unroll
      for (int kk = 0; kk < 2; ++kk) {
        const int sb = kk * 32 + quad * 8;
        bf16x8 aLh, aLl, aCh, aCl;
#pragma unroll
        for (int j = 0; j < 8; ++j) {
          float kval = Kt[sb + j][dblk + l16];
          float nn = nrm[sb + j];
          float kfl = kval > 0.f ? kval + 1.f : __expf(kval);
          float kn = kval / fmaxf(nn, 1e-12f);
          float kfc = fmaxf(kn, 0.f) + 1e-6f;
          kslp += kfl;
          kscp += kfc;
          unsigned short hL = f2bf(kfl);
          aLh[j] = hL;
          aLl[j] = f2bf(kfl - bf2f(hL));
          unsigned short hC = f2bf(kfc);
          aCh[j] = hC;
          aCl[j] = f2bf(kfc - bf2f(hC));
        }
#pragma unroll
        for (int n = 0; n < 4; ++n) {
          bf16x8 bhv, blv;
#pragma unroll
          for (int j = 0; j < 8; ++j) {
            unsigned uv = Vu[sb + j][n * 16 + l16];
            bhv[j] = (short)(unsigned short)(uv >> 16);
            blv[j] = (short)(unsigned short)(uv & 0xffffu);
          }
          accL[n] = __builtin_amdgcn_mfma_f32_16x16x32_bf16(aLh, bhv, accL[n], 0, 0, 0);
          accL[n] = __builtin_amdgcn_mfma_f32_16x16x32_bf16(aLh, blv, accL[n], 0, 0, 0);
          accL[n] = __builtin_amdgcn_mfma_f32_16x16x32_bf16(aLl, bhv, accL[n], 0, 0, 0);
          accC[n] = __builtin_amdgcn_mfma_f32_16x16x32_bf16(aCh, bhv, accC[n], 0, 0, 0);
          accC[n] = __builtin_amdgcn_mfma_f32_16x16x32_bf16(aCh, blv, accC[n], 0, 0, 0);
          accC[n] = __builtin_amdgcn_mfma_f32_16x16x32_bf16(aCl, bhv, accC[n], 0, 0, 0);
        }
      }
      __syncthreads();
    }
    // outputs: kv partials (D layout: row = quad*4+q, col = l16)
    const int obase = part * 131072 + bh * 4096;
#pragma unroll
    for (int n = 0; n < 4; ++n)
#pragma unroll
      for (int q = 0; q < 4; ++q) {
        int o = obase + (dblk + quad * 4 + q) * 64 + n * 16 + l16;
        kvpL[o] = accL[n][q];
        kvpC[o] = accC[n][q];
      }
    kslp += __shfl_xor(kslp, 16);
    kslp += __shfl_xor(kslp, 32);
    kscp += __shfl_xor(kscp, 16);
    kscp += __shfl_xor(kscp, 32);
    if (quad == 0) {
      kspL[part * 2048 + bh * 64 + dblk + l16] = kslp;
      kspC[part * 2048 + bh * 64 + dblk + l16] = kscp;
    }
    vpart.x += __shfl_xor(vpart.x, 16); vpart.x += __shfl_xor(vpart.x, 32);
    vpart.y += __shfl_xor(vpart.y, 16); vpart.y += __shfl_xor(vpart.y, 32);
    vpart.z += __shfl_xor(vpart.z, 16); vpart.z += __shfl_xor(vpart.z, 32);
    vpart.w += __shfl_xor(vpart.w, 16); vpart.w += __shfl_xor(vpart.w, 32);
    if (quad == 0) vred[wv * 16 + l16] = vpart;
    __syncthreads();
    if (tid < 16) {
      float4 a0 = vred[tid], a1 = vred[16 + tid];
      float4 a2 = vred[32 + tid], a3 = vred[48 + tid];
      float4 s = make_float4(a0.x + a1.x + a2.x + a3.x, a0.y + a1.y + a2.y + a3.y,
                             a0.z + a1.z + a2.z + a3.z, a0.w + a1.w + a2.w + a3.w);
      *(float4*)&vsp[part * 2048 + bh * 64 + tid * 4] = s;
    }
  } else {
    // ---- pp_scores (fp32; sums the 8 split-K partials in fixed order) ----
    float (*ksL)[65] = (float(*)[65])smraw;  // 38*65*4 = 9880 B
    int bx = bx0 - 1536;
    int bh = bx >> 2, chunk = bx & 3;
    int b = bh >> 4, h = bh & 15;
    int t0 = chunk * 128;
    const float* Qb = Q + (b * LDEC) * DMODEL + h * HD;
    for (int slot = tid; slot < NSAMP * 16; slot += 256) {
      int r = slot >> 4, c4 = slot & 15;
      const float* kp = KsPart + r * 1024 + h * HD + c4 * 4;
      float4 kx = *(const float4*)kp;
#pragma unroll
      for (int p = 1; p < 8; ++p) {
        float4 k2 = *(const float4*)(kp + (size_t)p * (NSAMP * 1024));
        kx.x += k2.x; kx.y += k2.y; kx.z += k2.z; kx.w += k2.w;
      }
      ksL[r][c4 * 4 + 0] = kx.x; ksL[r][c4 * 4 + 1] = kx.y;
      ksL[r][c4 * 4 + 2] = kx.z; ksL[r][c4 * 4 + 3] = kx.w;
    }
    __syncthreads();
    if (tid < 128) {
      float qr[64];
      const float* qrow = Qb + (size_t)(t0 + tid) * DMODEL;
#pragma unroll
      for (int d4 = 0; d4 < 16; ++d4)
        *(float4*)&qr[d4 * 4] = *(const float4*)(qrow + d4 * 4);
      float mx = -INFINITY, sm = 0.f;
      for (int j = 0; j < NSAMP; ++j) {
        float s = 0.f;
#pragma unroll
        for (int d = 0; d < 64; ++d) s = fmaf(qr[d], ksL[j][d], s);
        s *= SCALE;
        mx = fmaxf(mx, s);
        sm += s;
      }
      Mout[bh * LDEC + t0 + tid] = mx - sm / (float)NSAMP;
    }
  }
}

// ------ MFMA flash attention (split-K 4 + XCD swizzle) FUSED with tail2 -----
// grid: [0,1024) attn | [1024,2072) reduce_all | [2072,2104) pp_topk.
// SAFETY: attn outputs (P0..P3, L0, L1, stats) live at ws+18M.. -- fully
// disjoint from tail2's inputs (kvp*, ksp*, vsp at ws+11M..15.1M) and
// outputs (ws+16M..). No cross-slice aliasing (R8's bug).
__global__ __launch_bounds__(256) void attn_mfma(
    const float* __restrict__ Qf, const unsigned short* __restrict__ Kb,
    const unsigned short* __restrict__ Vt,
    float* __restrict__ OsP0, float* __restrict__ OsP1,
    float* __restrict__ OsP2, float* __restrict__ OsP3,
    float* __restrict__ OlS0, float* __restrict__ OlS1,
    float* __restrict__ st,
    const float* __restrict__ kvpL, const float* __restrict__ kvpC,
    const float* __restrict__ kspL, const float* __restrict__ kspC,
    const float* __restrict__ vsp, float* __restrict__ kvL,
    float* __restrict__ kvC, float* __restrict__ ksL,
    float* __restrict__ ksC, float* __restrict__ vmean,
    const float* __restrict__ Mbuf, int* __restrict__ sel) {
  __shared__ unsigned short Ks[2][4096];
  __shared__ unsigned short Vs[2][4096];
  __shared__ unsigned short Ps[4][1024];
  const int tid = threadIdx.x;
  const int bxAll = blockIdx.x;
  if (bxAll >= 1024) {
    // ================= tail2 (independent of attn; fused launch) ===========
    int bx = bxAll - 1024;
    if (bx < 1048) {
      int i = bx * 256 + tid;
      if (i < 131072) {
        float s = 0.f;
#pragma unroll
        for (int p = 0; p < 16; ++p) s += kvpL[p * 131072 + i];
        kvL[i] = s;
      } else if (i < 262144) {
        int j = i - 131072;
        float s = 0.f;
#pragma unroll
        for (int p = 0; p < 16; ++p) s += kvpC[p * 131072 + j];
        kvC[j] = s;
      } else if (i < 268288) {
        int j = i - 262144;
        int which = j >> 11, jj = j & 2047;
        const float* src = which == 0 ? kspL : (which == 1 ? kspC : vsp);
        float s = 0.f;
#pragma unroll
        for (int p = 0; p < 16; ++p) s += src[p * 2048 + jj];
        if (which == 0) ksL[jj] = s;
        else if (which == 1) ksC[jj] = s;
        else vmean[jj] = s * (1.f / 2048.f);
      }
    } else {
      // ---- pp_topk (tie -> lower index), LDS aliased onto Ks/Vs ----
      char* smraw = (char*)Ks;
      float* vals = (float*)smraw;
      int* flag = (int*)(smraw + 2048);
      float* wvs = (float*)(smraw + 4096);
      int* wis = (int*)(smraw + 4112);
      int bh = bx - 1048;
      int lane = tid & 63, g = tid >> 6;
      vals[tid] = Mbuf[bh * 512 + tid];
      vals[tid + 256] = Mbuf[bh * 512 + tid + 256];
      flag[tid] = 0; flag[tid + 256] = 0;
      __syncthreads();
      for (int it = 0; it < NTOP; ++it) {
        float v0 = vals[tid]; int i0 = tid;
        float v1 = vals[tid + 256];
        if (v1 > v0) { v0 = v1; i0 = tid + 256; }
#pragma unroll
        for (int mm = 32; mm > 0; mm >>= 1) {
          float ov = __shfl_xor(v0, mm);
          int oi = __shfl_xor(i0, mm);
          if (ov > v0 || (ov == v0 && oi < i0)) { v0 = ov; i0 = oi; }
        }
        if (lane == 0) { wvs[g] = v0; wis[g] = i0; }
        __syncthreads();
        if (tid == 0) {
          float bv = wvs[0]; int bi = wis[0];
#pragma unroll
          for (int w = 1; w < 4; ++w)
            if (wvs[w] > bv || (wvs[w] == bv && wis[w] < bi)) { bv = wvs[w]; bi = wis[w]; }
          vals[bi] = -INFINITY;
          flag[bi] = 1;
        }
        __syncthreads();
      }
      sel[bh * 512 + tid] = flag[tid];
      sel[bh * 512 + tid + 256] = flag[tid + 256];
    }
    return;
  }
  // ========================= attention proper ==============================
  const int wave = tid >> 6, lane = tid & 63;
  const int l16 = lane & 15, quad = lane >> 4;
  const int bx = bxAll;
  const int xcd = bx & 7, sub = bx >> 3;
  const int qt = sub & 7, qr = (sub >> 3) & 3, grp = sub >> 5;
  const int bh = xcd + 8 * grp;
  const int b = bh >> 4, h = bh & 15;
  const int tbase = qt * 64 + wave * 16;
  const int sbase = qr * 512;

  const float* qrow = Qf + (size_t)(b * LDEC + tbase + l16) * DMODEL + h * HD + quad * 8;
  bf16x8 qa0, qa1;
  {
    float4 a0 = *(const float4*)qrow, a1 = *(const float4*)(qrow + 4);
    float4 a2 = *(const float4*)(qrow + 32), a3 = *(const float4*)(qrow + 36);
    qa0[0] = f2bf(a0.x * SCALE); qa0[1] = f2bf(a0.y * SCALE);
    qa0[2] = f2bf(a0.z * SCALE); qa0[3] = f2bf(a0.w * SCALE);
    qa0[4] = f2bf(a1.x * SCALE); qa0[5] = f2bf(a1.y * SCALE);
    qa0[6] = f2bf(a1.z * SCALE); qa0[7] = f2bf(a1.w * SCALE);
    qa1[0] = f2bf(a2.x * SCALE); qa1[1] = f2bf(a2.y * SCALE);
    qa1[2] = f2bf(a2.z * SCALE); qa1[3] = f2bf(a2.w * SCALE);
    qa1[4] = f2bf(a3.x * SCALE); qa1[5] = f2bf(a3.y * SCALE);
    qa1[6] = f2bf(a3.z * SCALE); qa1[7] = f2bf(a3.w * SCALE);
  }

  // ones B-fragment: row-sum of P via MFMA (D col all equal)
  bf16x8 bone;
#pragma unroll
  for (int j = 0; j < 8; ++j) bone[j] = (short)0x3f80;

  int tA = tbase + l16;
  int cA = min(4 * tA, LENC - 1);
  int loA = max(cA - 256, 0), hiA = min(cA + 256, LENC - 1);
  const int loW = max(4 * tbase - 256, 0);
  const int hiW = min(4 * (tbase + 15) + 256, LENC - 1);
  const bool blockAny = (sbase <= hiW) && (sbase + 511 >= loW);

  f32x4 Os[4], Ol[4], Ssum, Slsum;
#pragma unroll
  for (int n = 0; n < 4; ++n) {
    Os[n] = (f32x4){0.f, 0.f, 0.f, 0.f};
    Ol[n] = (f32x4){0.f, 0.f, 0.f, 0.f};
  }
  Ssum = (f32x4){0.f, 0.f, 0.f, 0.f};
  Slsum = (f32x4){0.f, 0.f, 0.f, 0.f};

  const int c0 = tid, c1 = tid + 256;
  const unsigned short* kg0 = Kb + (size_t)(b * LENC + sbase + (c0 >> 3)) * DMODEL + h * HD + (c0 & 7) * 8;
  const unsigned short* kg1 = Kb + (size_t)(b * LENC + sbase + (c1 >> 3)) * DMODEL + h * HD + (c1 & 7) * 8;
  const unsigned short* vg0 = Vt + (size_t)(bh * 64 + (c0 >> 3)) * LENC + sbase + (c0 & 7) * 8;
  const unsigned short* vg1 = Vt + (size_t)(bh * 64 + (c1 >> 3)) * LENC + sbase + (c1 & 7) * 8;
  const int of0 = sws(c0 >> 3, (c0 & 7) * 8);
  const int of1 = sws(c1 >> 3, (c1 & 7) * 8);

  uint4 pk0, pk1, pv0, pv1;
  pk0 = *(const uint4*)kg0; pk1 = *(const uint4*)kg1;
  pv0 = *(const uint4*)vg0; pv1 = *(const uint4*)vg1;
  *(uint4*)&Ks[0][of0] = pk0; *(uint4*)&Ks[0][of1] = pk1;
  *(uint4*)&Vs[0][of0] = pv0; *(uint4*)&Vs[0][of1] = pv1;
  __syncthreads();

  for (int it = 0; it < 8; ++it) {
    const int cur = it & 1;
    const int s0 = sbase + it * 64;
    const bool anyL = (s0 <= hiW) && (s0 + 63 >= loW);
    if (it < 7) {
      pk0 = *(const uint4*)(kg0 + (size_t)(it + 1) * 64 * DMODEL);
      pk1 = *(const uint4*)(kg1 + (size_t)(it + 1) * 64 * DMODEL);
      pv0 = *(const uint4*)(vg0 + (it + 1) * 64);
      pv1 = *(const uint4*)(vg1 + (it + 1) * 64);
    }
    const unsigned short* K_ = Ks[cur];
    const unsigned short* V_ = Vs[cur];

    f32x4 S[4];
#pragma unroll
    for (int n = 0; n < 4; ++n) {
      bf16x8 bk0 = *(const bf16x8*)&K_[sws(n * 16 + l16, quad * 8)];
      bf16x8 bk1 = *(const bf16x8*)&K_[sws(n * 16 + l16, 32 + quad * 8)];
      f32x4 z = (f32x4){0.f, 0.f, 0.f, 0.f};
      z = __builtin_amdgcn_mfma_f32_16x16x32_bf16(qa0, bk0, z, 0, 0, 0);
      S[n] = __builtin_amdgcn_mfma_f32_16x16x32_bf16(qa1, bk1, z, 0, 0, 0);
    }

    unsigned short* Pw = Ps[wave];
#pragma unroll
    for (int n = 0; n < 4; ++n)
#pragma unroll
      for (int r = 0; r < 4; ++r)
        Pw[sws(quad * 4 + r, n * 16 + l16)] = f2bf(__expf(S[n][r]));
    bf16x8 aP0 = *(const bf16x8*)&Pw[sws(l16, quad * 8)];
    bf16x8 aP1 = *(const bf16x8*)&Pw[sws(l16, 32 + quad * 8)];
    // row sums (softmax denominators) via ones-column MFMA
    Ssum = __builtin_amdgcn_mfma_f32_16x16x32_bf16(aP0, bone, Ssum, 0, 0, 0);
    Ssum = __builtin_amdgcn_mfma_f32_16x16x32_bf16(aP1, bone, Ssum, 0, 0, 0);
#pragma unroll
    for (int n = 0; n < 4; ++n) {
      bf16x8 bv0 = *(const bf16x8*)&V_[sws(n * 16 + l16, quad * 8)];
      bf16x8 bv1 = *(const bf16x8*)&V_[sws(n * 16 + l16, 32 + quad * 8)];
      Os[n] = __builtin_amdgcn_mfma_f32_16x16x32_bf16(aP0, bv0, Os[n], 0, 0, 0);
      Os[n] = __builtin_amdgcn_mfma_f32_16x16x32_bf16(aP1, bv1, Os[n], 0, 0, 0);
    }
    if (anyL) {
      bf16x8 aL0 = aP0, aL1 = aP1;
#pragma unroll
      for (int j = 0; j < 8; ++j) {
        int sc = s0 + quad * 8 + j;
        if (sc < loA || sc > hiA) aL0[j] = 0;
        if (sc + 32 < loA || sc + 32 > hiA) aL1[j] = 0;
      }
      Slsum = __builtin_amdgcn_mfma_f32_16x16x32_bf16(aL0, bone, Slsum, 0, 0, 0);
      Slsum = __builtin_amdgcn_mfma_f32_16x16x32_bf16(aL1, bone, Slsum, 0, 0, 0);
#pragma unroll
      for (int n = 0; n < 4; ++n) {
        bf16x8 bv0 = *(const bf16x8*)&V_[sws(n * 16 + l16, quad * 8)];
        bf16x8 bv1 = *(const bf16x8*)&V_[sws(n * 16 + l16, 32 + quad * 8)];
        Ol[n] = __builtin_amdgcn_mfma_f32_16x16x32_bf16(aL0, bv0, Ol[n], 0, 0, 0);
        Ol[n] = __builtin_amdgcn_mfma_f32_16x16x32_bf16(aL1, bv1, Ol[n], 0, 0, 0);
      }
    }
    // single barrier per iteration: all reads of buffer (1-cur) completed
    // before the previous iteration's barrier, so writing it now is safe.
    if (it < 7) {
      unsigned short* KL = Ks[1 - cur];
      unsigned short* VL = Vs[1 - cur];
      *(uint4*)&KL[of0] = pk0; *(uint4*)&KL[of1] = pk1;
      *(uint4*)&VL[of0] = pv0; *(uint4*)&VL[of1] = pv1;
    }
    __syncthreads();
  }

  float* osp = qr == 0 ? OsP0 : (qr == 1 ? OsP1 : (qr == 2 ? OsP2 : OsP3));
  float* olp = (qr & 1) ? OlS1 : OlS0;
  float* sp = st + qr * 32768;
#pragma unroll
  for (int r = 0; r < 4; ++r) {
    int t = tbase + quad * 4 + r;
#pragma unroll
    for (int n = 0; n < 4; ++n) {
      size_t o = (size_t)(b * LDEC + t) * DMODEL + h * HD + n * 16 + l16;
      osp[o] = Os[n][r];
      if (blockAny) olp[o] = Ol[n][r];
    }
    if (l16 == 0) {
      int sr = bh * 512 + t;
      sp[sr] = Ssum[r];
      sp[16384 + sr] = Slsum[r];
    }
  }
}

// fused: split-K-4 combine + probsparse fill + lin/cos apply.
// Emits bf16 DIRECTLY into b16 (the gemm_one input).
// grid: [0,1024) combine | [1024,5120) lin_cos.
__global__ __launch_bounds__(256) void combine_fill(
    const float* __restrict__ P0, const float* __restrict__ P1,
    const float* __restrict__ P2, const float* __restrict__ P3,
    const float* __restrict__ L0, const float* __restrict__ L1,
    const float* __restrict__ st,
    const float* __restrict__ vmean, const int* __restrict__ sel,
    const float* __restrict__ Q, const float* __restrict__ kvL,
    const float* __restrict__ kvC, const float* __restrict__ ksL,
    const float* __restrict__ ksC,
    unsigned short* __restrict__ b16) {
  __shared__ float sh[2][4][64];
  int bx0 = blockIdx.x;
  int tid = threadIdx.x;
  if (bx0 < 1024) {
    int i4 = bx0 * 256 + tid;
    int i = i4 * 4;
    int col = i & 1023, bt = i >> 10;
    int t = bt & 511, b = bt >> 9, h = col >> 6, d = col & 63;
    int bh = b * 16 + h;
    int sr = bh * 512 + t;
    float iS = 1.f / (st[sr] + st[32768 + sr] + st[65536 + sr] + st[98304 + sr]);
    float iL = 1.f / (st[16384 + sr] + st[49152 + sr] + st[81920 + sr] + st[114688 + sr]);
    float4 s0 = *(const float4*)(P0 + i);
    float4 s1 = *(const float4*)(P1 + i);
    float4 s2 = *(const float4*)(P2 + i);
    float4 s3 = *(const float4*)(P3 + i);
    // local-branch: row t's window touches quarters q0..q1 (q1-q0 <= 1);
    // quarter q wrote parity slot q&1 (slot0 = L0, slot1 = L1).
    int c = min(4 * t, LENC - 1);
    int lo = max(c - 256, 0), hi = min(c + 256, LENC - 1);
    int q0 = lo >> 9, q1 = hi >> 9;
    const float* Lp0 = (q0 & 1) ? L1 : L0;
    float4 l = *(const float4*)(Lp0 + i);
    if (q1 != q0) {
      const float* Lp1 = (q1 & 1) ? L1 : L0;
      float4 l2 = *(const float4*)(Lp1 + i);
      l.x += l2.x; l.y += l2.y; l.z += l2.z; l.w += l2.w;
    }
    float4 os = make_float4((s0.x + s1.x + s2.x + s3.x) * iS,
                            (s0.y + s1.y + s2.y + s3.y) * iS,
                            (s0.z + s1.z + s2.z + s3.z) * iS,
                            (s0.w + s1.w + s2.w + s3.w) * iS);
    float4 ol = make_float4(l.x * iL, l.y * iL, l.z * iL, l.w * iL);
    float4 pp = sel[sr] ? os : *(const float4*)(vmean + bh * 64 + d);
    uint2 o2;
    o2.x = (unsigned)f2bf(os.x) | ((unsigned)f2bf(os.y) << 16);
    o2.y = (unsigned)f2bf(os.z) | ((unsigned)f2bf(os.w) << 16);
    *(uint2*)(b16 + i) = o2;
    o2.x = (unsigned)f2bf(pp.x) | ((unsigned)f2bf(pp.y) << 16);
    o2.y = (unsigned)f2bf(pp.z) | ((unsigned)f2bf(pp.w) << 16);
    *(uint2*)(b16 + 2097152 + i) = o2;
    o2.x = (unsigned)f2bf(ol.x) | ((unsigned)f2bf(ol.y) << 16);
    o2.y = (unsigned)f2bf(ol.z) | ((unsigned)f2bf(ol.w) << 16);
    *(uint2*)(b16 + 4194304 + i) = o2;
  } else {
    // ---- lin_cos_apply (bf16 direct out) ----
    int lane = tid & 63, g = tid >> 6;
    int row = (bx0 - 1024) * 4 + g;
    int bh = row >> 9, t = row & 511;
    int b = bh >> 4, h = bh & 15;
    float qv = Q[(b * LDEC + t) * DMODEL + h * HD + lane];
    float x = qv * SCALE;
    float qfl = x > 0.f ? x + 1.f : __expf(x);
    float qnorm = sqrtf(wave_sum(qv * qv));
    float qn = qv / fmaxf(qnorm, 1e-12f);
    float qfc = fmaxf(qn, 0.f) + 1e-6f;
    sh[0][g][lane] = qfl;
    sh[1][g][lane] = qfc;
    float denL = fmaxf(wave_sum(qfl * ksL[bh * 64 + lane]), 1e-6f);
    float denC = fmaxf(wave_sum(qfc * ksC[bh * 64 + lane]), 1e-6f);
    const float* kvLb = kvL + bh * 4096;
    const float* kvCb = kvC + bh * 4096;
    float aL = 0.f, aC = 0.f;
#pragma unroll
    for (int d = 0; d < 64; ++d) {
      aL = fmaf(sh[0][g][d], kvLb[d * 64 + lane], aL);
      aC = fmaf(sh[1][g][d], kvCb[d * 64 + lane], aC);
    }
    int o = (b * LDEC + t) * DMODEL + h * HD + lane;
    b16[1048576 + o] = f2bf(aL / denL);
    b16[3145728 + o] = f2bf(aC / denC);
  }
}

// ---------------- final combine
__global__ __launch_bounds__(256) void combine(
    const float* __restrict__ dec, const float* __restrict__ proj,
    const float* __restrict__ rmsw, const float* __restrict__ alphas,
    float* __restrict__ out) {
  __shared__ float red[4];
  int row = blockIdx.x;
  int tid = threadIdx.x, lane = tid & 63, g = tid >> 6;
  int base = row * DMODEL + tid * 4;
  float4 dv = *(const float4*)(dec + base);
  float4 wv = *(const float4*)(rmsw + tid * 4);
  float a[6];
  float amax = -INFINITY;
#pragma unroll
  for (int i = 0; i < 6; ++i) { a[i] = alphas[i]; amax = fmaxf(amax, a[i]); }
  float asum = 0.f;
#pragma unroll
  for (int i = 0; i < 6; ++i) { a[i] = __expf(a[i] - amax); asum += a[i]; }
#pragma unroll
  for (int i = 0; i < 6; ++i) a[i] /= asum;
  float4 acc = make_float4(a[0] * dv.x, a[0] * dv.y, a[0] * dv.z, a[0] * dv.w);
  for (int br = 0; br < 5; ++br) {
    float4 pv = *(const float4*)(proj + br * 1048576 + base);
    float4 xx = make_float4(dv.x + pv.x, dv.y + pv.y, dv.z + pv.z, dv.w + pv.w);
    float ssq = xx.x * xx.x + xx.y * xx.y + xx.z * xx.z + xx.w * xx.w;
    float wsum = wave_sum(ssq);
    if (lane == 0) red[g] = wsum;
    __syncthreads();
    float tot = red[0] + red[1] + red[2] + red[3];
    float rr = rsqrtf(tot / 1024.f + 1e-6f);
    float wb = a[br + 1];
    acc.x += wb * xx.x * rr * wv.x;
    acc.y += wb * xx.y * rr * wv.y;
    acc.z += wb * xx.z * rr * wv.z;
    acc.w += wb * xx.w * rr * wv.w;
    __syncthreads();
  }
  *(float4*)(out + base) = acc;
}

extern "C" void kernel_launch(void* const* d_in, const int* in_sizes, int n_in,
                              void* d_out, int out_size, void* d_ws, size_t ws_size,
                              hipStream_t stream) {
  const float* dec = (const float*)d_in[0];
  const float* enc = (const float*)d_in[1];
  const float* Wq = (const float*)d_in[2];
  const float* Wk = (const float*)d_in[3];
  const float* Wv = (const float*)d_in[4];
  const float* Wo = (const float*)d_in[5];
  const float* rmsw = (const float*)d_in[6];
  const float* alphas = (const float*)d_in[7];
  const int* sidx = (const int*)d_in[8];

  const size_t M = 1048576;
  float* ws = (float*)d_ws;
  float* Q    = ws;                                  // [0,1M)
  unsigned short* Kb16 = (unsigned short*)(ws + M);  // [1M,3M)
  float* KsPart = ws + 3 * M;                        // [3M,+311296)
  float* V    = ws + 5 * M;                          // [5M,9M)
  float* Vtb_f= ws + 9 * M;                          // [9M,11M)
  unsigned short* Wqh = (unsigned short*)(ws + 9 * M);
  unsigned short* Wql = (unsigned short*)(ws + 9 * M + M / 2);
  unsigned short* Wkh = (unsigned short*)(ws + 10 * M);
  unsigned short* Wvh = (unsigned short*)(ws + 10 * M + M / 2);
  unsigned short* eh  = (unsigned short*)(ws + 11 * M);
  unsigned short* dh  = (unsigned short*)(ws + 15 * M);
  unsigned short* dl  = (unsigned short*)(ws + 15 * M + M / 2);
  unsigned short* Vtb = (unsigned short*)Vtb_f;
  float* kvpL = ws + 11 * M;
  float* kvpC = ws + 13 * M;
  float* kspL = ws + 15 * M;
  float* kspC = ws + 15 * M + 32768;
  float* vsp  = ws + 15 * M + 65536;
  float* tail = ws + 16 * M;
  float* kvL  = tail;
  float* kvC  = tail + 131072;
  float* ksL  = tail + 262144;
  float* ksC  = tail + 264192;
  float* vmean= tail + 266240;
  float* Mbuf = tail + 317440;
  int*   sel  = (int*)(tail + 333824);
  // bf16 GEMM inputs: braw16 written by combine_fill; Woh by prologue.
  unsigned short* braw16 = (unsigned short*)(ws + 12 * M);
  unsigned short* Woh = (unsigned short*)(ws + 17 * M);
  // attn split-K-4 partials: VIRGIN regions (>=18M) so the fused
  // attn+tail2 kernel has zero aliasing between its two slices.
  float* P0   = ws + 18 * M;
  float* OsP1 = ws + 19 * M;
  float* OsP2 = ws + 20 * M;
  float* OsP3 = ws + 21 * M;
  float* OlS0 = ws + 22 * M;
  float* OlS1 = ws + 23 * M;
  float* stats = ws + 24 * M;  // 4*32768 floats
  float* proj = ws + 3 * M + M / 2;

  hipLaunchKernelGGL(prologue, dim3(7360), dim3(256), 17408, stream,
                     dec, enc, Wq, Wk, Wv, sidx, dh, dl, eh, Wqh, Wql, Wkh, Wvh,
                     KsPart, Wo, Woh);
  hipLaunchKernelGGL(gemm_qkv, dim3(72, 8), dim3(512), 81920, stream,
                     dh, dl, Wqh, Wql, Q, eh, Wkh, Kb16, Wvh, V);
  hipLaunchKernelGGL(trio, dim3(1664), dim3(256), 34816, stream,
                     V, Vtb, Kb16, kvpL, kvpC, kspL, kspC, vsp, Q, KsPart, Mbuf);
  hipLaunchKernelGGL(attn_mfma, dim3(2104), dim3(256), 0, stream, Q, Kb16, Vtb,
                     P0, OsP1, OsP2, OsP3, OlS0, OlS1, stats,
                     kvpL, kvpC, kspL, kspC, vsp, kvL, kvC, ksL, ksC, vmean,
                     Mbuf, sel);
  hipLaunchKernelGGL(combine_fill, dim3(5120), dim3(256), 0, stream,
                     P0, OsP1, OsP2, OsP3, OlS0, OlS1, stats, vmean, sel,
                     Q, kvL, kvC, ksL, ksC, braw16);
  hipLaunchKernelGGL(gemm_one, dim3(40, 8), dim3(512), 65536, stream, braw16, Woh, proj);
  hipLaunchKernelGGL(combine, dim3(1024), dim3(256), 0, stream, dec, proj, rmsw, alphas,
                     (float*)d_out);
}

// Round 11
// 249.863 us; speedup vs baseline: 1.2141x; 1.0727x over previous
//
#include <hip/hip_runtime.h>
#include <math.h>

#define LDEC 512
#define LENC 2048
#define DMODEL 1024
#define NH 16
#define HD 64
#define SCALE 0.125f
#define NTOP 31
#define NSAMP 38

typedef __attribute__((ext_vector_type(8))) short bf16x8;
typedef __attribute__((ext_vector_type(4))) float f32x4;

__device__ inline float wave_sum(float v) {
#pragma unroll
  for (int m = 32; m > 0; m >>= 1) v += __shfl_xor(v, m);
  return v;
}

__device__ inline unsigned short f2bf(float x) {
  unsigned u = __float_as_uint(x);
  u += 0x7fff + ((u >> 16) & 1);  // RNE
  return (unsigned short)(u >> 16);
}
__device__ inline float bf2f(unsigned short h) {
  return __uint_as_float(((unsigned)h) << 16);
}

// async HBM -> LDS, 16 B per lane; lds base must be wave-uniform
__device__ __forceinline__ void gld16(const unsigned short* g, unsigned short* l) {
  __builtin_amdgcn_global_load_lds(
      (const __attribute__((address_space(1))) unsigned int*)g,
      (__attribute__((address_space(3))) unsigned int*)l, 16, 0, 0);
}

// XOR-swizzled LDS index (row stride 64 shorts = 128 B): kills the
// stride-128B bank-conflict pattern; col must stay within [0,64).
__device__ __forceinline__ int sws(int row, int col) {
  return row * 64 + (col ^ ((row & 7) << 3));
}

// ====== FUSED PROLOGUE: cvt_in + cvt_w3 + k_samp + cvt_w(Wo) ================
// grid: [0,5120) cvt_in | [5120,5888) cvt_w3 | [5888,7104) k_samp split-K |
// [7104,7360) Wo cvt (input-only dep; moved OFF the post-attn critical path).
// dyn LDS 17408.
__global__ __launch_bounds__(256) void prologue(
    const float* __restrict__ dec, const float* __restrict__ enc,
    const float* __restrict__ Wq, const float* __restrict__ Wk,
    const float* __restrict__ Wv, const int* __restrict__ sidx,
    unsigned short* __restrict__ dh, unsigned short* __restrict__ dl,
    unsigned short* __restrict__ eh,
    unsigned short* __restrict__ Wqh, unsigned short* __restrict__ Wql,
    unsigned short* __restrict__ Wkh, unsigned short* __restrict__ Wvh,
    float* __restrict__ KsPart,
    const float* __restrict__ Wo, unsigned short* __restrict__ Woh) {
  extern __shared__ char smraw[];
  int bx = blockIdx.x;
  int tid = threadIdx.x;
  if (bx < 5120) {
    // ---- cvt_in ----
    int i = bx * 256 + tid;
    if (i < 262144) {
      float4 v = ((const float4*)dec)[i];
      ushort4 h = make_ushort4(f2bf(v.x), f2bf(v.y), f2bf(v.z), f2bf(v.w));
      ushort4 l = make_ushort4(f2bf(v.x - bf2f(h.x)), f2bf(v.y - bf2f(h.y)),
                               f2bf(v.z - bf2f(h.z)), f2bf(v.w - bf2f(h.w)));
      *(ushort4*)(dh + i * 4) = h;
      *(ushort4*)(dl + i * 4) = l;
    } else {
      int j = i - 262144;
      float4 v = ((const float4*)enc)[j];
      *(ushort4*)(eh + j * 4) =
          make_ushort4(f2bf(v.x), f2bf(v.y), f2bf(v.z), f2bf(v.w));
    }
  } else if (bx < 5888) {
    // ---- cvt_w3 ----
    float (*t)[68] = (float(*)[68])smraw;
    int wb = bx - 5120;
    int which = wb >> 8, rem = wb & 255;
    const float* W = which == 0 ? Wq : (which == 1 ? Wk : Wv);
    unsigned short* Th = which == 0 ? Wqh : (which == 1 ? Wkh : Wvh);
    unsigned short* Tl = which == 0 ? Wql : nullptr;
    int k0 = (rem >> 4) * 64, n0 = (rem & 15) * 64;
#pragma unroll
    for (int i = 0; i < 4; ++i) {
      int c = tid + 256 * i;
      int r = c >> 4, c4 = (c & 15) * 4;
      float4 v = *(const float4*)(W + (size_t)(k0 + r) * DMODEL + n0 + c4);
      t[c4 + 0][r] = v.x; t[c4 + 1][r] = v.y; t[c4 + 2][r] = v.z; t[c4 + 3][r] = v.w;
    }
    __syncthreads();
#pragma unroll
    for (int i = 0; i < 4; ++i) {
      int c = tid + 256 * i;
      int n = c >> 4, k4 = (c & 15) * 4;
      float4 v = *(const float4*)&t[n][k4];
      ushort4 h = make_ushort4(f2bf(v.x), f2bf(v.y), f2bf(v.z), f2bf(v.w));
      *(ushort4*)(Th + (size_t)(n0 + n) * DMODEL + k0 + k4) = h;
      if (Tl) {
        ushort4 l = make_ushort4(f2bf(v.x - bf2f(h.x)), f2bf(v.y - bf2f(h.y)),
                                 f2bf(v.z - bf2f(h.z)), f2bf(v.w - bf2f(h.w)));
        *(ushort4*)(Tl + (size_t)(n0 + n) * DMODEL + k0 + k4) = l;
      }
    }
  } else if (bx < 7104) {
    // ---- k_samp split-K (fp32; 38s x 4 col-chunks x 8 k-chunks) ----
    float* er = (float*)smraw;  // 128 floats
    int sb = bx - 5888;         // 0..1215
    int s = sb >> 5;            // 0..37
    int rem = sb & 31;
    int cchunk = rem >> 3, kc = rem & 7;
    int c = cchunk * 256 + tid;
    int srow = sidx[s];
    if (tid < 32) {
      int idx = tid * 4;
      *(float4*)&er[idx] =
          *(const float4*)(enc + (size_t)srow * DMODEL + kc * 128 + idx);
    }
    __syncthreads();
    float acc = 0.f;
    const float* wp = Wk + (size_t)(kc * 128) * DMODEL + c;
    for (int k0 = 0; k0 < 128; k0 += 16) {
      float w[16];
#pragma unroll
      for (int j = 0; j < 16; ++j) w[j] = wp[(size_t)(k0 + j) * DMODEL];
#pragma unroll
      for (int j = 0; j < 16; ++j) acc = fmaf(er[k0 + j], w[j], acc);
    }
    KsPart[(size_t)kc * (NSAMP * 1024) + s * 1024 + c] = acc;
  } else {
    // ---- cvt_w (Wo transpose -> bf16) ----
    float (*tl)[68] = (float(*)[68])smraw;
    int wb = bx - 7104;
    int k0 = (wb >> 4) * 64, n0 = (wb & 15) * 64;
#pragma unroll
    for (int i = 0; i < 4; ++i) {
      int c = tid + 256 * i;
      int r = c >> 4, c4 = (c & 15) * 4;
      float4 v = *(const float4*)(Wo + (size_t)(k0 + r) * DMODEL + n0 + c4);
      tl[c4 + 0][r] = v.x; tl[c4 + 1][r] = v.y; tl[c4 + 2][r] = v.z; tl[c4 + 3][r] = v.w;
    }
    __syncthreads();
#pragma unroll
    for (int i = 0; i < 4; ++i) {
      int c = tid + 256 * i;
      int n = c >> 4, k4 = (c & 15) * 4;
      float4 v = *(const float4*)&tl[n][k4];
      *(ushort4*)(Woh + (size_t)(n0 + n) * DMODEL + k0 + k4) =
          make_ushort4(f2bf(v.x), f2bf(v.y), f2bf(v.z), f2bf(v.w));
    }
  }
}

// ======= shared epilogue: 64x32 wave tile via LDS transpose (stride 36) ====
template <int BF16OUT>
__device__ __forceinline__ void gemm_epilogue(
    unsigned short* sm, f32x4 (&acc)[4][2], float* __restrict__ C,
    unsigned short* __restrict__ Cb, int row0, int col0, int wave, int lane) {
  const int l16 = lane & 15, quad = lane >> 4;
  float* eL = (float*)sm + wave * 576;
  const int rr = lane >> 2, cc = (lane & 3) * 8;
  const int wr = wave >> 2, wc = wave & 3;
#pragma unroll
  for (int x = 0; x < 4; ++x) {
#pragma unroll
    for (int y = 0; y < 2; ++y)
#pragma unroll
      for (int q = 0; q < 4; ++q)
        eL[(quad * 4 + q) * 36 + y * 16 + l16] = acc[x][y][q];
    float4 v0 = *(const float4*)&eL[rr * 36 + cc];
    float4 v1 = *(const float4*)&eL[rr * 36 + cc + 4];
    size_t ro = (size_t)(row0 + wr * 64 + x * 16 + rr) * DMODEL + col0 + wc * 32 + cc;
    if (BF16OUT) {
      uint2 o;
      o.x = (unsigned)f2bf(v0.x) | ((unsigned)f2bf(v0.y) << 16);
      o.y = (unsigned)f2bf(v0.z) | ((unsigned)f2bf(v0.w) << 16);
      *(uint2*)(Cb + ro) = o;
      o.x = (unsigned)f2bf(v1.x) | ((unsigned)f2bf(v1.y) << 16);
      o.y = (unsigned)f2bf(v1.z) | ((unsigned)f2bf(v1.w) << 16);
      *(uint2*)(Cb + ro + 4) = o;
    } else {
      *(float4*)(C + ro) = v0;
      *(float4*)(C + ro + 4) = v1;
    }
  }
}

// ======= 1-pass bf16 GEMM, 512 thr, wave-tile 64x32, ASYNC global->LDS ====
// BK=64, full sws XOR swizzle (attn-proven, 0 conflicts).
template <int BF16OUT>
__device__ __forceinline__ void gemm512_1p_async(
    const unsigned short* __restrict__ Ah, const unsigned short* __restrict__ Bh,
    float* __restrict__ C, unsigned short* __restrict__ Cb, int row0, int col0) {
  extern __shared__ unsigned short sm[];
  const int BUFS = 16384;  // shorts per buffer (A 8192 | B 8192)
  const int tid = threadIdx.x, lane = tid & 63, wave = tid >> 6;
  const int l16 = lane & 15, quad = lane >> 4;
  const int wr = wave >> 2, wc = wave & 3;

  const int srow = wave * 16 + (lane >> 3);
  const int scol = ((lane & 7) ^ (lane >> 3)) * 8;
  const unsigned short* gA = Ah + (size_t)(row0 + srow) * DMODEL + scol;
  const unsigned short* gB = Bh + (size_t)(col0 + srow) * DMODEL + scol;
  const int wofs = wave * 1024;

  f32x4 acc[4][2];
#pragma unroll
  for (int x = 0; x < 4; ++x)
#pragma unroll
    for (int y = 0; y < 2; ++y) acc[x][y] = (f32x4){0.f, 0.f, 0.f, 0.f};

  gld16(gA, sm + wofs);
  gld16(gA + (size_t)8 * DMODEL, sm + wofs + 512);
  gld16(gB, sm + 8192 + wofs);
  gld16(gB + (size_t)8 * DMODEL, sm + 8192 + wofs + 512);
  __syncthreads();

  for (int it = 0; it < 16; ++it) {
    const unsigned short* cur = sm + (it & 1) * BUFS;
    if (it < 15) {
      int ko = (it + 1) * 64;
      unsigned short* nxt = sm + ((it + 1) & 1) * BUFS;
      gld16(gA + ko, nxt + wofs);
      gld16(gA + (size_t)8 * DMODEL + ko, nxt + wofs + 512);
      gld16(gB + ko, nxt + 8192 + wofs);
      gld16(gB + (size_t)8 * DMODEL + ko, nxt + 8192 + wofs + 512);
    }
    bf16x8 a[2][4], b[2][2];
#pragma unroll
    for (int ks = 0; ks < 2; ++ks) {
#pragma unroll
      for (int x = 0; x < 4; ++x)
        a[ks][x] = *(const bf16x8*)&cur[sws(wr * 64 + x * 16 + l16, ks * 32 + quad * 8)];
#pragma unroll
      for (int y = 0; y < 2; ++y)
        b[ks][y] = *(const bf16x8*)&cur[8192 + sws(wc * 32 + y * 16 + l16, ks * 32 + quad * 8)];
    }
#pragma unroll
    for (int ks = 0; ks < 2; ++ks)
#pragma unroll
      for (int x = 0; x < 4; ++x)
#pragma unroll
        for (int y = 0; y < 2; ++y)
          acc[x][y] = __builtin_amdgcn_mfma_f32_16x16x32_bf16(a[ks][x], b[ks][y], acc[x][y], 0, 0, 0);
    __syncthreads();
  }
  gemm_epilogue<BF16OUT>(sm, acc, C, Cb, row0, col0, wave, lane);
}

// ======= 3-pass hi/lo GEMM, 512 thr, padded dbuf (unchanged from best) =====
__device__ __forceinline__ void gemm512_3p(
    const unsigned short* __restrict__ Ah, const unsigned short* __restrict__ Al,
    const unsigned short* __restrict__ Bh, const unsigned short* __restrict__ Bl,
    float* __restrict__ C, int row0, int col0) {
  extern __shared__ unsigned short sm[];
  const int BUFS = 20480;
  const int tid = threadIdx.x, lane = tid & 63, wave = tid >> 6;
  const int l16 = lane & 15, quad = lane >> 4;
  const int wr = wave >> 2, wc = wave & 3;

  const int r = tid >> 2, kc = tid & 3;
  const unsigned short* gAh = Ah + (size_t)(row0 + r) * DMODEL + kc * 8;
  const unsigned short* gBh = Bh + (size_t)(col0 + r) * DMODEL + kc * 8;
  const unsigned short* gAl = Al + (size_t)(row0 + r) * DMODEL + kc * 8;
  const unsigned short* gBl = Bl + (size_t)(col0 + r) * DMODEL + kc * 8;
  const int lofs = r * 40 + kc * 8;

  f32x4 acc[4][2];
#pragma unroll
  for (int x = 0; x < 4; ++x)
#pragma unroll
    for (int y = 0; y < 2; ++y) acc[x][y] = (f32x4){0.f, 0.f, 0.f, 0.f};

  uint4 pah = *(const uint4*)gAh, pbh = *(const uint4*)gBh;
  uint4 pal = *(const uint4*)gAl, pbl = *(const uint4*)gBl;
  *(uint4*)&sm[lofs] = pah;
  *(uint4*)&sm[5120 + lofs] = pbh;
  *(uint4*)&sm[10240 + lofs] = pal;
  *(uint4*)&sm[15360 + lofs] = pbl;
  pah = *(const uint4*)(gAh + 32);
  pbh = *(const uint4*)(gBh + 32);
  pal = *(const uint4*)(gAl + 32);
  pbl = *(const uint4*)(gBl + 32);
  __syncthreads();

  for (int it = 0; it < 32; ++it) {
    const unsigned short* cur = sm + (it & 1) * BUFS;
    bf16x8 ah[4], bh[2], al[4], bl[2];
#pragma unroll
    for (int x = 0; x < 4; ++x) {
      ah[x] = *(const bf16x8*)&cur[(wr * 64 + x * 16 + l16) * 40 + quad * 8];
      al[x] = *(const bf16x8*)&cur[10240 + (wr * 64 + x * 16 + l16) * 40 + quad * 8];
    }
#pragma unroll
    for (int y = 0; y < 2; ++y) {
      bh[y] = *(const bf16x8*)&cur[5120 + (wc * 32 + y * 16 + l16) * 40 + quad * 8];
      bl[y] = *(const bf16x8*)&cur[15360 + (wc * 32 + y * 16 + l16) * 40 + quad * 8];
    }
#pragma unroll
    for (int x = 0; x < 4; ++x)
#pragma unroll
      for (int y = 0; y < 2; ++y) {
        acc[x][y] = __builtin_amdgcn_mfma_f32_16x16x32_bf16(ah[x], bh[y], acc[x][y], 0, 0, 0);
        acc[x][y] = __builtin_amdgcn_mfma_f32_16x16x32_bf16(ah[x], bl[y], acc[x][y], 0, 0, 0);
        acc[x][y] = __builtin_amdgcn_mfma_f32_16x16x32_bf16(al[x], bh[y], acc[x][y], 0, 0, 0);
      }
    if (it < 31) {
      unsigned short* nxt = sm + ((it + 1) & 1) * BUFS;
      *(uint4*)&nxt[lofs] = pah;
      *(uint4*)&nxt[5120 + lofs] = pbh;
      *(uint4*)&nxt[10240 + lofs] = pal;
      *(uint4*)&nxt[15360 + lofs] = pbl;
      if (it < 30) {
        int ko = (it + 2) * 32;
        pah = *(const uint4*)(gAh + ko);
        pbh = *(const uint4*)(gBh + ko);
        pal = *(const uint4*)(gAl + ko);
        pbl = *(const uint4*)(gBl + ko);
      }
    }
    __syncthreads();
  }
  gemm_epilogue<0>(sm, acc, C, nullptr, row0, col0, wave, lane);
}

// merged Q(3-pass) + K(1-pass async, bf16-out) + V(1-pass async)
__global__ __launch_bounds__(512, 4) void gemm_qkv(
    const unsigned short* __restrict__ dh, const unsigned short* __restrict__ dl,
    const unsigned short* __restrict__ Wqh, const unsigned short* __restrict__ Wql,
    float* __restrict__ Q,
    const unsigned short* __restrict__ eh, const unsigned short* __restrict__ Wkh,
    unsigned short* __restrict__ Kb16,
    const unsigned short* __restrict__ Wvh, float* __restrict__ V) {
  int bx = blockIdx.x;
  if (bx < 8)
    gemm512_3p(dh, dl, Wqh, Wql, Q, bx * 128, blockIdx.y * 128);
  else if (bx < 40)
    gemm512_1p_async<1>(eh, Wkh, nullptr, Kb16, (bx - 8) * 128, blockIdx.y * 128);
  else
    gemm512_1p_async<0>(eh, Wvh, V, nullptr, (bx - 40) * 128, blockIdx.y * 128);
}

__global__ __launch_bounds__(512, 4) void gemm_one(
    const unsigned short* __restrict__ Ah, const unsigned short* __restrict__ Bh,
    float* __restrict__ C) {
  gemm512_1p_async<0>(Ah, Bh, C, nullptr, blockIdx.x * 128, blockIdx.y * 128);
}

// ============ FUSED TRIO: cvt_vt + lin_cos_stats(MFMA) + pp_scores ==========
// grid: [0,1024) cvt_vt | [1024,1536) lin_cos_stats | [1536,1664) pp_scores.
// dyn LDS 34816 B (max branch: lin_cos 34560).
__global__ __launch_bounds__(256, 4) void trio(
    const float* __restrict__ V, unsigned short* __restrict__ Vt,
    const unsigned short* __restrict__ Kb,
    float* __restrict__ kvpL, float* __restrict__ kvpC,
    float* __restrict__ kspL, float* __restrict__ kspC, float* __restrict__ vsp,
    const float* __restrict__ Q, const float* __restrict__ KsPart,
    float* __restrict__ Mout) {
  extern __shared__ char smraw[];
  int bx0 = blockIdx.x;
  int tid = threadIdx.x;
  if (bx0 < 1024) {
    // ---- cvt_vt ----
    unsigned short (*tile)[72] = (unsigned short(*)[72])smraw;
    int bh = bx0 >> 5;
    int s0 = (bx0 & 31) * 64;
    int b = bh >> 4, h = bh & 15;
#pragma unroll
    for (int i = 0; i < 4; ++i) {
      int c = tid + 256 * i;
      int s = c >> 4, d4 = (c & 15) * 4;
      float4 v = *(const float4*)(V + (size_t)(b * LENC + s0 + s) * DMODEL + h * HD + d4);
      tile[d4 + 0][s] = f2bf(v.x);
      tile[d4 + 1][s] = f2bf(v.y);
      tile[d4 + 2][s] = f2bf(v.z);
      tile[d4 + 3][s] = f2bf(v.w);
    }
    __syncthreads();
#pragma unroll
    for (int i = 0; i < 2; ++i) {
      int c = tid + 256 * i;
      int d = c >> 3, soff = (c & 7) * 8;
      uint4 o = *(const uint4*)&tile[d][soff];
      *(uint4*)(Vt + (size_t)(bh * 64 + d) * LENC + s0 + soff) = o;
    }
  } else if (bx0 < 1536) {
    // ---- lin_cos_stats via hi/lo bf16 MFMA 3-pass ----
    float (*Kt)[65] = (float(*)[65])smraw;                          // 16640 B
    unsigned int (*Vu)[65] = (unsigned int(*)[65])(smraw + 16640);  // 16640 B
    float* nrm = (float*)(smraw + 33280);                           //   256 B
    float4* vred = (float4*)(smraw + 33536);                        //  1024 B
    int bx = bx0 - 1024;
    int bh = bx >> 4, part = bx & 15;
    int b = bh >> 4, h = bh & 15;
    const int lane = tid & 63, wv = tid >> 6;
    const int l16 = lane & 15, quad = lane >> 4;
    const int dblk = wv * 16;
    const unsigned short* Kg = Kb + (size_t)(b * LENC + part * 128) * DMODEL + h * HD;
    const float* Vg = V + (size_t)(b * LENC + part * 128) * DMODEL + h * HD;
    const int sK = tid >> 2, d16 = (tid & 3) * 16;
    const int sVb = tid >> 4, v4 = (tid & 15) * 4;

    f32x4 accL[4], accC[4];
#pragma unroll
    for (int n = 0; n < 4; ++n) {
      accL[n] = (f32x4){0.f, 0.f, 0.f, 0.f};
      accC[n] = (f32x4){0.f, 0.f, 0.f, 0.f};
    }
    float kslp = 0.f, kscp = 0.f;
    float4 vpart = make_float4(0.f, 0.f, 0.f, 0.f);

    for (int ch = 0; ch < 2; ++ch) {
      const int s0 = ch * 64;
      // stage K (bf16 -> f32) + row sumsq -> nrm
      {
        const unsigned short* kr = Kg + (size_t)(s0 + sK) * DMODEL + d16;
        uint4 p0 = *(const uint4*)kr;
        uint4 p1 = *(const uint4*)(kr + 8);
        float kvv[16];
        kvv[0] = __uint_as_float(p0.x << 16);
        kvv[1] = __uint_as_float(p0.x & 0xffff0000u);
        kvv[2] = __uint_as_float(p0.y << 16);
        kvv[3] = __uint_as_float(p0.y & 0xffff0000u);
        kvv[4] = __uint_as_float(p0.z << 16);
        kvv[5] = __uint_as_float(p0.z & 0xffff0000u);
        kvv[6] = __uint_as_float(p0.w << 16);
        kvv[7] = __uint_as_float(p0.w & 0xffff0000u);
        kvv[8] = __uint_as_float(p1.x << 16);
        kvv[9] = __uint_as_float(p1.x & 0xffff0000u);
        kvv[10] = __uint_as_float(p1.y << 16);
        kvv[11] = __uint_as_float(p1.y & 0xffff0000u);
        kvv[12] = __uint_as_float(p1.z << 16);
        kvv[13] = __uint_as_float(p1.z & 0xffff0000u);
        kvv[14] = __uint_as_float(p1.w << 16);
        kvv[15] = __uint_as_float(p1.w & 0xffff0000u);
        float ss = 0.f;
#pragma unroll
        for (int j = 0; j < 16; ++j) ss = fmaf(kvv[j], kvv[j], ss);
        ss += __shfl_xor(ss, 1);
        ss += __shfl_xor(ss, 2);
        if ((tid & 3) == 0) nrm[sK] = sqrtf(ss);
#pragma unroll
        for (int j = 0; j < 16; ++j) Kt[sK][d16 + j] = kvv[j];
      }
      // stage V (f32 -> packed hi|lo bf16) + column-sum partial
#pragma unroll
      for (int i = 0; i < 4; ++i) {
        int sv = sVb + 16 * i;
        float4 vv = *(const float4*)(Vg + (size_t)(s0 + sv) * DMODEL + v4);
        vpart.x += vv.x; vpart.y += vv.y; vpart.z += vv.z; vpart.w += vv.w;
        unsigned short h0 = f2bf(vv.x), h1 = f2bf(vv.y);
        unsigned short h2 = f2bf(vv.z), h3 = f2bf(vv.w);
        Vu[sv][v4 + 0] = ((unsigned)h0 << 16) | (unsigned)f2bf(vv.x - bf2f(h0));
        Vu[sv][v4 + 1] = ((unsigned)h1 << 16) | (unsigned)f2bf(vv.y - bf2f(h1));
        Vu[sv][v4 + 2] = ((unsigned)h2 << 16) | (unsigned)f2bf(vv.z - bf2f(h2));
        Vu[sv][v4 + 3] = ((unsigned)h3 << 16) | (unsigned)f2bf(vv.w - bf2f(h3));
      }
      __syncthreads();
      // fragment build + MFMA
#pragma unroll
      for (int kk = 0; kk < 2; ++kk) {
        const int sb = kk * 32 + quad * 8;
        bf16x8 aLh, aLl, aCh, aCl;
#pragma unroll
        for (int j = 0; j < 8; ++j) {
          float kval = Kt[sb + j][dblk + l16];
          float nn = nrm[sb + j];
          float kfl = kval > 0.f ? kval + 1.f : __expf(kval);
          float kn = kval / fmaxf(nn, 1e-12f);
          float kfc = fmaxf(kn, 0.f) + 1e-6f;
          kslp += kfl;
          kscp += kfc;
          unsigned short hL = f2bf(kfl);
          aLh[j] = hL;
          aLl[j] = f2bf(kfl - bf2f(hL));
          unsigned short hC = f2bf(kfc);
          aCh[j] = hC;
          aCl[j] = f2bf(kfc - bf2f(hC));
        }
#pragma unroll
        for (int n = 0; n < 4; ++n) {
          bf16x8 bhv, blv;
#pragma unroll
          for (int j = 0; j < 8; ++j) {
            unsigned uv = Vu[sb + j][n * 16 + l16];
            bhv[j] = (short)(unsigned short)(uv >> 16);
            blv[j] = (short)(unsigned short)(uv & 0xffffu);
          }
          accL[n] = __builtin_amdgcn_mfma_f32_16x16x32_bf16(aLh, bhv, accL[n], 0, 0, 0);
          accL[n] = __builtin_amdgcn_mfma_f32_16x16x32_bf16(aLh, blv, accL[n], 0, 0, 0);
          accL[n] = __builtin_amdgcn_mfma_f32_16x16x32_bf16(aLl, bhv, accL[n], 0, 0, 0);
          accC[n] = __builtin_amdgcn_mfma_f32_16x16x32_bf16(aCh, bhv, accC[n], 0, 0, 0);
          accC[n] = __builtin_amdgcn_mfma_f32_16x16x32_bf16(aCh, blv, accC[n], 0, 0, 0);
          accC[n] = __builtin_amdgcn_mfma_f32_16x16x32_bf16(aCl, bhv, accC[n], 0, 0, 0);
        }
      }
      __syncthreads();
    }
    // outputs: kv partials (D layout: row = quad*4+q, col = l16)
    const int obase = part * 131072 + bh * 4096;
#pragma unroll
    for (int n = 0; n < 4; ++n)
#pragma unroll
      for (int q = 0; q < 4; ++q) {
        int o = obase + (dblk + quad * 4 + q) * 64 + n * 16 + l16;
        kvpL[o] = accL[n][q];
        kvpC[o] = accC[n][q];
      }
    kslp += __shfl_xor(kslp, 16);
    kslp += __shfl_xor(kslp, 32);
    kscp += __shfl_xor(kscp, 16);
    kscp += __shfl_xor(kscp, 32);
    if (quad == 0) {
      kspL[part * 2048 + bh * 64 + dblk + l16] = kslp;
      kspC[part * 2048 + bh * 64 + dblk + l16] = kscp;
    }
    vpart.x += __shfl_xor(vpart.x, 16); vpart.x += __shfl_xor(vpart.x, 32);
    vpart.y += __shfl_xor(vpart.y, 16); vpart.y += __shfl_xor(vpart.y, 32);
    vpart.z += __shfl_xor(vpart.z, 16); vpart.z += __shfl_xor(vpart.z, 32);
    vpart.w += __shfl_xor(vpart.w, 16); vpart.w += __shfl_xor(vpart.w, 32);
    if (quad == 0) vred[wv * 16 + l16] = vpart;
    __syncthreads();
    if (tid < 16) {
      float4 a0 = vred[tid], a1 = vred[16 + tid];
      float4 a2 = vred[32 + tid], a3 = vred[48 + tid];
      float4 s = make_float4(a0.x + a1.x + a2.x + a3.x, a0.y + a1.y + a2.y + a3.y,
                             a0.z + a1.z + a2.z + a3.z, a0.w + a1.w + a2.w + a3.w);
      *(float4*)&vsp[part * 2048 + bh * 64 + tid * 4] = s;
    }
  } else {
    // ---- pp_scores (fp32; sums the 8 split-K partials in fixed order) ----
    float (*ksL)[65] = (float(*)[65])smraw;  // 38*65*4 = 9880 B
    int bx = bx0 - 1536;
    int bh = bx >> 2, chunk = bx & 3;
    int b = bh >> 4, h = bh & 15;
    int t0 = chunk * 128;
    const float* Qb = Q + (b * LDEC) * DMODEL + h * HD;
    for (int slot = tid; slot < NSAMP * 16; slot += 256) {
      int r = slot >> 4, c4 = slot & 15;
      const float* kp = KsPart + r * 1024 + h * HD + c4 * 4;
      float4 kx = *(const float4*)kp;
#pragma unroll
      for (int p = 1; p < 8; ++p) {
        float4 k2 = *(const float4*)(kp + (size_t)p * (NSAMP * 1024));
        kx.x += k2.x; kx.y += k2.y; kx.z += k2.z; kx.w += k2.w;
      }
      ksL[r][c4 * 4 + 0] = kx.x; ksL[r][c4 * 4 + 1] = kx.y;
      ksL[r][c4 * 4 + 2] = kx.z; ksL[r][c4 * 4 + 3] = kx.w;
    }
    __syncthreads();
    if (tid < 128) {
      float qr[64];
      const float* qrow = Qb + (size_t)(t0 + tid) * DMODEL;
#pragma unroll
      for (int d4 = 0; d4 < 16; ++d4)
        *(float4*)&qr[d4 * 4] = *(const float4*)(qrow + d4 * 4);
      float mx = -INFINITY, sm = 0.f;
      for (int j = 0; j < NSAMP; ++j) {
        float s = 0.f;
#pragma unroll
        for (int d = 0; d < 64; ++d) s = fmaf(qr[d], ksL[j][d], s);
        s *= SCALE;
        mx = fmaxf(mx, s);
        sm += s;
      }
      Mout[bh * LDEC + t0 + tid] = mx - sm / (float)NSAMP;
    }
  }
}

// ------ MFMA flash attention (split-K 4 + XCD swizzle) FUSED with tail2 -----
// grid: [0,1080) tail2 FIRST (cheap memory-bound blocks drain while attn
// streams in behind them) | [1080,2104) attn.
// SAFETY: attn outputs (P0..P3, L0, L1, stats) live at ws+18M.. -- fully
// disjoint from tail2's inputs (kvp*, ksp*, vsp at ws+11M..15.1M) and
// outputs (ws+16M..). No cross-slice aliasing.
__global__ __launch_bounds__(256) void attn_mfma(
    const float* __restrict__ Qf, const unsigned short* __restrict__ Kb,
    const unsigned short* __restrict__ Vt,
    float* __restrict__ OsP0, float* __restrict__ OsP1,
    float* __restrict__ OsP2, float* __restrict__ OsP3,
    float* __restrict__ OlS0, float* __restrict__ OlS1,
    float* __restrict__ st,
    const float* __restrict__ kvpL, const float* __restrict__ kvpC,
    const float* __restrict__ kspL, const float* __restrict__ kspC,
    const float* __restrict__ vsp, float* __restrict__ kvL,
    float* __restrict__ kvC, float* __restrict__ ksL,
    float* __restrict__ ksC, float* __restrict__ vmean,
    const float* __restrict__ Mbuf, int* __restrict__ sel) {
  __shared__ unsigned short Ks[2][4096];
  __shared__ unsigned short Vs[2][4096];
  __shared__ unsigned short Ps[4][1024];
  const int tid = threadIdx.x;
  const int bxAll = blockIdx.x;
  if (bxAll < 1080) {
    // ================= tail2 (independent of attn; fused launch) ===========
    int bx = bxAll;
    if (bx < 1048) {
      int i = bx * 256 + tid;
      if (i < 131072) {
        float s = 0.f;
#pragma unroll
        for (int p = 0; p < 16; ++p) s += kvpL[p * 131072 + i];
        kvL[i] = s;
      } else if (i < 262144) {
        int j = i - 131072;
        float s = 0.f;
#pragma unroll
        for (int p = 0; p < 16; ++p) s += kvpC[p * 131072 + j];
        kvC[j] = s;
      } else if (i < 268288) {
        int j = i - 262144;
        int which = j >> 11, jj = j & 2047;
        const float* src = which == 0 ? kspL : (which == 1 ? kspC : vsp);
        float s = 0.f;
#pragma unroll
        for (int p = 0; p < 16; ++p) s += src[p * 2048 + jj];
        if (which == 0) ksL[jj] = s;
        else if (which == 1) ksC[jj] = s;
        else vmean[jj] = s * (1.f / 2048.f);
      }
    } else {
      // ---- pp_topk (tie -> lower index), LDS aliased onto Ks/Vs ----
      char* smraw = (char*)Ks;
      float* vals = (float*)smraw;
      int* flag = (int*)(smraw + 2048);
      float* wvs = (float*)(smraw + 4096);
      int* wis = (int*)(smraw + 4112);
      int bh = bx - 1048;
      int lane = tid & 63, g = tid >> 6;
      vals[tid] = Mbuf[bh * 512 + tid];
      vals[tid + 256] = Mbuf[bh * 512 + tid + 256];
      flag[tid] = 0; flag[tid + 256] = 0;
      __syncthreads();
      for (int it = 0; it < NTOP; ++it) {
        float v0 = vals[tid]; int i0 = tid;
        float v1 = vals[tid + 256];
        if (v1 > v0) { v0 = v1; i0 = tid + 256; }
#pragma unroll
        for (int mm = 32; mm > 0; mm >>= 1) {
          float ov = __shfl_xor(v0, mm);
          int oi = __shfl_xor(i0, mm);
          if (ov > v0 || (ov == v0 && oi < i0)) { v0 = ov; i0 = oi; }
        }
        if (lane == 0) { wvs[g] = v0; wis[g] = i0; }
        __syncthreads();
        if (tid == 0) {
          float bv = wvs[0]; int bi = wis[0];
#pragma unroll
          for (int w = 1; w < 4; ++w)
            if (wvs[w] > bv || (wvs[w] == bv && wis[w] < bi)) { bv = wvs[w]; bi = wis[w]; }
          vals[bi] = -INFINITY;
          flag[bi] = 1;
        }
        __syncthreads();
      }
      sel[bh * 512 + tid] = flag[tid];
      sel[bh * 512 + tid + 256] = flag[tid + 256];
    }
    return;
  }
  // ========================= attention proper ==============================
  const int wave = tid >> 6, lane = tid & 63;
  const int l16 = lane & 15, quad = lane >> 4;
  const int bx = bxAll - 1080;
  const int xcd = bx & 7, sub = bx >> 3;
  const int qt = sub & 7, qr = (sub >> 3) & 3, grp = sub >> 5;
  const int bh = xcd + 8 * grp;
  const int b = bh >> 4, h = bh & 15;
  const int tbase = qt * 64 + wave * 16;
  const int sbase = qr * 512;

  const float* qrow = Qf + (size_t)(b * LDEC + tbase + l16) * DMODEL + h * HD + quad * 8;
  bf16x8 qa0, qa1;
  {
    float4 a0 = *(const float4*)qrow, a1 = *(const float4*)(qrow + 4);
    float4 a2 = *(const float4*)(qrow + 32), a3 = *(const float4*)(qrow + 36);
    qa0[0] = f2bf(a0.x * SCALE); qa0[1] = f2bf(a0.y * SCALE);
    qa0[2] = f2bf(a0.z * SCALE); qa0[3] = f2bf(a0.w * SCALE);
    qa0[4] = f2bf(a1.x * SCALE); qa0[5] = f2bf(a1.y * SCALE);
    qa0[6] = f2bf(a1.z * SCALE); qa0[7] = f2bf(a1.w * SCALE);
    qa1[0] = f2bf(a2.x * SCALE); qa1[1] = f2bf(a2.y * SCALE);
    qa1[2] = f2bf(a2.z * SCALE); qa1[3] = f2bf(a2.w * SCALE);
    qa1[4] = f2bf(a3.x * SCALE); qa1[5] = f2bf(a3.y * SCALE);
    qa1[6] = f2bf(a3.z * SCALE); qa1[7] = f2bf(a3.w * SCALE);
  }

  // ones B-fragment: row-sum of P via MFMA (D col all equal)
  bf16x8 bone;
#pragma unroll
  for (int j = 0; j < 8; ++j) bone[j] = (short)0x3f80;

  int tA = tbase + l16;
  int cA = min(4 * tA, LENC - 1);
  int loA = max(cA - 256, 0), hiA = min(cA + 256, LENC - 1);
  const int loW = max(4 * tbase - 256, 0);
  const int hiW = min(4 * (tbase + 15) + 256, LENC - 1);
  const bool blockAny = (sbase <= hiW) && (sbase + 511 >= loW);

  f32x4 Os[4], Ol[4], Ssum, Slsum;
#pragma unroll
  for (int n = 0; n < 4; ++n) {
    Os[n] = (f32x4){0.f, 0.f, 0.f, 0.f};
    Ol[n] = (f32x4){0.f, 0.f, 0.f, 0.f};
  }
  Ssum = (f32x4){0.f, 0.f, 0.f, 0.f};
  Slsum = (f32x4){0.f, 0.f, 0.f, 0.f};

  const int c0 = tid, c1 = tid + 256;
  const unsigned short* kg0 = Kb + (size_t)(b * LENC + sbase + (c0 >> 3)) * DMODEL + h * HD + (c0 & 7) * 8;
  const unsigned short* kg1 = Kb + (size_t)(b * LENC + sbase + (c1 >> 3)) * DMODEL + h * HD + (c1 & 7) * 8;
  const unsigned short* vg0 = Vt + (size_t)(bh * 64 + (c0 >> 3)) * LENC + sbase + (c0 & 7) * 8;
  const unsigned short* vg1 = Vt + (size_t)(bh * 64 + (c1 >> 3)) * LENC + sbase + (c1 & 7) * 8;
  const int of0 = sws(c0 >> 3, (c0 & 7) * 8);
  const int of1 = sws(c1 >> 3, (c1 & 7) * 8);

  uint4 pk0, pk1, pv0, pv1;
  pk0 = *(const uint4*)kg0; pk1 = *(const uint4*)kg1;
  pv0 = *(const uint4*)vg0; pv1 = *(const uint4*)vg1;
  *(uint4*)&Ks[0][of0] = pk0; *(uint4*)&Ks[0][of1] = pk1;
  *(uint4*)&Vs[0][of0] = pv0; *(uint4*)&Vs[0][of1] = pv1;
  __syncthreads();

  for (int it = 0; it < 8; ++it) {
    const int cur = it & 1;
    const int s0 = sbase + it * 64;
    const bool anyL = (s0 <= hiW) && (s0 + 63 >= loW);
    if (it < 7) {
      pk0 = *(const uint4*)(kg0 + (size_t)(it + 1) * 64 * DMODEL);
      pk1 = *(const uint4*)(kg1 + (size_t)(it + 1) * 64 * DMODEL);
      pv0 = *(const uint4*)(vg0 + (it + 1) * 64);
      pv1 = *(const uint4*)(vg1 + (it + 1) * 64);
    }
    const unsigned short* K_ = Ks[cur];
    const unsigned short* V_ = Vs[cur];

    f32x4 S[4];
#pragma unroll
    for (int n = 0; n < 4; ++n) {
      bf16x8 bk0 = *(const bf16x8*)&K_[sws(n * 16 + l16, quad * 8)];
      bf16x8 bk1 = *(const bf16x8*)&K_[sws(n * 16 + l16, 32 + quad * 8)];
      f32x4 z = (f32x4){0.f, 0.f, 0.f, 0.f};
      z = __builtin_amdgcn_mfma_f32_16x16x32_bf16(qa0, bk0, z, 0, 0, 0);
      S[n] = __builtin_amdgcn_mfma_f32_16x16x32_bf16(qa1, bk1, z, 0, 0, 0);
    }

    unsigned short* Pw = Ps[wave];
#pragma unroll
    for (int n = 0; n < 4; ++n)
#pragma unroll
      for (int r = 0; r < 4; ++r)
        Pw[sws(quad * 4 + r, n * 16 + l16)] = f2bf(__expf(S[n][r]));
    bf16x8 aP0 = *(const bf16x8*)&Pw[sws(l16, quad * 8)];
    bf16x8 aP1 = *(const bf16x8*)&Pw[sws(l16, 32 + quad * 8)];
    // row sums (softmax denominators) via ones-column MFMA
    Ssum = __builtin_amdgcn_mfma_f32_16x16x32_bf16(aP0, bone, Ssum, 0, 0, 0);
    Ssum = __builtin_amdgcn_mfma_f32_16x16x32_bf16(aP1, bone, Ssum, 0, 0, 0);
#pragma unroll
    for (int n = 0; n < 4; ++n) {
      bf16x8 bv0 = *(const bf16x8*)&V_[sws(n * 16 + l16, quad * 8)];
      bf16x8 bv1 = *(const bf16x8*)&V_[sws(n * 16 + l16, 32 + quad * 8)];
      Os[n] = __builtin_amdgcn_mfma_f32_16x16x32_bf16(aP0, bv0, Os[n], 0, 0, 0);
      Os[n] = __builtin_amdgcn_mfma_f32_16x16x32_bf16(aP1, bv1, Os[n], 0, 0, 0);
    }
    if (anyL) {
      bf16x8 aL0 = aP0, aL1 = aP1;
#pragma unroll
      for (int j = 0; j < 8; ++j) {
        int sc = s0 + quad * 8 + j;
        if (sc < loA || sc > hiA) aL0[j] = 0;
        if (sc + 32 < loA || sc + 32 > hiA) aL1[j] = 0;
      }
      Slsum = __builtin_amdgcn_mfma_f32_16x16x32_bf16(aL0, bone, Slsum, 0, 0, 0);
      Slsum = __builtin_amdgcn_mfma_f32_16x16x32_bf16(aL1, bone, Slsum, 0, 0, 0);
#pragma unroll
      for (int n = 0; n < 4; ++n) {
        bf16x8 bv0 = *(const bf16x8*)&V_[sws(n * 16 + l16, quad * 8)];
        bf16x8 bv1 = *(const bf16x8*)&V_[sws(n * 16 + l16, 32 + quad * 8)];
        Ol[n] = __builtin_amdgcn_mfma_f32_16x16x32_bf16(aL0, bv0, Ol[n], 0, 0, 0);
        Ol[n] = __builtin_amdgcn_mfma_f32_16x16x32_bf16(aL1, bv1, Ol[n], 0, 0, 0);
      }
    }
    // single barrier per iteration: all reads of buffer (1-cur) completed
    // before the previous iteration's barrier, so writing it now is safe.
    if (it < 7) {
      unsigned short* KL = Ks[1 - cur];
      unsigned short* VL = Vs[1 - cur];
      *(uint4*)&KL[of0] = pk0; *(uint4*)&KL[of1] = pk1;
      *(uint4*)&VL[of0] = pv0; *(uint4*)&VL[of1] = pv1;
    }
    __syncthreads();
  }

  float* osp = qr == 0 ? OsP0 : (qr == 1 ? OsP1 : (qr == 2 ? OsP2 : OsP3));
  float* olp = (qr & 1) ? OlS1 : OlS0;
  float* sp = st + qr * 32768;
#pragma unroll
  for (int r = 0; r < 4; ++r) {
    int t = tbase + quad * 4 + r;
#pragma unroll
    for (int n = 0; n < 4; ++n) {
      size_t o = (size_t)(b * LDEC + t) * DMODEL + h * HD + n * 16 + l16;
      osp[o] = Os[n][r];
      if (blockAny) olp[o] = Ol[n][r];
    }
    if (l16 == 0) {
      int sr = bh * 512 + t;
      sp[sr] = Ssum[r];
      sp[16384 + sr] = Slsum[r];
    }
  }
}

// fused: split-K-4 combine + probsparse fill + lin/cos apply.
// Emits bf16 DIRECTLY into b16 (the gemm_one input).
// grid: [0,1024) combine | [1024,5120) lin_cos.
__global__ __launch_bounds__(256) void combine_fill(
    const float* __restrict__ P0, const float* __restrict__ P1,
    const float* __restrict__ P2, const float* __restrict__ P3,
    const float* __restrict__ L0, const float* __restrict__ L1,
    const float* __restrict__ st,
    const float* __restrict__ vmean, const int* __restrict__ sel,
    const float* __restrict__ Q, const float* __restrict__ kvL,
    const float* __restrict__ kvC, const float* __restrict__ ksL,
    const float* __restrict__ ksC,
    unsigned short* __restrict__ b16) {
  __shared__ float sh[2][4][64];
  int bx0 = blockIdx.x;
  int tid = threadIdx.x;
  if (bx0 < 1024) {
    int i4 = bx0 * 256 + tid;
    int i = i4 * 4;
    int col = i & 1023, bt = i >> 10;
    int t = bt & 511, b = bt >> 9, h = col >> 6, d = col & 63;
    int bh = b * 16 + h;
    int sr = bh * 512 + t;
    float iS = 1.f / (st[sr] + st[32768 + sr] + st[65536 + sr] + st[98304 + sr]);
    float iL = 1.f / (st[16384 + sr] + st[49152 + sr] + st[81920 + sr] + st[114688 + sr]);
    float4 s0 = *(const float4*)(P0 + i);
    float4 s1 = *(const float4*)(P1 + i);
    float4 s2 = *(const float4*)(P2 + i);
    float4 s3 = *(const float4*)(P3 + i);
    // local-branch: row t's window touches quarters q0..q1 (q1-q0 <= 1);
    // quarter q wrote parity slot q&1 (slot0 = L0, slot1 = L1).
    int c = min(4 * t, LENC - 1);
    int lo = max(c - 256, 0), hi = min(c + 256, LENC - 1);
    int q0 = lo >> 9, q1 = hi >> 9;
    const float* Lp0 = (q0 & 1) ? L1 : L0;
    float4 l = *(const float4*)(Lp0 + i);
    if (q1 != q0) {
      const float* Lp1 = (q1 & 1) ? L1 : L0;
      float4 l2 = *(const float4*)(Lp1 + i);
      l.x += l2.x; l.y += l2.y; l.z += l2.z; l.w += l2.w;
    }
    float4 os = make_float4((s0.x + s1.x + s2.x + s3.x) * iS,
                            (s0.y + s1.y + s2.y + s3.y) * iS,
                            (s0.z + s1.z + s2.z + s3.z) * iS,
                            (s0.w + s1.w + s2.w + s3.w) * iS);
    float4 ol = make_float4(l.x * iL, l.y * iL, l.z * iL, l.w * iL);
    float4 pp = sel[sr] ? os : *(const float4*)(vmean + bh * 64 + d);
    uint2 o2;
    o2.x = (unsigned)f2bf(os.x) | ((unsigned)f2bf(os.y) << 16);
    o2.y = (unsigned)f2bf(os.z) | ((unsigned)f2bf(os.w) << 16);
    *(uint2*)(b16 + i) = o2;
    o2.x = (unsigned)f2bf(pp.x) | ((unsigned)f2bf(pp.y) << 16);
    o2.y = (unsigned)f2bf(pp.z) | ((unsigned)f2bf(pp.w) << 16);
    *(uint2*)(b16 + 2097152 + i) = o2;
    o2.x = (unsigned)f2bf(ol.x) | ((unsigned)f2bf(ol.y) << 16);
    o2.y = (unsigned)f2bf(ol.z) | ((unsigned)f2bf(ol.w) << 16);
    *(uint2*)(b16 + 4194304 + i) = o2;
  } else {
    // ---- lin_cos_apply (bf16 direct out) ----
    int lane = tid & 63, g = tid >> 6;
    int row = (bx0 - 1024) * 4 + g;
    int bh = row >> 9, t = row & 511;
    int b = bh >> 4, h = bh & 15;
    float qv = Q[(b * LDEC + t) * DMODEL + h * HD + lane];
    float x = qv * SCALE;
    float qfl = x > 0.f ? x + 1.f : __expf(x);
    float qnorm = sqrtf(wave_sum(qv * qv));
    float qn = qv / fmaxf(qnorm, 1e-12f);
    float qfc = fmaxf(qn, 0.f) + 1e-6f;
    sh[0][g][lane] = qfl;
    sh[1][g][lane] = qfc;
    float denL = fmaxf(wave_sum(qfl * ksL[bh * 64 + lane]), 1e-6f);
    float denC = fmaxf(wave_sum(qfc * ksC[bh * 64 + lane]), 1e-6f);
    const float* kvLb = kvL + bh * 4096;
    const float* kvCb = kvC + bh * 4096;
    float aL = 0.f, aC = 0.f;
#pragma unroll
    for (int d = 0; d < 64; ++d) {
      aL = fmaf(sh[0][g][d], kvLb[d * 64 + lane], aL);
      aC = fmaf(sh[1][g][d], kvCb[d * 64 + lane], aC);
    }
    int o = (b * LDEC + t) * DMODEL + h * HD + lane;
    b16[1048576 + o] = f2bf(aL / denL);
    b16[3145728 + o] = f2bf(aC / denC);
  }
}

// ---------------- final combine
__global__ __launch_bounds__(256) void combine(
    const float* __restrict__ dec, const float* __restrict__ proj,
    const float* __restrict__ rmsw, const float* __restrict__ alphas,
    float* __restrict__ out) {
  __shared__ float red[4];
  int row = blockIdx.x;
  int tid = threadIdx.x, lane = tid & 63, g = tid >> 6;
  int base = row * DMODEL + tid * 4;
  float4 dv = *(const float4*)(dec + base);
  float4 wv = *(const float4*)(rmsw + tid * 4);
  float a[6];
  float amax = -INFINITY;
#pragma unroll
  for (int i = 0; i < 6; ++i) { a[i] = alphas[i]; amax = fmaxf(amax, a[i]); }
  float asum = 0.f;
#pragma unroll
  for (int i = 0; i < 6; ++i) { a[i] = __expf(a[i] - amax); asum += a[i]; }
#pragma unroll
  for (int i = 0; i < 6; ++i) a[i] /= asum;
  float4 acc = make_float4(a[0] * dv.x, a[0] * dv.y, a[0] * dv.z, a[0] * dv.w);
  for (int br = 0; br < 5; ++br) {
    float4 pv = *(const float4*)(proj + br * 1048576 + base);
    float4 xx = make_float4(dv.x + pv.x, dv.y + pv.y, dv.z + pv.z, dv.w + pv.w);
    float ssq = xx.x * xx.x + xx.y * xx.y + xx.z * xx.z + xx.w * xx.w;
    float wsum = wave_sum(ssq);
    if (lane == 0) red[g] = wsum;
    __syncthreads();
    float tot = red[0] + red[1] + red[2] + red[3];
    float rr = rsqrtf(tot / 1024.f + 1e-6f);
    float wb = a[br + 1];
    acc.x += wb * xx.x * rr * wv.x;
    acc.y += wb * xx.y * rr * wv.y;
    acc.z += wb * xx.z * rr * wv.z;
    acc.w += wb * xx.w * rr * wv.w;
    __syncthreads();
  }
  *(float4*)(out + base) = acc;
}

extern "C" void kernel_launch(void* const* d_in, const int* in_sizes, int n_in,
                              void* d_out, int out_size, void* d_ws, size_t ws_size,
                              hipStream_t stream) {
  const float* dec = (const float*)d_in[0];
  const float* enc = (const float*)d_in[1];
  const float* Wq = (const float*)d_in[2];
  const float* Wk = (const float*)d_in[3];
  const float* Wv = (const float*)d_in[4];
  const float* Wo = (const float*)d_in[5];
  const float* rmsw = (const float*)d_in[6];
  const float* alphas = (const float*)d_in[7];
  const int* sidx = (const int*)d_in[8];

  const size_t M = 1048576;
  float* ws = (float*)d_ws;
  float* Q    = ws;                                  // [0,1M)
  unsigned short* Kb16 = (unsigned short*)(ws + M);  // [1M,3M)
  float* KsPart = ws + 3 * M;                        // [3M,+311296)
  float* V    = ws + 5 * M;                          // [5M,9M)
  float* Vtb_f= ws + 9 * M;                          // [9M,11M)
  unsigned short* Wqh = (unsigned short*)(ws + 9 * M);
  unsigned short* Wql = (unsigned short*)(ws + 9 * M + M / 2);
  unsigned short* Wkh = (unsigned short*)(ws + 10 * M);
  unsigned short* Wvh = (unsigned short*)(ws + 10 * M + M / 2);
  unsigned short* eh  = (unsigned short*)(ws + 11 * M);
  unsigned short* dh  = (unsigned short*)(ws + 15 * M);
  unsigned short* dl  = (unsigned short*)(ws + 15 * M + M / 2);
  unsigned short* Vtb = (unsigned short*)Vtb_f;
  float* kvpL = ws + 11 * M;
  float* kvpC = ws + 13 * M;
  float* kspL = ws + 15 * M;
  float* kspC = ws + 15 * M + 32768;
  float* vsp  = ws + 15 * M + 65536;
  float* tail = ws + 16 * M;
  float* kvL  = tail;
  float* kvC  = tail + 131072;
  float* ksL  = tail + 262144;
  float* ksC  = tail + 264192;
  float* vmean= tail + 266240;
  float* Mbuf = tail + 317440;
  int*   sel  = (int*)(tail + 333824);
  // bf16 GEMM inputs: braw16 written by combine_fill; Woh by prologue.
  unsigned short* braw16 = (unsigned short*)(ws + 12 * M);
  unsigned short* Woh = (unsigned short*)(ws + 17 * M);
  // attn split-K-4 partials: VIRGIN regions (>=18M) so the fused
  // attn+tail2 kernel has zero aliasing between its two slices.
  float* P0   = ws + 18 * M;
  float* OsP1 = ws + 19 * M;
  float* OsP2 = ws + 20 * M;
  float* OsP3 = ws + 21 * M;
  float* OlS0 = ws + 22 * M;
  float* OlS1 = ws + 23 * M;
  float* stats = ws + 24 * M;  // 4*32768 floats
  float* proj = ws + 3 * M + M / 2;

  hipLaunchKernelGGL(prologue, dim3(7360), dim3(256), 17408, stream,
                     dec, enc, Wq, Wk, Wv, sidx, dh, dl, eh, Wqh, Wql, Wkh, Wvh,
                     KsPart, Wo, Woh);
  hipLaunchKernelGGL(gemm_qkv, dim3(72, 8), dim3(512), 81920, stream,
                     dh, dl, Wqh, Wql, Q, eh, Wkh, Kb16, Wvh, V);
  hipLaunchKernelGGL(trio, dim3(1664), dim3(256), 34816, stream,
                     V, Vtb, Kb16, kvpL, kvpC, kspL, kspC, vsp, Q, KsPart, Mbuf);
  hipLaunchKernelGGL(attn_mfma, dim3(2104), dim3(256), 0, stream, Q, Kb16, Vtb,
                     P0, OsP1, OsP2, OsP3, OlS0, OlS1, stats,
                     kvpL, kvpC, kspL, kspC, vsp, kvL, kvC, ksL, ksC, vmean,
                     Mbuf, sel);
  hipLaunchKernelGGL(combine_fill, dim3(5120), dim3(256), 0, stream,
                     P0, OsP1, OsP2, OsP3, OlS0, OlS1, stats, vmean, sel,
                     Q, kvL, kvC, ksL, ksC, braw16);
  hipLaunchKernelGGL(gemm_one, dim3(40, 8), dim3(512), 65536, stream, braw16, Woh, proj);
  hipLaunchKernelGGL(combine, dim3(1024), dim3(256), 0, stream, dec, proj, rmsw, alphas,
                     (float*)d_out);
}

// Round 12
// 239.660 us; speedup vs baseline: 1.2657x; 1.0426x over previous
//
#include <hip/hip_runtime.h>
#include <math.h>

#define LDEC 512
#define LENC 2048
#define DMODEL 1024
#define NH 16
#define HD 64
#define SCALE 0.125f
#define NTOP 31
#define NSAMP 38

typedef __attribute__((ext_vector_type(8))) short bf16x8;
typedef __attribute__((ext_vector_type(4))) float f32x4;

__device__ inline float wave_sum(float v) {
#pragma unroll
  for (int m = 32; m > 0; m >>= 1) v += __shfl_xor(v, m);
  return v;
}

__device__ inline unsigned short f2bf(float x) {
  unsigned u = __float_as_uint(x);
  u += 0x7fff + ((u >> 16) & 1);  // RNE
  return (unsigned short)(u >> 16);
}
__device__ inline float bf2f(unsigned short h) {
  return __uint_as_float(((unsigned)h) << 16);
}

// async HBM -> LDS, 16 B per lane; lds base must be wave-uniform
__device__ __forceinline__ void gld16(const unsigned short* g, unsigned short* l) {
  __builtin_amdgcn_global_load_lds(
      (const __attribute__((address_space(1))) unsigned int*)g,
      (__attribute__((address_space(3))) unsigned int*)l, 16, 0, 0);
}

// XOR-swizzled LDS index (row stride 64 shorts = 128 B): kills the
// stride-128B bank-conflict pattern; col must stay within [0,64).
__device__ __forceinline__ int sws(int row, int col) {
  return row * 64 + (col ^ ((row & 7) << 3));
}

// ====== FUSED PROLOGUE: cvt_in + cvt_w3 + k_samp + cvt_w(Wo) ================
// grid: [0,5120) cvt_in | [5120,5888) cvt_w3 | [5888,7104) k_samp split-K |
// [7104,7360) Wo cvt. dyn LDS 17408.
__global__ __launch_bounds__(256) void prologue(
    const float* __restrict__ dec, const float* __restrict__ enc,
    const float* __restrict__ Wq, const float* __restrict__ Wk,
    const float* __restrict__ Wv, const int* __restrict__ sidx,
    unsigned short* __restrict__ dh, unsigned short* __restrict__ dl,
    unsigned short* __restrict__ eh,
    unsigned short* __restrict__ Wqh, unsigned short* __restrict__ Wql,
    unsigned short* __restrict__ Wkh, unsigned short* __restrict__ Wvh,
    float* __restrict__ KsPart,
    const float* __restrict__ Wo, unsigned short* __restrict__ Woh) {
  extern __shared__ char smraw[];
  int bx = blockIdx.x;
  int tid = threadIdx.x;
  if (bx < 5120) {
    // ---- cvt_in ----
    int i = bx * 256 + tid;
    if (i < 262144) {
      float4 v = ((const float4*)dec)[i];
      ushort4 h = make_ushort4(f2bf(v.x), f2bf(v.y), f2bf(v.z), f2bf(v.w));
      ushort4 l = make_ushort4(f2bf(v.x - bf2f(h.x)), f2bf(v.y - bf2f(h.y)),
                               f2bf(v.z - bf2f(h.z)), f2bf(v.w - bf2f(h.w)));
      *(ushort4*)(dh + i * 4) = h;
      *(ushort4*)(dl + i * 4) = l;
    } else {
      int j = i - 262144;
      float4 v = ((const float4*)enc)[j];
      *(ushort4*)(eh + j * 4) =
          make_ushort4(f2bf(v.x), f2bf(v.y), f2bf(v.z), f2bf(v.w));
    }
  } else if (bx < 5888) {
    // ---- cvt_w3 ----
    float (*t)[68] = (float(*)[68])smraw;
    int wb = bx - 5120;
    int which = wb >> 8, rem = wb & 255;
    const float* W = which == 0 ? Wq : (which == 1 ? Wk : Wv);
    unsigned short* Th = which == 0 ? Wqh : (which == 1 ? Wkh : Wvh);
    unsigned short* Tl = which == 0 ? Wql : nullptr;
    int k0 = (rem >> 4) * 64, n0 = (rem & 15) * 64;
#pragma unroll
    for (int i = 0; i < 4; ++i) {
      int c = tid + 256 * i;
      int r = c >> 4, c4 = (c & 15) * 4;
      float4 v = *(const float4*)(W + (size_t)(k0 + r) * DMODEL + n0 + c4);
      t[c4 + 0][r] = v.x; t[c4 + 1][r] = v.y; t[c4 + 2][r] = v.z; t[c4 + 3][r] = v.w;
    }
    __syncthreads();
#pragma unroll
    for (int i = 0; i < 4; ++i) {
      int c = tid + 256 * i;
      int n = c >> 4, k4 = (c & 15) * 4;
      float4 v = *(const float4*)&t[n][k4];
      ushort4 h = make_ushort4(f2bf(v.x), f2bf(v.y), f2bf(v.z), f2bf(v.w));
      *(ushort4*)(Th + (size_t)(n0 + n) * DMODEL + k0 + k4) = h;
      if (Tl) {
        ushort4 l = make_ushort4(f2bf(v.x - bf2f(h.x)), f2bf(v.y - bf2f(h.y)),
                                 f2bf(v.z - bf2f(h.z)), f2bf(v.w - bf2f(h.w)));
        *(ushort4*)(Tl + (size_t)(n0 + n) * DMODEL + k0 + k4) = l;
      }
    }
  } else if (bx < 7104) {
    // ---- k_samp split-K (fp32; 38s x 4 col-chunks x 8 k-chunks) ----
    float* er = (float*)smraw;  // 128 floats
    int sb = bx - 5888;         // 0..1215
    int s = sb >> 5;            // 0..37
    int rem = sb & 31;
    int cchunk = rem >> 3, kc = rem & 7;
    int c = cchunk * 256 + tid;
    int srow = sidx[s];
    if (tid < 32) {
      int idx = tid * 4;
      *(float4*)&er[idx] =
          *(const float4*)(enc + (size_t)srow * DMODEL + kc * 128 + idx);
    }
    __syncthreads();
    float acc = 0.f;
    const float* wp = Wk + (size_t)(kc * 128) * DMODEL + c;
    for (int k0 = 0; k0 < 128; k0 += 16) {
      float w[16];
#pragma unroll
      for (int j = 0; j < 16; ++j) w[j] = wp[(size_t)(k0 + j) * DMODEL];
#pragma unroll
      for (int j = 0; j < 16; ++j) acc = fmaf(er[k0 + j], w[j], acc);
    }
    KsPart[(size_t)kc * (NSAMP * 1024) + s * 1024 + c] = acc;
  } else {
    // ---- cvt_w (Wo transpose -> bf16) ----
    float (*tl)[68] = (float(*)[68])smraw;
    int wb = bx - 7104;
    int k0 = (wb >> 4) * 64, n0 = (wb & 15) * 64;
#pragma unroll
    for (int i = 0; i < 4; ++i) {
      int c = tid + 256 * i;
      int r = c >> 4, c4 = (c & 15) * 4;
      float4 v = *(const float4*)(Wo + (size_t)(k0 + r) * DMODEL + n0 + c4);
      tl[c4 + 0][r] = v.x; tl[c4 + 1][r] = v.y; tl[c4 + 2][r] = v.z; tl[c4 + 3][r] = v.w;
    }
    __syncthreads();
#pragma unroll
    for (int i = 0; i < 4; ++i) {
      int c = tid + 256 * i;
      int n = c >> 4, k4 = (c & 15) * 4;
      float4 v = *(const float4*)&tl[n][k4];
      *(ushort4*)(Woh + (size_t)(n0 + n) * DMODEL + k0 + k4) =
          make_ushort4(f2bf(v.x), f2bf(v.y), f2bf(v.z), f2bf(v.w));
    }
  }
}

// ======= shared epilogue: 64x32 wave tile via LDS transpose (stride 36) ====
// VTOUT: additionally emit transposed bf16 into Vt[(bh*64+d)*LENC + s]
// (replaces the old cvt_vt kernel; same f2bf of the same f32 acc -> bit-exact).
template <int BF16OUT, int VTOUT>
__device__ __forceinline__ void gemm_epilogue(
    unsigned short* sm, f32x4 (&acc)[4][2], float* __restrict__ C,
    unsigned short* __restrict__ Cb, int row0, int col0, int wave, int lane,
    unsigned short* __restrict__ Vt) {
  const int l16 = lane & 15, quad = lane >> 4;
  float* eL = (float*)sm + wave * 576;
  const int rr = lane >> 2, cc = (lane & 3) * 8;
  const int wr = wave >> 2, wc = wave & 3;
#pragma unroll
  for (int x = 0; x < 4; ++x) {
#pragma unroll
    for (int y = 0; y < 2; ++y)
#pragma unroll
      for (int q = 0; q < 4; ++q)
        eL[(quad * 4 + q) * 36 + y * 16 + l16] = acc[x][y][q];
    float4 v0 = *(const float4*)&eL[rr * 36 + cc];
    float4 v1 = *(const float4*)&eL[rr * 36 + cc + 4];
    size_t ro = (size_t)(row0 + wr * 64 + x * 16 + rr) * DMODEL + col0 + wc * 32 + cc;
    if (BF16OUT) {
      uint2 o;
      o.x = (unsigned)f2bf(v0.x) | ((unsigned)f2bf(v0.y) << 16);
      o.y = (unsigned)f2bf(v0.z) | ((unsigned)f2bf(v0.w) << 16);
      *(uint2*)(Cb + ro) = o;
      o.x = (unsigned)f2bf(v1.x) | ((unsigned)f2bf(v1.y) << 16);
      o.y = (unsigned)f2bf(v1.z) | ((unsigned)f2bf(v1.w) << 16);
      *(uint2*)(Cb + ro + 4) = o;
    } else {
      *(float4*)(C + ro) = v0;
      *(float4*)(C + ro + 4) = v1;
    }
    if (VTOUT) {
      // transposed bf16 out: lane -> (d = lane>>1 within wave's 32 cols,
      // 8 s-values at (lane&1)*8). Row index here is enc position.
      int dl = lane >> 1;
      int sh8 = (lane & 1) * 8;
      int col = col0 + wc * 32 + dl;
      int b = row0 >> 11;                       // LENC = 2048
      int sabs = (row0 & 2047) + wr * 64 + x * 16 + sh8;
      int bh = b * 16 + (col >> 6);
      int d = col & 63;
      uint4 o;
      unsigned w0, w1;
      w0 = (unsigned)f2bf(eL[(sh8 + 0) * 36 + dl]);
      w1 = (unsigned)f2bf(eL[(sh8 + 1) * 36 + dl]);
      o.x = w0 | (w1 << 16);
      w0 = (unsigned)f2bf(eL[(sh8 + 2) * 36 + dl]);
      w1 = (unsigned)f2bf(eL[(sh8 + 3) * 36 + dl]);
      o.y = w0 | (w1 << 16);
      w0 = (unsigned)f2bf(eL[(sh8 + 4) * 36 + dl]);
      w1 = (unsigned)f2bf(eL[(sh8 + 5) * 36 + dl]);
      o.z = w0 | (w1 << 16);
      w0 = (unsigned)f2bf(eL[(sh8 + 6) * 36 + dl]);
      w1 = (unsigned)f2bf(eL[(sh8 + 7) * 36 + dl]);
      o.w = w0 | (w1 << 16);
      *(uint4*)(Vt + (size_t)(bh * 64 + d) * LENC + sabs) = o;
    }
  }
}

// ======= 1-pass bf16 GEMM, 512 thr, wave-tile 64x32, ASYNC global->LDS ====
// BK=64, full sws XOR swizzle (attn-proven, 0 conflicts).
template <int BF16OUT, int VTOUT>
__device__ __forceinline__ void gemm512_1p_async(
    const unsigned short* __restrict__ Ah, const unsigned short* __restrict__ Bh,
    float* __restrict__ C, unsigned short* __restrict__ Cb, int row0, int col0,
    unsigned short* __restrict__ Vt) {
  extern __shared__ unsigned short sm[];
  const int BUFS = 16384;  // shorts per buffer (A 8192 | B 8192)
  const int tid = threadIdx.x, lane = tid & 63, wave = tid >> 6;
  const int l16 = lane & 15, quad = lane >> 4;
  const int wr = wave >> 2, wc = wave & 3;

  const int srow = wave * 16 + (lane >> 3);
  const int scol = ((lane & 7) ^ (lane >> 3)) * 8;
  const unsigned short* gA = Ah + (size_t)(row0 + srow) * DMODEL + scol;
  const unsigned short* gB = Bh + (size_t)(col0 + srow) * DMODEL + scol;
  const int wofs = wave * 1024;

  f32x4 acc[4][2];
#pragma unroll
  for (int x = 0; x < 4; ++x)
#pragma unroll
    for (int y = 0; y < 2; ++y) acc[x][y] = (f32x4){0.f, 0.f, 0.f, 0.f};

  gld16(gA, sm + wofs);
  gld16(gA + (size_t)8 * DMODEL, sm + wofs + 512);
  gld16(gB, sm + 8192 + wofs);
  gld16(gB + (size_t)8 * DMODEL, sm + 8192 + wofs + 512);
  __syncthreads();

  for (int it = 0; it < 16; ++it) {
    const unsigned short* cur = sm + (it & 1) * BUFS;
    if (it < 15) {
      int ko = (it + 1) * 64;
      unsigned short* nxt = sm + ((it + 1) & 1) * BUFS;
      gld16(gA + ko, nxt + wofs);
      gld16(gA + (size_t)8 * DMODEL + ko, nxt + wofs + 512);
      gld16(gB + ko, nxt + 8192 + wofs);
      gld16(gB + (size_t)8 * DMODEL + ko, nxt + 8192 + wofs + 512);
    }
    bf16x8 a[2][4], b[2][2];
#pragma unroll
    for (int ks = 0; ks < 2; ++ks) {
#pragma unroll
      for (int x = 0; x < 4; ++x)
        a[ks][x] = *(const bf16x8*)&cur[sws(wr * 64 + x * 16 + l16, ks * 32 + quad * 8)];
#pragma unroll
      for (int y = 0; y < 2; ++y)
        b[ks][y] = *(const bf16x8*)&cur[8192 + sws(wc * 32 + y * 16 + l16, ks * 32 + quad * 8)];
    }
#pragma unroll
    for (int ks = 0; ks < 2; ++ks)
#pragma unroll
      for (int x = 0; x < 4; ++x)
#pragma unroll
        for (int y = 0; y < 2; ++y)
          acc[x][y] = __builtin_amdgcn_mfma_f32_16x16x32_bf16(a[ks][x], b[ks][y], acc[x][y], 0, 0, 0);
    __syncthreads();
  }
  gemm_epilogue<BF16OUT, VTOUT>(sm, acc, C, Cb, row0, col0, wave, lane, Vt);
}

// ======= 3-pass hi/lo GEMM, 512 thr, padded dbuf (unchanged from best) =====
__device__ __forceinline__ void gemm512_3p(
    const unsigned short* __restrict__ Ah, const unsigned short* __restrict__ Al,
    const unsigned short* __restrict__ Bh, const unsigned short* __restrict__ Bl,
    float* __restrict__ C, int row0, int col0) {
  extern __shared__ unsigned short sm[];
  const int BUFS = 20480;
  const int tid = threadIdx.x, lane = tid & 63, wave = tid >> 6;
  const int l16 = lane & 15, quad = lane >> 4;
  const int wr = wave >> 2, wc = wave & 3;

  const int r = tid >> 2, kc = tid & 3;
  const unsigned short* gAh = Ah + (size_t)(row0 + r) * DMODEL + kc * 8;
  const unsigned short* gBh = Bh + (size_t)(col0 + r) * DMODEL + kc * 8;
  const unsigned short* gAl = Al + (size_t)(row0 + r) * DMODEL + kc * 8;
  const unsigned short* gBl = Bl + (size_t)(col0 + r) * DMODEL + kc * 8;
  const int lofs = r * 40 + kc * 8;

  f32x4 acc[4][2];
#pragma unroll
  for (int x = 0; x < 4; ++x)
#pragma unroll
    for (int y = 0; y < 2; ++y) acc[x][y] = (f32x4){0.f, 0.f, 0.f, 0.f};

  uint4 pah = *(const uint4*)gAh, pbh = *(const uint4*)gBh;
  uint4 pal = *(const uint4*)gAl, pbl = *(const uint4*)gBl;
  *(uint4*)&sm[lofs] = pah;
  *(uint4*)&sm[5120 + lofs] = pbh;
  *(uint4*)&sm[10240 + lofs] = pal;
  *(uint4*)&sm[15360 + lofs] = pbl;
  pah = *(const uint4*)(gAh + 32);
  pbh = *(const uint4*)(gBh + 32);
  pal = *(const uint4*)(gAl + 32);
  pbl = *(const uint4*)(gBl + 32);
  __syncthreads();

  for (int it = 0; it < 32; ++it) {
    const unsigned short* cur = sm + (it & 1) * BUFS;
    bf16x8 ah[4], bh[2], al[4], bl[2];
#pragma unroll
    for (int x = 0; x < 4; ++x) {
      ah[x] = *(const bf16x8*)&cur[(wr * 64 + x * 16 + l16) * 40 + quad * 8];
      al[x] = *(const bf16x8*)&cur[10240 + (wr * 64 + x * 16 + l16) * 40 + quad * 8];
    }
#pragma unroll
    for (int y = 0; y < 2; ++y) {
      bh[y] = *(const bf16x8*)&cur[5120 + (wc * 32 + y * 16 + l16) * 40 + quad * 8];
      bl[y] = *(const bf16x8*)&cur[15360 + (wc * 32 + y * 16 + l16) * 40 + quad * 8];
    }
#pragma unroll
    for (int x = 0; x < 4; ++x)
#pragma unroll
      for (int y = 0; y < 2; ++y) {
        acc[x][y] = __builtin_amdgcn_mfma_f32_16x16x32_bf16(ah[x], bh[y], acc[x][y], 0, 0, 0);
        acc[x][y] = __builtin_amdgcn_mfma_f32_16x16x32_bf16(ah[x], bl[y], acc[x][y], 0, 0, 0);
        acc[x][y] = __builtin_amdgcn_mfma_f32_16x16x32_bf16(al[x], bh[y], acc[x][y], 0, 0, 0);
      }
    if (it < 31) {
      unsigned short* nxt = sm + ((it + 1) & 1) * BUFS;
      *(uint4*)&nxt[lofs] = pah;
      *(uint4*)&nxt[5120 + lofs] = pbh;
      *(uint4*)&nxt[10240 + lofs] = pal;
      *(uint4*)&nxt[15360 + lofs] = pbl;
      if (it < 30) {
        int ko = (it + 2) * 32;
        pah = *(const uint4*)(gAh + ko);
        pbh = *(const uint4*)(gBh + ko);
        pal = *(const uint4*)(gAl + ko);
        pbl = *(const uint4*)(gBl + ko);
      }
    }
    __syncthreads();
  }
  gemm_epilogue<0, 0>(sm, acc, C, nullptr, row0, col0, wave, lane, nullptr);
}

// merged Q(3-pass) + K(1-pass async, bf16-out) + V(1-pass async + Vt-out)
__global__ __launch_bounds__(512, 4) void gemm_qkv(
    const unsigned short* __restrict__ dh, const unsigned short* __restrict__ dl,
    const unsigned short* __restrict__ Wqh, const unsigned short* __restrict__ Wql,
    float* __restrict__ Q,
    const unsigned short* __restrict__ eh, const unsigned short* __restrict__ Wkh,
    unsigned short* __restrict__ Kb16,
    const unsigned short* __restrict__ Wvh, float* __restrict__ V,
    unsigned short* __restrict__ Vt) {
  int bx = blockIdx.x;
  if (bx < 8)
    gemm512_3p(dh, dl, Wqh, Wql, Q, bx * 128, blockIdx.y * 128);
  else if (bx < 40)
    gemm512_1p_async<1, 0>(eh, Wkh, nullptr, Kb16, (bx - 8) * 128, blockIdx.y * 128, nullptr);
  else
    gemm512_1p_async<0, 1>(eh, Wvh, V, nullptr, (bx - 40) * 128, blockIdx.y * 128, Vt);
}

__global__ __launch_bounds__(512, 4) void gemm_one(
    const unsigned short* __restrict__ Ah, const unsigned short* __restrict__ Bh,
    float* __restrict__ C) {
  gemm512_1p_async<0, 0>(Ah, Bh, C, nullptr, blockIdx.x * 128, blockIdx.y * 128, nullptr);
}

// ============ FUSED TRIO (cvt_vt removed): lin_cos_stats + pp_scores ========
// grid: [0,512) lin_cos_stats | [512,640) pp_scores. dyn LDS 34816 B.
__global__ __launch_bounds__(256, 4) void trio(
    const float* __restrict__ V,
    const unsigned short* __restrict__ Kb,
    float* __restrict__ kvpL, float* __restrict__ kvpC,
    float* __restrict__ kspL, float* __restrict__ kspC, float* __restrict__ vsp,
    const float* __restrict__ Q, const float* __restrict__ KsPart,
    float* __restrict__ Mout) {
  extern __shared__ char smraw[];
  int bx0 = blockIdx.x;
  int tid = threadIdx.x;
  if (bx0 < 512) {
    // ---- lin_cos_stats via hi/lo bf16 MFMA 3-pass ----
    float (*Kt)[65] = (float(*)[65])smraw;                          // 16640 B
    unsigned int (*Vu)[65] = (unsigned int(*)[65])(smraw + 16640);  // 16640 B
    float* nrm = (float*)(smraw + 33280);                           //   256 B
    float4* vred = (float4*)(smraw + 33536);                        //  1024 B
    int bx = bx0;
    int bh = bx >> 4, part = bx & 15;
    int b = bh >> 4, h = bh & 15;
    const int lane = tid & 63, wv = tid >> 6;
    const int l16 = lane & 15, quad = lane >> 4;
    const int dblk = wv * 16;
    const unsigned short* Kg = Kb + (size_t)(b * LENC + part * 128) * DMODEL + h * HD;
    const float* Vg = V + (size_t)(b * LENC + part * 128) * DMODEL + h * HD;
    const int sK = tid >> 2, d16 = (tid & 3) * 16;
    const int sVb = tid >> 4, v4 = (tid & 15) * 4;

    f32x4 accL[4], accC[4];
#pragma unroll
    for (int n = 0; n < 4; ++n) {
      accL[n] = (f32x4){0.f, 0.f, 0.f, 0.f};
      accC[n] = (f32x4){0.f, 0.f, 0.f, 0.f};
    }
    float kslp = 0.f, kscp = 0.f;
    float4 vpart = make_float4(0.f, 0.f, 0.f, 0.f);

    for (int ch = 0; ch < 2; ++ch) {
      const int s0 = ch * 64;
      // stage K (bf16 -> f32) + row sumsq -> nrm
      {
        const unsigned short* kr = Kg + (size_t)(s0 + sK) * DMODEL + d16;
        uint4 p0 = *(const uint4*)kr;
        uint4 p1 = *(const uint4*)(kr + 8);
        float kvv[16];
        kvv[0] = __uint_as_float(p0.x << 16);
        kvv[1] = __uint_as_float(p0.x & 0xffff0000u);
        kvv[2] = __uint_as_float(p0.y << 16);
        kvv[3] = __uint_as_float(p0.y & 0xffff0000u);
        kvv[4] = __uint_as_float(p0.z << 16);
        kvv[5] = __uint_as_float(p0.z & 0xffff0000u);
        kvv[6] = __uint_as_float(p0.w << 16);
        kvv[7] = __uint_as_float(p0.w & 0xffff0000u);
        kvv[8] = __uint_as_float(p1.x << 16);
        kvv[9] = __uint_as_float(p1.x & 0xffff0000u);
        kvv[10] = __uint_as_float(p1.y << 16);
        kvv[11] = __uint_as_float(p1.y & 0xffff0000u);
        kvv[12] = __uint_as_float(p1.z << 16);
        kvv[13] = __uint_as_float(p1.z & 0xffff0000u);
        kvv[14] = __uint_as_float(p1.w << 16);
        kvv[15] = __uint_as_float(p1.w & 0xffff0000u);
        float ss = 0.f;
#pragma unroll
        for (int j = 0; j < 16; ++j) ss = fmaf(kvv[j], kvv[j], ss);
        ss += __shfl_xor(ss, 1);
        ss += __shfl_xor(ss, 2);
        if ((tid & 3) == 0) nrm[sK] = sqrtf(ss);
#pragma unroll
        for (int j = 0; j < 16; ++j) Kt[sK][d16 + j] = kvv[j];
      }
      // stage V (f32 -> packed hi|lo bf16) + column-sum partial
#pragma unroll
      for (int i = 0; i < 4; ++i) {
        int sv = sVb + 16 * i;
        float4 vv = *(const float4*)(Vg + (size_t)(s0 + sv) * DMODEL + v4);
        vpart.x += vv.x; vpart.y += vv.y; vpart.z += vv.z; vpart.w += vv.w;
        unsigned short h0 = f2bf(vv.x), h1 = f2bf(vv.y);
        unsigned short h2 = f2bf(vv.z), h3 = f2bf(vv.w);
        Vu[sv][v4 + 0] = ((unsigned)h0 << 16) | (unsigned)f2bf(vv.x - bf2f(h0));
        Vu[sv][v4 + 1] = ((unsigned)h1 << 16) | (unsigned)f2bf(vv.y - bf2f(h1));
        Vu[sv][v4 + 2] = ((unsigned)h2 << 16) | (unsigned)f2bf(vv.z - bf2f(h2));
        Vu[sv][v4 + 3] = ((unsigned)h3 << 16) | (unsigned)f2bf(vv.w - bf2f(h3));
      }
      __syncthreads();
      // fragment build + MFMA
#pragma unroll
      for (int kk = 0; kk < 2; ++kk) {
        const int sb = kk * 32 + quad * 8;
        bf16x8 aLh, aLl, aCh, aCl;
#pragma unroll
        for (int j = 0; j < 8; ++j) {
          float kval = Kt[sb + j][dblk + l16];
          float nn = nrm[sb + j];
          float kfl = kval > 0.f ? kval + 1.f : __expf(kval);
          float kn = kval / fmaxf(nn, 1e-12f);
          float kfc = fmaxf(kn, 0.f) + 1e-6f;
          kslp += kfl;
          kscp += kfc;
          unsigned short hL = f2bf(kfl);
          aLh[j] = hL;
          aLl[j] = f2bf(kfl - bf2f(hL));
          unsigned short hC = f2bf(kfc);
          aCh[j] = hC;
          aCl[j] = f2bf(kfc - bf2f(hC));
        }
#pragma unroll
        for (int n = 0; n < 4; ++n) {
          bf16x8 bhv, blv;
#pragma unroll
          for (int j = 0; j < 8; ++j) {
            unsigned uv = Vu[sb + j][n * 16 + l16];
            bhv[j] = (short)(unsigned short)(uv >> 16);
            blv[j] = (short)(unsigned short)(uv & 0xffffu);
          }
          accL[n] = __builtin_amdgcn_mfma_f32_16x16x32_bf16(aLh, bhv, accL[n], 0, 0, 0);
          accL[n] = __builtin_amdgcn_mfma_f32_16x16x32_bf16(aLh, blv, accL[n], 0, 0, 0);
          accL[n] = __builtin_amdgcn_mfma_f32_16x16x32_bf16(aLl, bhv, accL[n], 0, 0, 0);
          accC[n] = __builtin_amdgcn_mfma_f32_16x16x32_bf16(aCh, bhv, accC[n], 0, 0, 0);
          accC[n] = __builtin_amdgcn_mfma_f32_16x16x32_bf16(aCh, blv, accC[n], 0, 0, 0);
          accC[n] = __builtin_amdgcn_mfma_f32_16x16x32_bf16(aCl, bhv, accC[n], 0, 0, 0);
        }
      }
      __syncthreads();
    }
    // outputs: kv partials (D layout: row = quad*4+q, col = l16)
    const int obase = part * 131072 + bh * 4096;
#pragma unroll
    for (int n = 0; n < 4; ++n)
#pragma unroll
      for (int q = 0; q < 4; ++q) {
        int o = obase + (dblk + quad * 4 + q) * 64 + n * 16 + l16;
        kvpL[o] = accL[n][q];
        kvpC[o] = accC[n][q];
      }
    kslp += __shfl_xor(kslp, 16);
    kslp += __shfl_xor(kslp, 32);
    kscp += __shfl_xor(kscp, 16);
    kscp += __shfl_xor(kscp, 32);
    if (quad == 0) {
      kspL[part * 2048 + bh * 64 + dblk + l16] = kslp;
      kspC[part * 2048 + bh * 64 + dblk + l16] = kscp;
    }
    vpart.x += __shfl_xor(vpart.x, 16); vpart.x += __shfl_xor(vpart.x, 32);
    vpart.y += __shfl_xor(vpart.y, 16); vpart.y += __shfl_xor(vpart.y, 32);
    vpart.z += __shfl_xor(vpart.z, 16); vpart.z += __shfl_xor(vpart.z, 32);
    vpart.w += __shfl_xor(vpart.w, 16); vpart.w += __shfl_xor(vpart.w, 32);
    if (quad == 0) vred[wv * 16 + l16] = vpart;
    __syncthreads();
    if (tid < 16) {
      float4 a0 = vred[tid], a1 = vred[16 + tid];
      float4 a2 = vred[32 + tid], a3 = vred[48 + tid];
      float4 s = make_float4(a0.x + a1.x + a2.x + a3.x, a0.y + a1.y + a2.y + a3.y,
                             a0.z + a1.z + a2.z + a3.z, a0.w + a1.w + a2.w + a3.w);
      *(float4*)&vsp[part * 2048 + bh * 64 + tid * 4] = s;
    }
  } else {
    // ---- pp_scores (fp32; sums the 8 split-K partials in fixed order) ----
    float (*ksL)[65] = (float(*)[65])smraw;  // 38*65*4 = 9880 B
    int bx = bx0 - 512;
    int bh = bx >> 2, chunk = bx & 3;
    int b = bh >> 4, h = bh & 15;
    int t0 = chunk * 128;
    const float* Qb = Q + (b * LDEC) * DMODEL + h * HD;
    for (int slot = tid; slot < NSAMP * 16; slot += 256) {
      int r = slot >> 4, c4 = slot & 15;
      const float* kp = KsPart + r * 1024 + h * HD + c4 * 4;
      float4 kx = *(const float4*)kp;
#pragma unroll
      for (int p = 1; p < 8; ++p) {
        float4 k2 = *(const float4*)(kp + (size_t)p * (NSAMP * 1024));
        kx.x += k2.x; kx.y += k2.y; kx.z += k2.z; kx.w += k2.w;
      }
      ksL[r][c4 * 4 + 0] = kx.x; ksL[r][c4 * 4 + 1] = kx.y;
      ksL[r][c4 * 4 + 2] = kx.z; ksL[r][c4 * 4 + 3] = kx.w;
    }
    __syncthreads();
    if (tid < 128) {
      float qr[64];
      const float* qrow = Qb + (size_t)(t0 + tid) * DMODEL;
#pragma unroll
      for (int d4 = 0; d4 < 16; ++d4)
        *(float4*)&qr[d4 * 4] = *(const float4*)(qrow + d4 * 4);
      float mx = -INFINITY, sm = 0.f;
      for (int j = 0; j < NSAMP; ++j) {
        float s = 0.f;
#pragma unroll
        for (int d = 0; d < 64; ++d) s = fmaf(qr[d], ksL[j][d], s);
        s *= SCALE;
        mx = fmaxf(mx, s);
        sm += s;
      }
      Mout[bh * LDEC + t0 + tid] = mx - sm / (float)NSAMP;
    }
  }
}

// ------ MFMA flash attention (split-K 4 + XCD swizzle) FUSED with tail2 -----
// grid: [0,1080) tail2 FIRST | [1080,2104) attn.
// SAFETY: attn outputs (P0..P3, L0, L1, stats) at ws+18M.. fully disjoint
// from tail2's inputs/outputs. Vt now at ws+25M (written by gemm_qkv).
__global__ __launch_bounds__(256) void attn_mfma(
    const float* __restrict__ Qf, const unsigned short* __restrict__ Kb,
    const unsigned short* __restrict__ Vt,
    float* __restrict__ OsP0, float* __restrict__ OsP1,
    float* __restrict__ OsP2, float* __restrict__ OsP3,
    float* __restrict__ OlS0, float* __restrict__ OlS1,
    float* __restrict__ st,
    const float* __restrict__ kvpL, const float* __restrict__ kvpC,
    const float* __restrict__ kspL, const float* __restrict__ kspC,
    const float* __restrict__ vsp, float* __restrict__ kvL,
    float* __restrict__ kvC, float* __restrict__ ksL,
    float* __restrict__ ksC, float* __restrict__ vmean,
    const float* __restrict__ Mbuf, int* __restrict__ sel) {
  __shared__ unsigned short Ks[2][4096];
  __shared__ unsigned short Vs[2][4096];
  __shared__ unsigned short Ps[4][1024];
  const int tid = threadIdx.x;
  const int bxAll = blockIdx.x;
  if (bxAll < 1080) {
    // ================= tail2 (independent of attn; fused launch) ===========
    int bx = bxAll;
    if (bx < 1048) {
      int i = bx * 256 + tid;
      if (i < 131072) {
        float s = 0.f;
#pragma unroll
        for (int p = 0; p < 16; ++p) s += kvpL[p * 131072 + i];
        kvL[i] = s;
      } else if (i < 262144) {
        int j = i - 131072;
        float s = 0.f;
#pragma unroll
        for (int p = 0; p < 16; ++p) s += kvpC[p * 131072 + j];
        kvC[j] = s;
      } else if (i < 268288) {
        int j = i - 262144;
        int which = j >> 11, jj = j & 2047;
        const float* src = which == 0 ? kspL : (which == 1 ? kspC : vsp);
        float s = 0.f;
#pragma unroll
        for (int p = 0; p < 16; ++p) s += src[p * 2048 + jj];
        if (which == 0) ksL[jj] = s;
        else if (which == 1) ksC[jj] = s;
        else vmean[jj] = s * (1.f / 2048.f);
      }
    } else {
      // ---- pp_topk (tie -> lower index), LDS aliased onto Ks/Vs ----
      char* smraw = (char*)Ks;
      float* vals = (float*)smraw;
      int* flag = (int*)(smraw + 2048);
      float* wvs = (float*)(smraw + 4096);
      int* wis = (int*)(smraw + 4112);
      int bh = bx - 1048;
      int lane = tid & 63, g = tid >> 6;
      vals[tid] = Mbuf[bh * 512 + tid];
      vals[tid + 256] = Mbuf[bh * 512 + tid + 256];
      flag[tid] = 0; flag[tid + 256] = 0;
      __syncthreads();
      for (int it = 0; it < NTOP; ++it) {
        float v0 = vals[tid]; int i0 = tid;
        float v1 = vals[tid + 256];
        if (v1 > v0) { v0 = v1; i0 = tid + 256; }
#pragma unroll
        for (int mm = 32; mm > 0; mm >>= 1) {
          float ov = __shfl_xor(v0, mm);
          int oi = __shfl_xor(i0, mm);
          if (ov > v0 || (ov == v0 && oi < i0)) { v0 = ov; i0 = oi; }
        }
        if (lane == 0) { wvs[g] = v0; wis[g] = i0; }
        __syncthreads();
        if (tid == 0) {
          float bv = wvs[0]; int bi = wis[0];
#pragma unroll
          for (int w = 1; w < 4; ++w)
            if (wvs[w] > bv || (wvs[w] == bv && wis[w] < bi)) { bv = wvs[w]; bi = wis[w]; }
          vals[bi] = -INFINITY;
          flag[bi] = 1;
        }
        __syncthreads();
      }
      sel[bh * 512 + tid] = flag[tid];
      sel[bh * 512 + tid + 256] = flag[tid + 256];
    }
    return;
  }
  // ========================= attention proper ==============================
  const int wave = tid >> 6, lane = tid & 63;
  const int l16 = lane & 15, quad = lane >> 4;
  const int bx = bxAll - 1080;
  const int xcd = bx & 7, sub = bx >> 3;
  const int qt = sub & 7, qr = (sub >> 3) & 3, grp = sub >> 5;
  const int bh = xcd + 8 * grp;
  const int b = bh >> 4, h = bh & 15;
  const int tbase = qt * 64 + wave * 16;
  const int sbase = qr * 512;

  const float* qrow = Qf + (size_t)(b * LDEC + tbase + l16) * DMODEL + h * HD + quad * 8;
  bf16x8 qa0, qa1;
  {
    float4 a0 = *(const float4*)qrow, a1 = *(const float4*)(qrow + 4);
    float4 a2 = *(const float4*)(qrow + 32), a3 = *(const float4*)(qrow + 36);
    qa0[0] = f2bf(a0.x * SCALE); qa0[1] = f2bf(a0.y * SCALE);
    qa0[2] = f2bf(a0.z * SCALE); qa0[3] = f2bf(a0.w * SCALE);
    qa0[4] = f2bf(a1.x * SCALE); qa0[5] = f2bf(a1.y * SCALE);
    qa0[6] = f2bf(a1.z * SCALE); qa0[7] = f2bf(a1.w * SCALE);
    qa1[0] = f2bf(a2.x * SCALE); qa1[1] = f2bf(a2.y * SCALE);
    qa1[2] = f2bf(a2.z * SCALE); qa1[3] = f2bf(a2.w * SCALE);
    qa1[4] = f2bf(a3.x * SCALE); qa1[5] = f2bf(a3.y * SCALE);
    qa1[6] = f2bf(a3.z * SCALE); qa1[7] = f2bf(a3.w * SCALE);
  }

  // ones B-fragment: row-sum of P via MFMA (D col all equal)
  bf16x8 bone;
#pragma unroll
  for (int j = 0; j < 8; ++j) bone[j] = (short)0x3f80;

  int tA = tbase + l16;
  int cA = min(4 * tA, LENC - 1);
  int loA = max(cA - 256, 0), hiA = min(cA + 256, LENC - 1);
  const int loW = max(4 * tbase - 256, 0);
  const int hiW = min(4 * (tbase + 15) + 256, LENC - 1);
  const bool blockAny = (sbase <= hiW) && (sbase + 511 >= loW);

  f32x4 Os[4], Ol[4], Ssum, Slsum;
#pragma unroll
  for (int n = 0; n < 4; ++n) {
    Os[n] = (f32x4){0.f, 0.f, 0.f, 0.f};
    Ol[n] = (f32x4){0.f, 0.f, 0.f, 0.f};
  }
  Ssum = (f32x4){0.f, 0.f, 0.f, 0.f};
  Slsum = (f32x4){0.f, 0.f, 0.f, 0.f};

  const int c0 = tid, c1 = tid + 256;
  const unsigned short* kg0 = Kb + (size_t)(b * LENC + sbase + (c0 >> 3)) * DMODEL + h * HD + (c0 & 7) * 8;
  const unsigned short* kg1 = Kb + (size_t)(b * LENC + sbase + (c1 >> 3)) * DMODEL + h * HD + (c1 & 7) * 8;
  const unsigned short* vg0 = Vt + (size_t)(bh * 64 + (c0 >> 3)) * LENC + sbase + (c0 & 7) * 8;
  const unsigned short* vg1 = Vt + (size_t)(bh * 64 + (c1 >> 3)) * LENC + sbase + (c1 & 7) * 8;
  const int of0 = sws(c0 >> 3, (c0 & 7) * 8);
  const int of1 = sws(c1 >> 3, (c1 & 7) * 8);

  uint4 pk0, pk1, pv0, pv1;
  pk0 = *(const uint4*)kg0; pk1 = *(const uint4*)kg1;
  pv0 = *(const uint4*)vg0; pv1 = *(const uint4*)vg1;
  *(uint4*)&Ks[0][of0] = pk0; *(uint4*)&Ks[0][of1] = pk1;
  *(uint4*)&Vs[0][of0] = pv0; *(uint4*)&Vs[0][of1] = pv1;
  __syncthreads();

  for (int it = 0; it < 8; ++it) {
    const int cur = it & 1;
    const int s0 = sbase + it * 64;
    const bool anyL = (s0 <= hiW) && (s0 + 63 >= loW);
    if (it < 7) {
      pk0 = *(const uint4*)(kg0 + (size_t)(it + 1) * 64 * DMODEL);
      pk1 = *(const uint4*)(kg1 + (size_t)(it + 1) * 64 * DMODEL);
      pv0 = *(const uint4*)(vg0 + (it + 1) * 64);
      pv1 = *(const uint4*)(vg1 + (it + 1) * 64);
    }
    const unsigned short* K_ = Ks[cur];
    const unsigned short* V_ = Vs[cur];

    f32x4 S[4];
#pragma unroll
    for (int n = 0; n < 4; ++n) {
      bf16x8 bk0 = *(const bf16x8*)&K_[sws(n * 16 + l16, quad * 8)];
      bf16x8 bk1 = *(const bf16x8*)&K_[sws(n * 16 + l16, 32 + quad * 8)];
      f32x4 z = (f32x4){0.f, 0.f, 0.f, 0.f};
      z = __builtin_amdgcn_mfma_f32_16x16x32_bf16(qa0, bk0, z, 0, 0, 0);
      S[n] = __builtin_amdgcn_mfma_f32_16x16x32_bf16(qa1, bk1, z, 0, 0, 0);
    }

    unsigned short* Pw = Ps[wave];
#pragma unroll
    for (int n = 0; n < 4; ++n)
#pragma unroll
      for (int r = 0; r < 4; ++r)
        Pw[sws(quad * 4 + r, n * 16 + l16)] = f2bf(__expf(S[n][r]));
    bf16x8 aP0 = *(const bf16x8*)&Pw[sws(l16, quad * 8)];
    bf16x8 aP1 = *(const bf16x8*)&Pw[sws(l16, 32 + quad * 8)];
    // row sums (softmax denominators) via ones-column MFMA
    Ssum = __builtin_amdgcn_mfma_f32_16x16x32_bf16(aP0, bone, Ssum, 0, 0, 0);
    Ssum = __builtin_amdgcn_mfma_f32_16x16x32_bf16(aP1, bone, Ssum, 0, 0, 0);
#pragma unroll
    for (int n = 0; n < 4; ++n) {
      bf16x8 bv0 = *(const bf16x8*)&V_[sws(n * 16 + l16, quad * 8)];
      bf16x8 bv1 = *(const bf16x8*)&V_[sws(n * 16 + l16, 32 + quad * 8)];
      Os[n] = __builtin_amdgcn_mfma_f32_16x16x32_bf16(aP0, bv0, Os[n], 0, 0, 0);
      Os[n] = __builtin_amdgcn_mfma_f32_16x16x32_bf16(aP1, bv1, Os[n], 0, 0, 0);
    }
    if (anyL) {
      bf16x8 aL0 = aP0, aL1 = aP1;
#pragma unroll
      for (int j = 0; j < 8; ++j) {
        int sc = s0 + quad * 8 + j;
        if (sc < loA || sc > hiA) aL0[j] = 0;
        if (sc + 32 < loA || sc + 32 > hiA) aL1[j] = 0;
      }
      Slsum = __builtin_amdgcn_mfma_f32_16x16x32_bf16(aL0, bone, Slsum, 0, 0, 0);
      Slsum = __builtin_amdgcn_mfma_f32_16x16x32_bf16(aL1, bone, Slsum, 0, 0, 0);
#pragma unroll
      for (int n = 0; n < 4; ++n) {
        bf16x8 bv0 = *(const bf16x8*)&V_[sws(n * 16 + l16, quad * 8)];
        bf16x8 bv1 = *(const bf16x8*)&V_[sws(n * 16 + l16, 32 + quad * 8)];
        Ol[n] = __builtin_amdgcn_mfma_f32_16x16x32_bf16(aL0, bv0, Ol[n], 0, 0, 0);
        Ol[n] = __builtin_amdgcn_mfma_f32_16x16x32_bf16(aL1, bv1, Ol[n], 0, 0, 0);
      }
    }
    // single barrier per iteration: all reads of buffer (1-cur) completed
    // before the previous iteration's barrier, so writing it now is safe.
    if (it < 7) {
      unsigned short* KL = Ks[1 - cur];
      unsigned short* VL = Vs[1 - cur];
      *(uint4*)&KL[of0] = pk0; *(uint4*)&KL[of1] = pk1;
      *(uint4*)&VL[of0] = pv0; *(uint4*)&VL[of1] = pv1;
    }
    __syncthreads();
  }

  float* osp = qr == 0 ? OsP0 : (qr == 1 ? OsP1 : (qr == 2 ? OsP2 : OsP3));
  float* olp = (qr & 1) ? OlS1 : OlS0;
  float* sp = st + qr * 32768;
#pragma unroll
  for (int r = 0; r < 4; ++r) {
    int t = tbase + quad * 4 + r;
#pragma unroll
    for (int n = 0; n < 4; ++n) {
      size_t o = (size_t)(b * LDEC + t) * DMODEL + h * HD + n * 16 + l16;
      osp[o] = Os[n][r];
      if (blockAny) olp[o] = Ol[n][r];
    }
    if (l16 == 0) {
      int sr = bh * 512 + t;
      sp[sr] = Ssum[r];
      sp[16384 + sr] = Slsum[r];
    }
  }
}

// fused: split-K-4 combine + probsparse fill + lin/cos apply.
// Emits bf16 DIRECTLY into b16 (the gemm_one input).
// grid: [0,1024) combine | [1024,5120) lin_cos.
__global__ __launch_bounds__(256) void combine_fill(
    const float* __restrict__ P0, const float* __restrict__ P1,
    const float* __restrict__ P2, const float* __restrict__ P3,
    const float* __restrict__ L0, const float* __restrict__ L1,
    const float* __restrict__ st,
    const float* __restrict__ vmean, const int* __restrict__ sel,
    const float* __restrict__ Q, const float* __restrict__ kvL,
    const float* __restrict__ kvC, const float* __restrict__ ksL,
    const float* __restrict__ ksC,
    unsigned short* __restrict__ b16) {
  __shared__ float sh[2][4][64];
  int bx0 = blockIdx.x;
  int tid = threadIdx.x;
  if (bx0 < 1024) {
    int i4 = bx0 * 256 + tid;
    int i = i4 * 4;
    int col = i & 1023, bt = i >> 10;
    int t = bt & 511, b = bt >> 9, h = col >> 6, d = col & 63;
    int bh = b * 16 + h;
    int sr = bh * 512 + t;
    float iS = 1.f / (st[sr] + st[32768 + sr] + st[65536 + sr] + st[98304 + sr]);
    float iL = 1.f / (st[16384 + sr] + st[49152 + sr] + st[81920 + sr] + st[114688 + sr]);
    float4 s0 = *(const float4*)(P0 + i);
    float4 s1 = *(const float4*)(P1 + i);
    float4 s2 = *(const float4*)(P2 + i);
    float4 s3 = *(const float4*)(P3 + i);
    // local-branch: row t's window touches quarters q0..q1 (q1-q0 <= 1);
    // quarter q wrote parity slot q&1 (slot0 = L0, slot1 = L1).
    int c = min(4 * t, LENC - 1);
    int lo = max(c - 256, 0), hi = min(c + 256, LENC - 1);
    int q0 = lo >> 9, q1 = hi >> 9;
    const float* Lp0 = (q0 & 1) ? L1 : L0;
    float4 l = *(const float4*)(Lp0 + i);
    if (q1 != q0) {
      const float* Lp1 = (q1 & 1) ? L1 : L0;
      float4 l2 = *(const float4*)(Lp1 + i);
      l.x += l2.x; l.y += l2.y; l.z += l2.z; l.w += l2.w;
    }
    float4 os = make_float4((s0.x + s1.x + s2.x + s3.x) * iS,
                            (s0.y + s1.y + s2.y + s3.y) * iS,
                            (s0.z + s1.z + s2.z + s3.z) * iS,
                            (s0.w + s1.w + s2.w + s3.w) * iS);
    float4 ol = make_float4(l.x * iL, l.y * iL, l.z * iL, l.w * iL);
    float4 pp = sel[sr] ? os : *(const float4*)(vmean + bh * 64 + d);
    uint2 o2;
    o2.x = (unsigned)f2bf(os.x) | ((unsigned)f2bf(os.y) << 16);
    o2.y = (unsigned)f2bf(os.z) | ((unsigned)f2bf(os.w) << 16);
    *(uint2*)(b16 + i) = o2;
    o2.x = (unsigned)f2bf(pp.x) | ((unsigned)f2bf(pp.y) << 16);
    o2.y = (unsigned)f2bf(pp.z) | ((unsigned)f2bf(pp.w) << 16);
    *(uint2*)(b16 + 2097152 + i) = o2;
    o2.x = (unsigned)f2bf(ol.x) | ((unsigned)f2bf(ol.y) << 16);
    o2.y = (unsigned)f2bf(ol.z) | ((unsigned)f2bf(ol.w) << 16);
    *(uint2*)(b16 + 4194304 + i) = o2;
  } else {
    // ---- lin_cos_apply (bf16 direct out) ----
    int lane = tid & 63, g = tid >> 6;
    int row = (bx0 - 1024) * 4 + g;
    int bh = row >> 9, t = row & 511;
    int b = bh >> 4, h = bh & 15;
    float qv = Q[(b * LDEC + t) * DMODEL + h * HD + lane];
    float x = qv * SCALE;
    float qfl = x > 0.f ? x + 1.f : __expf(x);
    float qnorm = sqrtf(wave_sum(qv * qv));
    float qn = qv / fmaxf(qnorm, 1e-12f);
    float qfc = fmaxf(qn, 0.f) + 1e-6f;
    sh[0][g][lane] = qfl;
    sh[1][g][lane] = qfc;
    float denL = fmaxf(wave_sum(qfl * ksL[bh * 64 + lane]), 1e-6f);
    float denC = fmaxf(wave_sum(qfc * ksC[bh * 64 + lane]), 1e-6f);
    const float* kvLb = kvL + bh * 4096;
    const float* kvCb = kvC + bh * 4096;
    float aL = 0.f, aC = 0.f;
#pragma unroll
    for (int d = 0; d < 64; ++d) {
      aL = fmaf(sh[0][g][d], kvLb[d * 64 + lane], aL);
      aC = fmaf(sh[1][g][d], kvCb[d * 64 + lane], aC);
    }
    int o = (b * LDEC + t) * DMODEL + h * HD + lane;
    b16[1048576 + o] = f2bf(aL / denL);
    b16[3145728 + o] = f2bf(aC / denC);
  }
}

// ---------------- final combine
__global__ __launch_bounds__(256) void combine(
    const float* __restrict__ dec, const float* __restrict__ proj,
    const float* __restrict__ rmsw, const float* __restrict__ alphas,
    float* __restrict__ out) {
  __shared__ float red[4];
  int row = blockIdx.x;
  int tid = threadIdx.x, lane = tid & 63, g = tid >> 6;
  int base = row * DMODEL + tid * 4;
  float4 dv = *(const float4*)(dec + base);
  float4 wv = *(const float4*)(rmsw + tid * 4);
  float a[6];
  float amax = -INFINITY;
#pragma unroll
  for (int i = 0; i < 6; ++i) { a[i] = alphas[i]; amax = fmaxf(amax, a[i]); }
  float asum = 0.f;
#pragma unroll
  for (int i = 0; i < 6; ++i) { a[i] = __expf(a[i] - amax); asum += a[i]; }
#pragma unroll
  for (int i = 0; i < 6; ++i) a[i] /= asum;
  float4 acc = make_float4(a[0] * dv.x, a[0] * dv.y, a[0] * dv.z, a[0] * dv.w);
  for (int br = 0; br < 5; ++br) {
    float4 pv = *(const float4*)(proj + br * 1048576 + base);
    float4 xx = make_float4(dv.x + pv.x, dv.y + pv.y, dv.z + pv.z, dv.w + pv.w);
    float ssq = xx.x * xx.x + xx.y * xx.y + xx.z * xx.z + xx.w * xx.w;
    float wsum = wave_sum(ssq);
    if (lane == 0) red[g] = wsum;
    __syncthreads();
    float tot = red[0] + red[1] + red[2] + red[3];
    float rr = rsqrtf(tot / 1024.f + 1e-6f);
    float wb = a[br + 1];
    acc.x += wb * xx.x * rr * wv.x;
    acc.y += wb * xx.y * rr * wv.y;
    acc.z += wb * xx.z * rr * wv.z;
    acc.w += wb * xx.w * rr * wv.w;
    __syncthreads();
  }
  *(float4*)(out + base) = acc;
}

extern "C" void kernel_launch(void* const* d_in, const int* in_sizes, int n_in,
                              void* d_out, int out_size, void* d_ws, size_t ws_size,
                              hipStream_t stream) {
  const float* dec = (const float*)d_in[0];
  const float* enc = (const float*)d_in[1];
  const float* Wq = (const float*)d_in[2];
  const float* Wk = (const float*)d_in[3];
  const float* Wv = (const float*)d_in[4];
  const float* Wo = (const float*)d_in[5];
  const float* rmsw = (const float*)d_in[6];
  const float* alphas = (const float*)d_in[7];
  const int* sidx = (const int*)d_in[8];

  const size_t M = 1048576;
  float* ws = (float*)d_ws;
  float* Q    = ws;                                  // [0,1M)
  unsigned short* Kb16 = (unsigned short*)(ws + M);  // [1M,3M)
  float* KsPart = ws + 3 * M;                        // [3M,+311296)
  float* V    = ws + 5 * M;                          // [5M,9M)
  unsigned short* Wqh = (unsigned short*)(ws + 9 * M);
  unsigned short* Wql = (unsigned short*)(ws + 9 * M + M / 2);
  unsigned short* Wkh = (unsigned short*)(ws + 10 * M);
  unsigned short* Wvh = (unsigned short*)(ws + 10 * M + M / 2);
  unsigned short* eh  = (unsigned short*)(ws + 11 * M);
  unsigned short* dh  = (unsigned short*)(ws + 15 * M);
  unsigned short* dl  = (unsigned short*)(ws + 15 * M + M / 2);
  float* kvpL = ws + 11 * M;
  float* kvpC = ws + 13 * M;
  float* kspL = ws + 15 * M;
  float* kspC = ws + 15 * M + 32768;
  float* vsp  = ws + 15 * M + 65536;
  float* tail = ws + 16 * M;
  float* kvL  = tail;
  float* kvC  = tail + 131072;
  float* ksL  = tail + 262144;
  float* ksC  = tail + 264192;
  float* vmean= tail + 266240;
  float* Mbuf = tail + 317440;
  int*   sel  = (int*)(tail + 333824);
  // bf16 GEMM inputs: braw16 written by combine_fill; Woh by prologue.
  unsigned short* braw16 = (unsigned short*)(ws + 12 * M);
  unsigned short* Woh = (unsigned short*)(ws + 17 * M);
  // attn split-K-4 partials: VIRGIN regions (>=18M).
  float* P0   = ws + 18 * M;
  float* OsP1 = ws + 19 * M;
  float* OsP2 = ws + 20 * M;
  float* OsP3 = ws + 21 * M;
  float* OlS0 = ws + 22 * M;
  float* OlS1 = ws + 23 * M;
  float* stats = ws + 24 * M;  // 4*32768 floats
  // Vt (bf16 transposed V) now written by gemm_qkv's V epilogue.
  // MUST be virgin: old ws+9M slot overlaps Wq/Wk/Wv bf16 weights which
  // gemm_qkv reads concurrently. Park at ws+25M..27M.
  unsigned short* Vtb = (unsigned short*)(ws + 25 * M);
  float* proj = ws + 3 * M + M / 2;

  hipLaunchKernelGGL(prologue, dim3(7360), dim3(256), 17408, stream,
                     dec, enc, Wq, Wk, Wv, sidx, dh, dl, eh, Wqh, Wql, Wkh, Wvh,
                     KsPart, Wo, Woh);
  hipLaunchKernelGGL(gemm_qkv, dim3(72, 8), dim3(512), 81920, stream,
                     dh, dl, Wqh, Wql, Q, eh, Wkh, Kb16, Wvh, V, Vtb);
  hipLaunchKernelGGL(trio, dim3(640), dim3(256), 34816, stream,
                     V, Kb16, kvpL, kvpC, kspL, kspC, vsp, Q, KsPart, Mbuf);
  hipLaunchKernelGGL(attn_mfma, dim3(2104), dim3(256), 0, stream, Q, Kb16, Vtb,
                     P0, OsP1, OsP2, OsP3, OlS0, OlS1, stats,
                     kvpL, kvpC, kspL, kspC, vsp, kvL, kvC, ksL, ksC, vmean,
                     Mbuf, sel);
  hipLaunchKernelGGL(combine_fill, dim3(5120), dim3(256), 0, stream,
                     P0, OsP1, OsP2, OsP3, OlS0, OlS1, stats, vmean, sel,
                     Q, kvL, kvC, ksL, ksC, braw16);
  hipLaunchKernelGGL(gemm_one, dim3(40, 8), dim3(512), 65536, stream, braw16, Woh, proj);
  hipLaunchKernelGGL(combine, dim3(1024), dim3(256), 0, stream, dec, proj, rmsw, alphas,
                     (float*)d_out);
}